// Round 9
// baseline (12673.492 us; speedup 1.0000x reference)
//
#include <hip/hip_runtime.h>
#include <cstdio>
#include <cstdint>

typedef __bf16 bf16;
typedef __attribute__((ext_vector_type(8))) __bf16 bf16x8;
typedef __attribute__((ext_vector_type(4))) __bf16 bf16x4;
typedef __attribute__((ext_vector_type(4))) float f32x4;
typedef unsigned long long u64;
typedef unsigned int u32;

// ---------------- problem dims ----------------
constexpr int BATCH = 16, TT = 750, DD = 2048, NC = 20;
constexpr int MM = 12000;
constexpr int PT = 758;            // padded T (4+750+4)
constexpr int PCH = 32;            // pairs per chunk (4 batches x 8 heads)
constexpr int NCHUNK = 4;
constexpr int RPC = 3000;          // x rows per chunk
constexpr int SROW = 752;
constexpr int SPAIR = 750 * SROW;  // 564000
constexpr int KE = 150, KH = 37;

// ---------------- output offsets (floats) ----------------
constexpr size_t OUT_EA  = 320;
constexpr size_t OUT_EB  = OUT_EA + (size_t)BATCH * KE * DD;
constexpr size_t OUT_HA  = OUT_EB + (size_t)BATCH * KE * DD;
constexpr size_t OUT_HB  = OUT_HA + (size_t)BATCH * KH * DD;
constexpr size_t OUT_ACT = OUT_HB + (size_t)BATCH * KH * DD;
constexpr size_t OUT_CAS = OUT_ACT + MM;

// ---------------- workspace (bytes) ----------------
constexpr size_t XCB = (size_t)(BATCH * PT) * DD * 2;   // 49,676,288
constexpr size_t O_XC1   = 0;
constexpr size_t O_XC2   = O_XC1 + XCB;
constexpr size_t O_XC3   = O_XC2 + XCB;
constexpr size_t O_EM1   = O_XC3 + XCB;
constexpr size_t O_EM2   = O_EM1 + XCB;
constexpr size_t O_EM3   = O_EM2 + XCB;
constexpr size_t O_CAS1  = O_EM3 + XCB;                  // 298,057,728
constexpr size_t O_CAST  = O_CAS1 + 960000;
constexpr size_t O_ACT   = O_CAST + 960000;
constexpr size_t O_AREV  = O_ACT + 48000;
constexpr size_t O_INNER = O_AREV + 48000;
constexpr size_t O_OUTER = O_INNER + 48000;
constexpr size_t O_SMEAN = O_OUTER + 48000;
constexpr size_t O_IDX   = O_SMEAN + 1280;
constexpr size_t O_RSINV = O_IDX + 23936;
constexpr size_t O_CSINV = O_RSINV + 96000;
constexpr size_t O_DBG   = O_CSINV + 96000;
constexpr size_t AR      = O_DBG + 256;                  // 300,387,200

constexpr size_t SB   = (size_t)PCH * SPAIR * 4;         // 72,192,000
constexpr size_t PL   = (size_t)PCH * 750 * 128 * 2;     // 6,144,000  o plane
constexpr size_t TPL  = (size_t)PCH * 128 * 768 * 2;     // 6,291,456  oT plane
constexpr size_t O_S    = AR;
constexpr size_t O_ST   = O_S + SB;
constexpr size_t O_Q1   = O_ST + SB;
constexpr size_t O_Q2   = O_Q1 + PL;
constexpr size_t O_Q3   = O_Q2 + PL;
constexpr size_t O_OR1  = O_Q3 + PL;
constexpr size_t O_OR2  = O_OR1 + PL;
constexpr size_t O_OR3  = O_OR2 + PL;
constexpr size_t O_OF1  = O_OR3 + PL;
constexpr size_t O_OF2  = O_OF1 + PL;
constexpr size_t O_OF3  = O_OF2 + PL;
constexpr size_t O_OTR1 = O_OF3 + PL;
constexpr size_t O_OTR2 = O_OTR1 + TPL;
constexpr size_t O_OTR3 = O_OTR2 + TPL;
constexpr size_t O_OTF1 = O_OTR3 + TPL;
constexpr size_t O_OTF2 = O_OTF1 + TPL;
constexpr size_t O_OTF3 = O_OTF2 + TPL;
constexpr size_t O_OPRE = O_OTF3 + TPL;                  // RPC*1024*4
constexpr size_t PRP  = (size_t)1024 * 1024 * 2;
constexpr size_t O_PR1  = O_OPRE + (size_t)RPC * 1024 * 4;
constexpr size_t O_PR2  = O_PR1 + PRP;
constexpr size_t O_PR3  = O_PR2 + PRP;
constexpr size_t O_PF1  = O_PR3 + PRP;
constexpr size_t O_PF2  = O_PF1 + PRP;
constexpr size_t O_PF3  = O_PF2 + PRP;
constexpr size_t AWP  = (size_t)8 * 128 * 128 * 2;
constexpr size_t O_AW1  = O_PF3 + PRP;
constexpr size_t O_AW2  = O_AW1 + AWP;
constexpr size_t O_AW3  = O_AW2 + AWP;
constexpr size_t WS_NEED = O_AW3 + AWP;                  // 563,473,280

// conv weights alias dead attention arena
constexpr size_t WTP  = (size_t)9 * 2048 * 2048 * 2;     // 75,497,472
constexpr size_t O_WT1  = AR;
constexpr size_t O_WT2  = O_WT1 + WTP;
constexpr size_t O_WT3  = O_WT2 + WTP;
constexpr size_t WCP  = (size_t)9 * 32 * 2048 * 2;
constexpr size_t O_WC1  = O_WT3 + WTP;
constexpr size_t O_WC2  = O_WC1 + WCP;
constexpr size_t O_WC3  = O_WC2 + WCP;

static_assert(O_WC3 + WCP <= WS_NEED, "WT/WC overrun");
static_assert(WS_NEED <= 603979776, "exceeds harness ws");

// ---------------- helpers ----------------
struct bf3 { bf16 h, m, l; };
static __device__ __forceinline__ bf3 split3(float v) {
  bf3 r;
  r.h = (bf16)v;
  float rem = v - (float)r.h;
  r.m = (bf16)rem;
  r.l = (bf16)(rem - (float)r.m);
  return r;
}
static __device__ __forceinline__ bf16x8 bzero8() {
  bf16x8 v;
#pragma unroll
  for (int i = 0; i < 8; i++) v[i] = (bf16)0.f;
  return v;
}
static __device__ __forceinline__ u32 asc_enc(float f) {
  u32 u = __float_as_uint(f);
  return (u & 0x80000000u) ? ~u : (u | 0x80000000u);
}
static __device__ __forceinline__ float asc_dec(u32 a) {
  u32 u = (a & 0x80000000u) ? (a ^ 0x80000000u) : ~a;
  return __uint_as_float(u);
}
static __device__ void bsort1024(u64* ks) {
  const int tid = threadIdx.x;
  for (int kk = 2; kk <= 1024; kk <<= 1) {
    for (int j = kk >> 1; j > 0; j >>= 1) {
      __syncthreads();
      for (int i = tid; i < 1024; i += 512) {
        int ixj = i ^ j;
        if (ixj > i) {
          u64 a = ks[i], b = ks[ixj];
          bool up = ((i & kk) == 0);
          if ((a > b) == up) { ks[i] = b; ks[ixj] = a; }
        }
      }
    }
  }
  __syncthreads();
}

// LDS layout: padded 80-byte rows (40 bf16), no XOR. Bank period 8 -> 2-way (free).
// ---------------- f32-acc 6-term GEMM (3-plane operands, BK=32) ----------------
template <int WGM, int WGN, int FM, int FN, class P>
__global__ __launch_bounds__(256) void gemm6(P p) {
  constexpr int BM = WGM * FM * 16;
  constexpr int BN = WGN * FN * 16;
  __shared__ bf16 sA1[BM * 40];
  __shared__ bf16 sA2[BM * 40];
  __shared__ bf16 sA3[BM * 40];
  __shared__ bf16 sB1[BN * 40];
  __shared__ bf16 sB2[BN * 40];
  __shared__ bf16 sB3[BN * 40];
  const int tid = threadIdx.x;
  const int z = blockIdx.z;
  const int row0 = blockIdx.y * BM;
  const int col0 = blockIdx.x * BN;
  const int lane = tid & 63;
  const int wv = tid >> 6;
  const int wm = (wv % WGM) * (FM * 16);
  const int wn = (wv / WGM) * (FN * 16);
  f32x4 acc[FM][FN];
#pragma unroll
  for (int i = 0; i < FM; i++)
#pragma unroll
    for (int j = 0; j < FN; j++)
#pragma unroll
      for (int r = 0; r < 4; r++) acc[i][j][r] = 0.f;

  const int ks = p.ksteps();
  for (int s = 0; s < ks; ++s) {
#pragma unroll
    for (int g0 = 0; g0 < BM * 4; g0 += 256) {
      int g = g0 + tid;
      if (g < BM * 4) {
        int row = g >> 2, k0 = (g & 3) * 8;
        bf16x8 v1, v2, v3;
        p.loadA3(z, row0 + row, k0, s, v1, v2, v3);
        int byte = row * 80 + k0 * 2;
        *(bf16x8*)((char*)sA1 + byte) = v1;
        *(bf16x8*)((char*)sA2 + byte) = v2;
        *(bf16x8*)((char*)sA3 + byte) = v3;
      }
    }
#pragma unroll
    for (int g0 = 0; g0 < BN * 4; g0 += 256) {
      int g = g0 + tid;
      if (g < BN * 4) {
        int row = g >> 2, k0 = (g & 3) * 8;
        bf16x8 v1, v2, v3;
        p.loadB3(z, col0 + row, k0, s, v1, v2, v3);
        int byte = row * 80 + k0 * 2;
        *(bf16x8*)((char*)sB1 + byte) = v1;
        *(bf16x8*)((char*)sB2 + byte) = v2;
        *(bf16x8*)((char*)sB3 + byte) = v3;
      }
    }
    __syncthreads();
    {
      const int kByte = (lane >> 4) << 4;
      bf16x8 a1[FM], a2[FM], a3[FM], b1[FN], b2[FN], b3[FN];
#pragma unroll
      for (int i = 0; i < FM; i++) {
        int r = wm + i * 16 + (lane & 15);
        int byte = r * 80 + kByte;
        a1[i] = *(const bf16x8*)((const char*)sA1 + byte);
        a2[i] = *(const bf16x8*)((const char*)sA2 + byte);
        a3[i] = *(const bf16x8*)((const char*)sA3 + byte);
      }
#pragma unroll
      for (int j = 0; j < FN; j++) {
        int r = wn + j * 16 + (lane & 15);
        int byte = r * 80 + kByte;
        b1[j] = *(const bf16x8*)((const char*)sB1 + byte);
        b2[j] = *(const bf16x8*)((const char*)sB2 + byte);
        b3[j] = *(const bf16x8*)((const char*)sB3 + byte);
      }
#pragma unroll
      for (int i = 0; i < FM; i++)
#pragma unroll
        for (int j = 0; j < FN; j++) {
          acc[i][j] = __builtin_amdgcn_mfma_f32_16x16x32_bf16(a1[i], b1[j], acc[i][j], 0, 0, 0);
          acc[i][j] = __builtin_amdgcn_mfma_f32_16x16x32_bf16(a1[i], b2[j], acc[i][j], 0, 0, 0);
          acc[i][j] = __builtin_amdgcn_mfma_f32_16x16x32_bf16(a2[i], b1[j], acc[i][j], 0, 0, 0);
          acc[i][j] = __builtin_amdgcn_mfma_f32_16x16x32_bf16(a2[i], b2[j], acc[i][j], 0, 0, 0);
          acc[i][j] = __builtin_amdgcn_mfma_f32_16x16x32_bf16(a1[i], b3[j], acc[i][j], 0, 0, 0);
          acc[i][j] = __builtin_amdgcn_mfma_f32_16x16x32_bf16(a3[i], b1[j], acc[i][j], 0, 0, 0);
        }
    }
    __syncthreads();
  }
#pragma unroll
  for (int i = 0; i < FM; i++)
#pragma unroll
    for (int j = 0; j < FN; j++)
#pragma unroll
      for (int rg = 0; rg < 4; rg++) {
        int r = row0 + wm + i * 16 + ((lane >> 4) << 2) + rg;
        int c = col0 + wn + j * 16 + (lane & 15);
        p.store(z, r, c, acc[i][j][rg]);
      }
}

// ---------------- f64-acc 6-term GEMM (main/corr split, flush 2/8) ----------------
// GMAP 0: row0=by*BM col0=bx*BN.
// GMAP 2: col-tile-major over 188 row-tiles (PCONV): blocks [c*188, c*188+188) cover
//   all rows of col-tile c -> xc stays L3-resident, weights stream once.
template <int TH, int GMAP, int WGM, int WGN, int FM, int FN, class P>
__global__ __launch_bounds__(TH) void gemm6d(P p) {
  constexpr int BM = WGM * FM * 16;
  constexpr int BN = WGN * FN * 16;
  __shared__ bf16 sA1[BM * 40];
  __shared__ bf16 sA2[BM * 40];
  __shared__ bf16 sA3[BM * 40];
  __shared__ bf16 sB1[BN * 40];
  __shared__ bf16 sB2[BN * 40];
  __shared__ bf16 sB3[BN * 40];
  const int tid = threadIdx.x;
  const int z = blockIdx.z;
  int row0, col0;
  if constexpr (GMAP == 2) {
    int id = blockIdx.x;
    row0 = (id % 188) * BM;
    col0 = (id / 188) * BN;
  } else {
    row0 = blockIdx.y * BM;
    col0 = blockIdx.x * BN;
  }
  const int lane = tid & 63;
  const int wv = tid >> 6;
  const int wm = (wv % WGM) * (FM * 16);
  const int wn = (wv / WGM) * (FN * 16);
  double acc[FM][FN][4];
  f32x4 fmn[FM][FN], fcr[FM][FN];
#pragma unroll
  for (int i = 0; i < FM; i++)
#pragma unroll
    for (int j = 0; j < FN; j++)
#pragma unroll
      for (int r = 0; r < 4; r++) {
        acc[i][j][r] = 0.0;
        fmn[i][j][r] = 0.f;
        fcr[i][j][r] = 0.f;
      }

  const int ks = p.ksteps();
  for (int s = 0; s < ks; ++s) {
#pragma unroll
    for (int g0 = 0; g0 < BM * 4; g0 += TH) {
      int g = g0 + tid;
      if (g < BM * 4) {
        int row = g >> 2, k0 = (g & 3) * 8;
        bf16x8 v1, v2, v3;
        p.loadA3(z, row0 + row, k0, s, v1, v2, v3);
        int byte = row * 80 + k0 * 2;
        *(bf16x8*)((char*)sA1 + byte) = v1;
        *(bf16x8*)((char*)sA2 + byte) = v2;
        *(bf16x8*)((char*)sA3 + byte) = v3;
      }
    }
#pragma unroll
    for (int g0 = 0; g0 < BN * 4; g0 += TH) {
      int g = g0 + tid;
      if (g < BN * 4) {
        int row = g >> 2, k0 = (g & 3) * 8;
        bf16x8 v1, v2, v3;
        p.loadB3(z, col0 + row, k0, s, v1, v2, v3);
        int byte = row * 80 + k0 * 2;
        *(bf16x8*)((char*)sB1 + byte) = v1;
        *(bf16x8*)((char*)sB2 + byte) = v2;
        *(bf16x8*)((char*)sB3 + byte) = v3;
      }
    }
    __syncthreads();
    {
      const int kByte = (lane >> 4) << 4;
      bf16x8 a1[FM], a2[FM], a3[FM], b1[FN], b2[FN], b3[FN];
#pragma unroll
      for (int i = 0; i < FM; i++) {
        int r = wm + i * 16 + (lane & 15);
        int byte = r * 80 + kByte;
        a1[i] = *(const bf16x8*)((const char*)sA1 + byte);
        a2[i] = *(const bf16x8*)((const char*)sA2 + byte);
        a3[i] = *(const bf16x8*)((const char*)sA3 + byte);
      }
#pragma unroll
      for (int j = 0; j < FN; j++) {
        int r = wn + j * 16 + (lane & 15);
        int byte = r * 80 + kByte;
        b1[j] = *(const bf16x8*)((const char*)sB1 + byte);
        b2[j] = *(const bf16x8*)((const char*)sB2 + byte);
        b3[j] = *(const bf16x8*)((const char*)sB3 + byte);
      }
#pragma unroll
      for (int i = 0; i < FM; i++)
#pragma unroll
        for (int j = 0; j < FN; j++) {
          fmn[i][j] = __builtin_amdgcn_mfma_f32_16x16x32_bf16(a1[i], b1[j], fmn[i][j], 0, 0, 0);
          fcr[i][j] = __builtin_amdgcn_mfma_f32_16x16x32_bf16(a1[i], b2[j], fcr[i][j], 0, 0, 0);
          fcr[i][j] = __builtin_amdgcn_mfma_f32_16x16x32_bf16(a2[i], b1[j], fcr[i][j], 0, 0, 0);
          fcr[i][j] = __builtin_amdgcn_mfma_f32_16x16x32_bf16(a2[i], b2[j], fcr[i][j], 0, 0, 0);
          fcr[i][j] = __builtin_amdgcn_mfma_f32_16x16x32_bf16(a1[i], b3[j], fcr[i][j], 0, 0, 0);
          fcr[i][j] = __builtin_amdgcn_mfma_f32_16x16x32_bf16(a3[i], b1[j], fcr[i][j], 0, 0, 0);
        }
    }
    bool flm = ((s & 1) == 1) || (s == ks - 1);
    bool flc = ((s & 7) == 7) || (s == ks - 1);
    if (flm) {
#pragma unroll
      for (int i = 0; i < FM; i++)
#pragma unroll
        for (int j = 0; j < FN; j++)
#pragma unroll
          for (int r = 0; r < 4; r++) {
            acc[i][j][r] += (double)fmn[i][j][r];
            fmn[i][j][r] = 0.f;
          }
    }
    if (flc) {
#pragma unroll
      for (int i = 0; i < FM; i++)
#pragma unroll
        for (int j = 0; j < FN; j++)
#pragma unroll
          for (int r = 0; r < 4; r++) {
            acc[i][j][r] += (double)fcr[i][j][r];
            fcr[i][j][r] = 0.f;
          }
    }
    __syncthreads();
  }
#pragma unroll
  for (int i = 0; i < FM; i++)
#pragma unroll
    for (int j = 0; j < FN; j++)
#pragma unroll
      for (int rg = 0; rg < 4; rg++) {
        int r = row0 + wm + i * 16 + ((lane >> 4) << 2) + rg;
        int c = col0 + wn + j * 16 + (lane & 15);
        p.store(z, r, c, acc[i][j][rg]);
      }
}

// ---------------- problem structs ----------------
struct P6PROJ {  // OPRE = x_half @ projT ; M=3000 N=1024 K=1024
  const float* x;
  const bf16 *b1, *b2, *b3;
  float* out;
  int rowoff, colbase;
  __device__ int ksteps() const { return 32; }
  __device__ void loadA3(int, int r, int k0, int s, bf16x8& v1, bf16x8& v2, bf16x8& v3) const {
    v1 = bzero8(); v2 = bzero8(); v3 = bzero8();
    if (r >= RPC) return;
    const float* src = x + (size_t)(rowoff + r) * 2048 + colbase + s * 32 + k0;
#pragma unroll
    for (int j = 0; j < 8; j++) {
      bf3 t = split3(src[j]);
      v1[j] = t.h; v2[j] = t.m; v3[j] = t.l;
    }
  }
  __device__ void loadB3(int, int c, int k0, int s, bf16x8& v1, bf16x8& v2, bf16x8& v3) const {
    size_t a = (size_t)c * 1024 + s * 32 + k0;
    v1 = *(const bf16x8*)(b1 + a); v2 = *(const bf16x8*)(b2 + a); v3 = *(const bf16x8*)(b3 + a);
  }
  __device__ void store(int, int r, int c, double v) const {
    if (r < RPC) out[(size_t)r * 1024 + c] = (float)v;
  }
};

struct P6Q {  // Q = o_rgb @ attwT per local pair ; M=750 N=128 K=128
  const bf16 *a1, *a2, *a3, *b1, *b2, *b3;
  bf16 *q1, *q2, *q3;
  __device__ int ksteps() const { return 4; }
  __device__ void loadA3(int z, int r, int k0, int s, bf16x8& v1, bf16x8& v2, bf16x8& v3) const {
    if (r >= 750) { v1 = bzero8(); v2 = bzero8(); v3 = bzero8(); return; }
    size_t a = (size_t)z * 96000 + (size_t)r * 128 + s * 32 + k0;
    v1 = *(const bf16x8*)(a1 + a); v2 = *(const bf16x8*)(a2 + a); v3 = *(const bf16x8*)(a3 + a);
  }
  __device__ void loadB3(int z, int c, int k0, int s, bf16x8& v1, bf16x8& v2, bf16x8& v3) const {
    size_t a = (size_t)(z & 7) * 16384 + (size_t)c * 128 + s * 32 + k0;
    v1 = *(const bf16x8*)(b1 + a); v2 = *(const bf16x8*)(b2 + a); v3 = *(const bf16x8*)(b3 + a);
  }
  __device__ void store(int z, int r, int c, float v) const {
    if (r >= 750) return;
    size_t a = (size_t)z * 96000 + (size_t)r * 128 + c;
    bf3 t = split3(v);
    q1[a] = t.h; q2[a] = t.m; q3[a] = t.l;
  }
};

struct P6S {  // P = exp(Q @ o_flow^T) per local pair ; M=N=750 K=128
  const bf16 *a1, *a2, *a3, *b1, *b2, *b3;
  float* out;
  __device__ int ksteps() const { return 4; }
  __device__ void loadA3(int z, int r, int k0, int s, bf16x8& v1, bf16x8& v2, bf16x8& v3) const {
    if (r >= 750) { v1 = bzero8(); v2 = bzero8(); v3 = bzero8(); return; }
    size_t a = (size_t)z * 96000 + (size_t)r * 128 + s * 32 + k0;
    v1 = *(const bf16x8*)(a1 + a); v2 = *(const bf16x8*)(a2 + a); v3 = *(const bf16x8*)(a3 + a);
  }
  __device__ void loadB3(int z, int c, int k0, int s, bf16x8& v1, bf16x8& v2, bf16x8& v3) const {
    if (c >= 750) { v1 = bzero8(); v2 = bzero8(); v3 = bzero8(); return; }
    size_t a = (size_t)z * 96000 + (size_t)c * 128 + s * 32 + k0;
    v1 = *(const bf16x8*)(b1 + a); v2 = *(const bf16x8*)(b2 + a); v3 = *(const bf16x8*)(b3 + a);
  }
  __device__ void store(int z, int r, int c, float v) const {
    if (r < 750 && c < 750) out[(size_t)z * SPAIR + (size_t)r * SROW + c] = expf(v);
  }
};

struct P6E {  // xc-half = (P/Z) @ oT^T (both rgb & flow via z), gelu+tanh epilogue
  const float *Pr, *Pt;          // row-softmax P and transposed P
  const float *invr, *invc;
  const bf16 *br1, *br2, *br3;   // OTR planes
  const bf16 *bt1, *bt2, *bt3;   // OTF planes
  const float* x;
  bf16 *xc1, *xc2, *xc3;
  int pairbase;
  __device__ int ksteps() const { return 24; }
  __device__ void loadA3(int z, int r, int k0, int s, bf16x8& v1, bf16x8& v2, bf16x8& v3) const {
    v1 = bzero8(); v2 = bzero8(); v3 = bzero8();
    if (r >= 750) return;
    int zp = z & 31;
    const float* Pm = (z < 32) ? Pr : Pt;
    const float* inv = (z < 32) ? invr : invc;
    int m0 = s * 32 + k0;
    const float* row = Pm + (size_t)zp * SPAIR + (size_t)r * SROW;
    float sc = inv[zp * 750 + r];
#pragma unroll
    for (int j = 0; j < 8; j++) {
      int m = m0 + j;
      if (m < 750) {
        bf3 t = split3(row[m] * sc);
        v1[j] = t.h; v2[j] = t.m; v3[j] = t.l;
      }
    }
  }
  __device__ void loadB3(int z, int c, int k0, int s, bf16x8& v1, bf16x8& v2, bf16x8& v3) const {
    int zp = z & 31;
    size_t a = (size_t)zp * 98304 + (size_t)c * 768 + s * 32 + k0;
    if (z < 32) {
      v1 = *(const bf16x8*)(br1 + a); v2 = *(const bf16x8*)(br2 + a); v3 = *(const bf16x8*)(br3 + a);
    } else {
      v1 = *(const bf16x8*)(bt1 + a); v2 = *(const bf16x8*)(bt2 + a); v3 = *(const bf16x8*)(bt3 + a);
    }
  }
  __device__ void store(int z, int r, int c, float v) const {
    if (r >= 750) return;
    int zp = z & 31;
    int gp = pairbase + zp;
    int hh = gp & 7, n = gp >> 3;
    int xcol = ((z < 32) ? 0 : 1024) + hh * 128 + c;
    float g = 0.5f * v * (1.f + erff(v * 0.70710678118654752f));
    float f = tanhf(g + x[((size_t)n * 750 + r) * 2048 + xcol]);
    size_t a = (size_t)(n * PT + r + 4) * 2048 + xcol;
    bf3 t = split3(f);
    xc1[a] = t.h; xc2[a] = t.m; xc3[a] = t.l;
  }
};

struct P6CONV {  // emb = relu(conv9(xc, W) + b)
  const bf16 *a1, *a2, *a3, *b1, *b2, *b3;
  const float* bias;
  bf16 *o1, *o2, *o3;
  __device__ int ksteps() const { return 576; }
  __device__ void loadA3(int, int r, int k0, int s, bf16x8& v1, bf16x8& v2, bf16x8& v3) const {
    if (r >= MM) { v1 = bzero8(); v2 = bzero8(); v3 = bzero8(); return; }
    int ktap = s >> 6, kb = s & 63;
    int n = (unsigned)r / 750u;
    size_t a = (size_t)(r + 8 * n + ktap) * 2048 + kb * 32 + k0;
    v1 = *(const bf16x8*)(a1 + a); v2 = *(const bf16x8*)(a2 + a); v3 = *(const bf16x8*)(a3 + a);
  }
  __device__ void loadB3(int, int c, int k0, int s, bf16x8& v1, bf16x8& v2, bf16x8& v3) const {
    int ktap = s >> 6, kb = s & 63;
    size_t a = ((size_t)(ktap * 2048 + c)) * 2048 + kb * 32 + k0;
    v1 = *(const bf16x8*)(b1 + a); v2 = *(const bf16x8*)(b2 + a); v3 = *(const bf16x8*)(b3 + a);
  }
  __device__ void store(int, int r, int c, double v) const {
    if (r >= MM) return;
    v += (double)bias[c];
    if (v < 0) v = 0;
    int n = (unsigned)r / 750u;
    size_t a = (size_t)(r + 8 * n + 4) * 2048 + c;
    bf3 t = split3((float)v);
    o1[a] = t.h; o2[a] = t.m; o3[a] = t.l;
  }
};

struct P6CLS1 {  // cas1 = conv9(emb, cls1_w), N=32 (20 used)
  const bf16 *a1, *a2, *a3, *b1, *b2, *b3;
  float* out;
  __device__ int ksteps() const { return 576; }
  __device__ void loadA3(int, int r, int k0, int s, bf16x8& v1, bf16x8& v2, bf16x8& v3) const {
    if (r >= MM) { v1 = bzero8(); v2 = bzero8(); v3 = bzero8(); return; }
    int ktap = s >> 6, kb = s & 63;
    int n = (unsigned)r / 750u;
    size_t a = (size_t)(r + 8 * n + ktap) * 2048 + kb * 32 + k0;
    v1 = *(const bf16x8*)(a1 + a); v2 = *(const bf16x8*)(a2 + a); v3 = *(const bf16x8*)(a3 + a);
  }
  __device__ void loadB3(int, int c, int k0, int s, bf16x8& v1, bf16x8& v2, bf16x8& v3) const {
    int ktap = s >> 6, kb = s & 63;
    size_t a = ((size_t)(ktap * 32 + c)) * 2048 + kb * 32 + k0;
    v1 = *(const bf16x8*)(b1 + a); v2 = *(const bf16x8*)(b2 + a); v3 = *(const bf16x8*)(b3 + a);
  }
  __device__ void store(int, int r, int c, double v) const {
    if (r < MM && c < NC) out[(size_t)r * NC + c] = (float)v;
  }
};

// ---------------- misc kernels ----------------
__global__ void k_split_projT3(const float* rgbp, const float* flowp, bf16* r1, bf16* r2, bf16* r3,
                               bf16* f1, bf16* f2, bf16* f3) {
  int bx = blockIdx.x;
  int st = bx >> 10, c = bx & 1023;
  int h = c >> 7, e = c & 127;
  const float* src = st ? flowp : rgbp;
  bf16* o1 = st ? f1 : r1;
  bf16* o2 = st ? f2 : r2;
  bf16* o3 = st ? f3 : r3;
  int d0 = threadIdx.x * 4;
  bf16x4 a, b, cc;
#pragma unroll
  for (int j = 0; j < 4; j++) {
    bf3 t = split3(src[(size_t)h * 131072 + (size_t)(d0 + j) * 128 + e]);
    a[j] = t.h; b[j] = t.m; cc[j] = t.l;
  }
  size_t o = (size_t)c * 1024 + d0;
  *(bf16x4*)(o1 + o) = a;
  *(bf16x4*)(o2 + o) = b;
  *(bf16x4*)(o3 + o) = cc;
}

__global__ void k_split_attewT3(const float* aw, bf16* w1, bf16* w2, bf16* w3) {
  int b = blockIdx.x;
  int h = b >> 7, f = b & 127;
  int e = threadIdx.x;
  bf3 t = split3(aw[(size_t)h * 16384 + (size_t)e * 128 + f]);
  size_t a = (size_t)h * 16384 + (size_t)f * 128 + e;
  w1[a] = t.h; w2[a] = t.m; w3[a] = t.l;
}

__global__ void k_split_wt3(const float* ew, bf16* w1, bf16* w2, bf16* w3) {
  __shared__ float tmp[1152];
  int o = blockIdx.x >> 4, ic0 = (blockIdx.x & 15) << 7;
  for (int t = threadIdx.x; t < 1152; t += 256)
    tmp[t] = ew[(size_t)o * 18432 + (size_t)ic0 * 9 + t];
  __syncthreads();
  for (int w = threadIdx.x; w < 1152; w += 256) {
    int k = w >> 7, i = w & 127;
    bf3 t = split3(tmp[i * 9 + k]);
    size_t a = ((size_t)(k * 2048 + o)) * 2048 + ic0 + i;
    w1[a] = t.h; w2[a] = t.m; w3[a] = t.l;
  }
}

__global__ void k_split_wc3(const float* cw, bf16* w1, bf16* w2, bf16* w3) {
  int k = blockIdx.x / 32, c = blockIdx.x % 32;
  for (int i = threadIdx.x; i < 2048; i += 256) {
    float v = (c < NC) ? cw[(size_t)c * 18432 + (size_t)i * 9 + k] : 0.f;
    bf3 t = split3(v);
    size_t a = ((size_t)(k * 32 + c)) * 2048 + i;
    w1[a] = t.h; w2[a] = t.m; w3[a] = t.l;
  }
}

__global__ void k_norm3(const float* opre, bf16* o1, bf16* o2, bf16* o3) {
  int r = blockIdx.x;  // 0..2999 local
  int head = threadIdx.x >> 5, ln = threadIdx.x & 31;
  const float* src = opre + (size_t)r * 1024 + head * 128 + ln * 4;
  float4 v = *(const float4*)src;
  double ss = (double)v.x * v.x + (double)v.y * v.y + (double)v.z * v.z + (double)v.w * v.w;
  for (int k = 16; k; k >>= 1) ss += __shfl_xor(ss, k, 32);
  double rn = 1.0 / fmax(sqrt(ss), 1e-12);
  int nl = r / 750, l = r % 750;
  int zp = nl * 8 + head;
  size_t o = (size_t)zp * 96000 + (size_t)l * 128 + ln * 4;
  float vv[4] = {v.x, v.y, v.z, v.w};
  bf16x4 h4, m4, l4;
#pragma unroll
  for (int j = 0; j < 4; j++) {
    bf3 t = split3((float)((double)vv[j] * rn));
    h4[j] = t.h; m4[j] = t.m; l4[j] = t.l;
  }
  *(bf16x4*)(o1 + o) = h4;
  *(bf16x4*)(o2 + o) = m4;
  *(bf16x4*)(o3 + o) = l4;
}

__global__ void k_trans3(const bf16* i1, const bf16* i2, const bf16* i3, bf16* o1, bf16* o2,
                         bf16* o3) {
  __shared__ bf16 t1[32][33], t2[32][33], t3[32][33];
  int zp = blockIdx.y;
  int lt = blockIdx.x >> 2, et = blockIdx.x & 3;
  int tx = threadIdx.x & 31, ty = threadIdx.x >> 5;
#pragma unroll
  for (int p = 0; p < 4; p++) {
    int lrow = lt * 32 + ty + p * 8;
    int e = et * 32 + tx;
    bf16 a = (bf16)0.f, b = (bf16)0.f, c = (bf16)0.f;
    if (lrow < 750) {
      size_t ad = (size_t)zp * 96000 + (size_t)lrow * 128 + e;
      a = i1[ad]; b = i2[ad]; c = i3[ad];
    }
    t1[ty + p * 8][tx] = a;
    t2[ty + p * 8][tx] = b;
    t3[ty + p * 8][tx] = c;
  }
  __syncthreads();
#pragma unroll
  for (int p = 0; p < 4; p++) {
    int e = et * 32 + ty + p * 8;
    int l2 = lt * 32 + tx;
    size_t ad = (size_t)zp * 98304 + (size_t)e * 768 + l2;
    o1[ad] = t1[tx][ty + p * 8];
    o2[ad] = t2[tx][ty + p * 8];
    o3[ad] = t3[tx][ty + p * 8];
  }
}

__global__ void k_transS(const float* S, float* ST) {
  __shared__ float t[32][33];
  int zp = blockIdx.y;
  int tr = (blockIdx.x / 24) * 32, tc = (blockIdx.x % 24) * 32;
  int tx = threadIdx.x & 31, ty = threadIdx.x >> 5;
#pragma unroll
  for (int p = 0; p < 4; p++) {
    int rr = tr + ty + p * 8, cc = tc + tx;
    t[ty + p * 8][tx] = (rr < 750 && cc < 750) ? S[(size_t)zp * SPAIR + (size_t)rr * SROW + cc] : 0.f;
  }
  __syncthreads();
#pragma unroll
  for (int p = 0; p < 4; p++) {
    int cc = tc + ty + p * 8, rr = tr + tx;
    if (cc < 750 && rr < 750) ST[(size_t)zp * SPAIR + (size_t)cc * SROW + rr] = t[tx][ty + p * 8];
  }
}

__global__ void k_statsd(const float* P, float* inv) {
  int b = blockIdx.x;
  int p = b / 94, r0 = (b % 94) * 8;
  int g = threadIdx.x >> 5, ln = threadIdx.x & 31;
  int r = r0 + g;
  if (r >= 750) return;
  const float* row = P + (size_t)p * SPAIR + (size_t)r * SROW;
  double s = 0.0;
  for (int m = ln; m < 750; m += 32) s += (double)row[m];
  for (int k = 16; k; k >>= 1) s += __shfl_xor(s, k, 32);
  if (ln == 0) inv[p * 750 + r] = (float)(1.0 / s);
}

__global__ void k_cls2(const float* cas1, const float* w2, float* cas_out, float* cast) {
  int idx = blockIdx.x * 256 + threadIdx.x;
  if (idx >= MM * NC) return;
  int r = idx / NC, c = idx % NC;
  int n = r / 750, t = r % 750;
  double a = 0.0;
#pragma unroll
  for (int j = 0; j < 7; j++) {
    int tt = t + 2 * j - 6;
    if (tt >= 0 && tt < 750)
      a += (double)w2[c * 7 + j] * (double)cas1[((size_t)n * 750 + tt) * NC + c];
  }
  if (a < 0) a = 0;
  cas_out[idx] = (float)a;
  cast[((size_t)n * NC + c) * 750 + t] = (float)a;
}

__global__ void k_act(const float* cas, float* act, float* out_act) {
  int r = blockIdx.x * 256 + threadIdx.x;
  if (r >= MM) return;
  double s = 0.0;
#pragma unroll
  for (int c = 0; c < NC; c++) s += (double)cas[(size_t)r * NC + c];
  act[r] = (float)s;
  out_act[r] = (float)s;
}

__global__ __launch_bounds__(512) void k_mask(const float* act, float* arev, float* inner,
                                              float* outer) {
  __shared__ u64 ks[1024];
  __shared__ float av[768];
  __shared__ float bb[768];
  int n = blockIdx.x;
  for (int i = threadIdx.x; i < 1024; i += 512) {
    if (i < 750) {
      float v = act[n * 750 + i];
      av[i] = v;
      ks[i] = ((u64)asc_enc(v) << 32) | (u32)i;
    } else
      ks[i] = ~0ull;
  }
  bsort1024(ks);
  float med = 0.5f * (asc_dec((u32)(ks[374] >> 32)) + asc_dec((u32)(ks[375] >> 32)));
  float amax = asc_dec((u32)(ks[749] >> 32));
  for (int t = threadIdx.x; t < 750; t += 512) bb[t] = (av[t] > med) ? 1.f : 0.f;
  __syncthreads();
  for (int t = threadIdx.x; t < 750; t += 512) {
    float e3 = 1.f, e6 = 1.f, d3 = 0.f, d6 = 0.f;
    for (int j = t - 1; j <= t + 1; ++j) {
      float v = (j >= 0 && j < 750) ? bb[j] : 0.f;
      e3 = fminf(e3, v); d3 = fmaxf(d3, v);
    }
    for (int j = t - 3; j <= t + 2; ++j) {
      float v = (j >= 0 && j < 750) ? bb[j] : 0.f;
      e6 = fminf(e6, v);
    }
    for (int j = t - 2; j <= t + 3; ++j) {
      float v = (j >= 0 && j < 750) ? bb[j] : 0.f;
      d6 = fmaxf(d6, v);
    }
    int g = n * 750 + t;
    inner[g] = (e3 - e6 > 0.5f) ? av[t] : 0.f;
    outer[g] = (d6 - d3 > 0.5f) ? av[t] : 0.f;
    arev[g] = amax - av[t];
  }
}

__global__ __launch_bounds__(512) void k_topk(const float* act, const float* arev,
                                              const float* inner, const float* outer, int* idxb) {
  __shared__ u64 ks[1024];
  int n = blockIdx.x >> 2, w = blockIdx.x & 3;
  const float* src = (w == 0) ? act : ((w == 1) ? arev : ((w == 2) ? inner : outer));
  int K = (w < 2) ? KE : KH;
  int off = (w == 0) ? 0 : ((w == 1) ? 150 : ((w == 2) ? 300 : 337));
  for (int i = threadIdx.x; i < 1024; i += 512) {
    if (i < 750) {
      u32 d = ~asc_enc(src[n * 750 + i]);
      ks[i] = ((u64)d << 32) | (u32)i;
    } else
      ks[i] = ~0ull;
  }
  bsort1024(ks);
  for (int i = threadIdx.x; i < K; i += 512) idxb[n * 374 + off + i] = (int)(ks[i] & 0xFFFFFFFFu);
}

__global__ __launch_bounds__(512) void k_topcas(const float* cast, float* smean) {
  __shared__ u64 ks[1024];
  __shared__ float red[512];
  int b = blockIdx.x;
  for (int i = threadIdx.x; i < 1024; i += 512) {
    if (i < 750) {
      u32 d = ~asc_enc(cast[(size_t)b * 750 + i]);
      ks[i] = ((u64)d << 32) | (u32)i;
    } else
      ks[i] = ~0ull;
  }
  bsort1024(ks);
  float s = 0.f;
  for (int i = threadIdx.x; i < KE; i += 512) s += asc_dec(~(u32)(ks[i] >> 32));
  red[threadIdx.x] = s;
  __syncthreads();
  for (int st = 256; st; st >>= 1) {
    if (threadIdx.x < st) red[threadIdx.x] += red[threadIdx.x + st];
    __syncthreads();
  }
  if (threadIdx.x == 0) smean[b] = red[0] / 150.f;
}

__global__ void k_gather(const int* idxb, const bf16* e1, const bf16* e2, const bf16* e3,
                         float* dout) {
  int b = blockIdx.x;
  int n = b / 374, j = b % 374;
  size_t obase;
  if (j < 150) obase = OUT_EA + ((size_t)n * KE + j) * 2048;
  else if (j < 300) obase = OUT_EB + ((size_t)n * KE + (j - 150)) * 2048;
  else if (j < 337) obase = OUT_HA + ((size_t)n * KH + (j - 300)) * 2048;
  else obase = OUT_HB + ((size_t)n * KH + (j - 337)) * 2048;
  int t = idxb[n * 374 + j];
  size_t irow = (size_t)(n * PT + t + 4) * 2048;
#pragma unroll
  for (int p = 0; p < 8; p++) {
    int c = threadIdx.x + p * 256;
    dout[obase + c] = (float)e1[irow + c] + (float)e2[irow + c] + (float)e3[irow + c];
  }
}

__global__ void k_vs(const float* smean, float* dout) {
  int n = blockIdx.x;
  int c = threadIdx.x;
  float v = (c < NC) ? smean[n * NC + c] : -3.4e38f;
  float m = v;
  for (int s = 32; s; s >>= 1) m = fmaxf(m, __shfl_xor(m, s));
  float e = (c < NC) ? expf(v - m) : 0.f;
  float sum = e;
  for (int s = 32; s; s >>= 1) sum += __shfl_xor(sum, s);
  if (c < NC) dout[n * NC + c] = e / sum;
}

// ---------------- host ----------------
extern "C" void kernel_launch(void* const* d_in, const int* in_sizes, int n_in, void* d_out,
                              int out_size, void* d_ws, size_t ws_size, hipStream_t stream) {
  const float* x = (const float*)d_in[0];
  const float* rgbp = (const float*)d_in[1];
  const float* flowp = (const float*)d_in[2];
  const float* attw = (const float*)d_in[3];
  const float* embw = (const float*)d_in[4];
  const float* embb = (const float*)d_in[5];
  const float* c1w = (const float*)d_in[6];
  const float* c2w = (const float*)d_in[7];
  float* dout = (float*)d_out;
  char* ws = (char*)d_ws;

  if (ws_size < WS_NEED) {
    fprintf(stderr, "[CoLA] FATAL ws_size=%zu < need=%zu\n", ws_size, (size_t)WS_NEED);
    return;
  }

  bf16* XC1 = (bf16*)(ws + O_XC1);
  bf16* XC2 = (bf16*)(ws + O_XC2);
  bf16* XC3 = (bf16*)(ws + O_XC3);
  bf16* EM1 = (bf16*)(ws + O_EM1);
  bf16* EM2 = (bf16*)(ws + O_EM2);
  bf16* EM3 = (bf16*)(ws + O_EM3);
  float* CAS1 = (float*)(ws + O_CAS1);
  float* CAST = (float*)(ws + O_CAST);
  float* ACT = (float*)(ws + O_ACT);
  float* AREV = (float*)(ws + O_AREV);
  float* INNER = (float*)(ws + O_INNER);
  float* OUTER = (float*)(ws + O_OUTER);
  float* SMEAN = (float*)(ws + O_SMEAN);
  int* IDX = (int*)(ws + O_IDX);
  float* RSINV = (float*)(ws + O_RSINV);
  float* CSINV = (float*)(ws + O_CSINV);
  float* SBUF = (float*)(ws + O_S);
  float* STBUF = (float*)(ws + O_ST);
  bf16 *Q1 = (bf16*)(ws + O_Q1), *Q2 = (bf16*)(ws + O_Q2), *Q3 = (bf16*)(ws + O_Q3);
  bf16 *OR1 = (bf16*)(ws + O_OR1), *OR2 = (bf16*)(ws + O_OR2), *OR3 = (bf16*)(ws + O_OR3);
  bf16 *OF1 = (bf16*)(ws + O_OF1), *OF2 = (bf16*)(ws + O_OF2), *OF3 = (bf16*)(ws + O_OF3);
  bf16 *OTR1 = (bf16*)(ws + O_OTR1), *OTR2 = (bf16*)(ws + O_OTR2), *OTR3 = (bf16*)(ws + O_OTR3);
  bf16 *OTF1 = (bf16*)(ws + O_OTF1), *OTF2 = (bf16*)(ws + O_OTF2), *OTF3 = (bf16*)(ws + O_OTF3);
  float* OPRE = (float*)(ws + O_OPRE);
  bf16 *PR1 = (bf16*)(ws + O_PR1), *PR2 = (bf16*)(ws + O_PR2), *PR3 = (bf16*)(ws + O_PR3);
  bf16 *PF1 = (bf16*)(ws + O_PF1), *PF2 = (bf16*)(ws + O_PF2), *PF3 = (bf16*)(ws + O_PF3);
  bf16 *AW1 = (bf16*)(ws + O_AW1), *AW2 = (bf16*)(ws + O_AW2), *AW3 = (bf16*)(ws + O_AW3);
  bf16 *WT1 = (bf16*)(ws + O_WT1), *WT2 = (bf16*)(ws + O_WT2), *WT3 = (bf16*)(ws + O_WT3);
  bf16 *WC1 = (bf16*)(ws + O_WC1), *WC2 = (bf16*)(ws + O_WC2), *WC3 = (bf16*)(ws + O_WC3);

  (void)hipMemsetAsync(ws, 0, O_CAS1, stream);  // zero 6 padded planes

  k_split_projT3<<<2048, 256, 0, stream>>>(rgbp, flowp, PR1, PR2, PR3, PF1, PF2, PF3);
  k_split_attewT3<<<1024, 128, 0, stream>>>(attw, AW1, AW2, AW3);

  for (int cb = 0; cb < NCHUNK; cb++) {
    int rowoff = cb * RPC;
    int pb = cb * PCH;
    // rgb: proj -> norm -> trans -> q
    {
      P6PROJ p{x, PR1, PR2, PR3, OPRE, rowoff, 0};
      gemm6d<256, 0, 1, 4, 4, 2, P6PROJ><<<dim3(8, 47, 1), 256, 0, stream>>>(p);
    }
    k_norm3<<<RPC, 256, 0, stream>>>(OPRE, OR1, OR2, OR3);
    k_trans3<<<dim3(96, 32), 256, 0, stream>>>(OR1, OR2, OR3, OTR1, OTR2, OTR3);
    {
      P6Q p{OR1, OR2, OR3, AW1, AW2, AW3, Q1, Q2, Q3};
      gemm6<2, 2, 4, 4, P6Q><<<dim3(1, 6, PCH), 256, 0, stream>>>(p);
    }
    // flow: proj -> norm -> trans
    {
      P6PROJ p{x, PF1, PF2, PF3, OPRE, rowoff, 1024};
      gemm6d<256, 0, 1, 4, 4, 2, P6PROJ><<<dim3(8, 47, 1), 256, 0, stream>>>(p);
    }
    k_norm3<<<RPC, 256, 0, stream>>>(OPRE, OF1, OF2, OF3);
    k_trans3<<<dim3(96, 32), 256, 0, stream>>>(OF1, OF2, OF3, OTF1, OTF2, OTF3);
    // P = exp(S), transpose, softmax denominators, fused e-GEMMs (rgb+flow in one)
    {
      P6S p{Q1, Q2, Q3, OF1, OF2, OF3, SBUF};
      gemm6<2, 2, 4, 4, P6S><<<dim3(6, 6, PCH), 256, 0, stream>>>(p);
    }
    k_transS<<<dim3(576, PCH), 256, 0, stream>>>(SBUF, STBUF);
    k_statsd<<<PCH * 94, 256, 0, stream>>>(SBUF, RSINV);
    k_statsd<<<PCH * 94, 256, 0, stream>>>(STBUF, CSINV);
    {
      P6E p{SBUF, STBUF, RSINV, CSINV, OTR1, OTR2, OTR3, OTF1, OTF2, OTF3, x, XC1, XC2, XC3, pb};
      gemm6<2, 2, 4, 4, P6E><<<dim3(1, 6, 2 * PCH), 256, 0, stream>>>(p);
    }
  }

  // conv weights (alias dead attention arena), conv GEMMs
  k_split_wt3<<<32768, 256, 0, stream>>>(embw, WT1, WT2, WT3);
  k_split_wc3<<<288, 256, 0, stream>>>(c1w, WC1, WC2, WC3);
  {
    // col-tile-major (GMAP=2): xc L3-resident, WT streamed once; 3 blocks/CU
    P6CONV p{XC1, XC2, XC3, WT1, WT2, WT3, embb, EM1, EM2, EM3};
    gemm6d<256, 2, 1, 4, 4, 2, P6CONV><<<dim3(188 * 16, 1, 1), 256, 0, stream>>>(p);
  }
  {
    P6CLS1 p{EM1, EM2, EM3, WC1, WC2, WC3, CAS1};
    gemm6d<256, 0, 4, 1, 2, 2, P6CLS1><<<dim3(1, 94, 1), 256, 0, stream>>>(p);
  }
  k_cls2<<<(MM * NC + 255) / 256, 256, 0, stream>>>(CAS1, c2w, dout + OUT_CAS, CAST);
  k_act<<<(MM + 255) / 256, 256, 0, stream>>>(dout + OUT_CAS, ACT, dout + OUT_ACT);

  // postprocess
  k_mask<<<16, 512, 0, stream>>>(ACT, AREV, INNER, OUTER);
  k_topk<<<64, 512, 0, stream>>>(ACT, AREV, INNER, OUTER, IDX);
  k_topcas<<<320, 512, 0, stream>>>(CAST, SMEAN);
  k_gather<<<16 * 374, 256, 0, stream>>>(IDX, EM1, EM2, EM3, dout);
  k_vs<<<16, 64, 0, stream>>>(SMEAN, dout);
}

// Round 10
// 9192.052 us; speedup vs baseline: 1.3787x; 1.3787x over previous
//
#include <hip/hip_runtime.h>
#include <cstdio>
#include <cstdint>

typedef __bf16 bf16;
typedef __attribute__((ext_vector_type(8))) __bf16 bf16x8;
typedef __attribute__((ext_vector_type(4))) __bf16 bf16x4;
typedef __attribute__((ext_vector_type(4))) float f32x4;
typedef unsigned long long u64;
typedef unsigned int u32;

// ---------------- problem dims ----------------
constexpr int BATCH = 16, TT = 750, DD = 2048, NC = 20;
constexpr int MM = 12000;
constexpr int PT = 758;            // padded T (4+750+4)
constexpr int PCH = 32;            // pairs per chunk (4 batches x 8 heads)
constexpr int NCHUNK = 4;
constexpr int RPC = 3000;          // x rows per chunk
constexpr int SROW = 752;
constexpr int SPAIR = 750 * SROW;  // 564000
constexpr int KE = 150, KH = 37;

// ---------------- output offsets (floats) ----------------
constexpr size_t OUT_EA  = 320;
constexpr size_t OUT_EB  = OUT_EA + (size_t)BATCH * KE * DD;
constexpr size_t OUT_HA  = OUT_EB + (size_t)BATCH * KE * DD;
constexpr size_t OUT_HB  = OUT_HA + (size_t)BATCH * KH * DD;
constexpr size_t OUT_ACT = OUT_HB + (size_t)BATCH * KH * DD;
constexpr size_t OUT_CAS = OUT_ACT + MM;

// ---------------- workspace (bytes) ----------------
constexpr size_t XCB = (size_t)(BATCH * PT) * DD * 2;   // 49,676,288
constexpr size_t O_XC1   = 0;
constexpr size_t O_XC2   = O_XC1 + XCB;
constexpr size_t O_XC3   = O_XC2 + XCB;
constexpr size_t O_EM1   = O_XC3 + XCB;
constexpr size_t O_EM2   = O_EM1 + XCB;
constexpr size_t O_EM3   = O_EM2 + XCB;
constexpr size_t O_CAS1  = O_EM3 + XCB;                  // 298,057,728
constexpr size_t O_CAST  = O_CAS1 + 960000;
constexpr size_t O_ACT   = O_CAST + 960000;
constexpr size_t O_AREV  = O_ACT + 48000;
constexpr size_t O_INNER = O_AREV + 48000;
constexpr size_t O_OUTER = O_INNER + 48000;
constexpr size_t O_SMEAN = O_OUTER + 48000;
constexpr size_t O_IDX   = O_SMEAN + 1280;
constexpr size_t O_RSINV = O_IDX + 23936;
constexpr size_t O_CSINV = O_RSINV + 96000;
constexpr size_t O_DBG   = O_CSINV + 96000;
constexpr size_t AR      = O_DBG + 256;                  // 300,387,200

constexpr size_t SB   = (size_t)PCH * SPAIR * 4;         // 72,192,000
constexpr size_t PL   = (size_t)PCH * 750 * 128 * 2;     // 6,144,000  o plane
constexpr size_t TPL  = (size_t)PCH * 128 * 768 * 2;     // 6,291,456  oT plane
constexpr size_t O_S    = AR;
constexpr size_t O_ST   = O_S + SB;
constexpr size_t O_Q1   = O_ST + SB;
constexpr size_t O_Q2   = O_Q1 + PL;
constexpr size_t O_Q3   = O_Q2 + PL;
constexpr size_t O_OR1  = O_Q3 + PL;
constexpr size_t O_OR2  = O_OR1 + PL;
constexpr size_t O_OR3  = O_OR2 + PL;
constexpr size_t O_OF1  = O_OR3 + PL;
constexpr size_t O_OF2  = O_OF1 + PL;
constexpr size_t O_OF3  = O_OF2 + PL;
constexpr size_t O_OTR1 = O_OF3 + PL;
constexpr size_t O_OTR2 = O_OTR1 + TPL;
constexpr size_t O_OTR3 = O_OTR2 + TPL;
constexpr size_t O_OTF1 = O_OTR3 + TPL;
constexpr size_t O_OTF2 = O_OTF1 + TPL;
constexpr size_t O_OTF3 = O_OTF2 + TPL;
constexpr size_t O_OPRE = O_OTF3 + TPL;                  // RPC*1024*4
constexpr size_t PRP  = (size_t)1024 * 1024 * 2;
constexpr size_t O_PR1  = O_OPRE + (size_t)RPC * 1024 * 4;
constexpr size_t O_PR2  = O_PR1 + PRP;
constexpr size_t O_PR3  = O_PR2 + PRP;
constexpr size_t O_PF1  = O_PR3 + PRP;
constexpr size_t O_PF2  = O_PF1 + PRP;
constexpr size_t O_PF3  = O_PF2 + PRP;
constexpr size_t AWP  = (size_t)8 * 128 * 128 * 2;
constexpr size_t O_AW1  = O_PF3 + PRP;
constexpr size_t O_AW2  = O_AW1 + AWP;
constexpr size_t O_AW3  = O_AW2 + AWP;
constexpr size_t WS_NEED = O_AW3 + AWP;                  // 563,473,280

// conv weights alias dead attention arena
constexpr size_t WTP  = (size_t)9 * 2048 * 2048 * 2;     // 75,497,472
constexpr size_t O_WT1  = AR;
constexpr size_t O_WT2  = O_WT1 + WTP;
constexpr size_t O_WT3  = O_WT2 + WTP;
constexpr size_t WCP  = (size_t)9 * 32 * 2048 * 2;
constexpr size_t O_WC1  = O_WT3 + WTP;
constexpr size_t O_WC2  = O_WC1 + WCP;
constexpr size_t O_WC3  = O_WC2 + WCP;

static_assert(O_WC3 + WCP <= WS_NEED, "WT/WC overrun");
static_assert(WS_NEED <= 603979776, "exceeds harness ws");

// ---------------- helpers ----------------
struct bf3 { bf16 h, m, l; };
static __device__ __forceinline__ bf3 split3(float v) {
  bf3 r;
  r.h = (bf16)v;
  float rem = v - (float)r.h;
  r.m = (bf16)rem;
  r.l = (bf16)(rem - (float)r.m);
  return r;
}
static __device__ __forceinline__ bf16x8 bzero8() {
  bf16x8 v;
#pragma unroll
  for (int i = 0; i < 8; i++) v[i] = (bf16)0.f;
  return v;
}
static __device__ __forceinline__ u32 asc_enc(float f) {
  u32 u = __float_as_uint(f);
  return (u & 0x80000000u) ? ~u : (u | 0x80000000u);
}
static __device__ __forceinline__ float asc_dec(u32 a) {
  u32 u = (a & 0x80000000u) ? (a ^ 0x80000000u) : ~a;
  return __uint_as_float(u);
}
static __device__ void bsort1024(u64* ks) {
  const int tid = threadIdx.x;
  for (int kk = 2; kk <= 1024; kk <<= 1) {
    for (int j = kk >> 1; j > 0; j >>= 1) {
      __syncthreads();
      for (int i = tid; i < 1024; i += 512) {
        int ixj = i ^ j;
        if (ixj > i) {
          u64 a = ks[i], b = ks[ixj];
          bool up = ((i & kk) == 0);
          if ((a > b) == up) { ks[i] = b; ks[ixj] = a; }
        }
      }
    }
  }
  __syncthreads();
}

// LDS layout: padded 80-byte rows (40 bf16), no XOR. Bank period 8 -> 2-way (free).
// ---------------- f32-acc 6-term GEMM (3-plane operands, BK=32) ----------------
template <int WGM, int WGN, int FM, int FN, class P>
__global__ __launch_bounds__(256) void gemm6(P p) {
  constexpr int BM = WGM * FM * 16;
  constexpr int BN = WGN * FN * 16;
  __shared__ bf16 sA1[BM * 40];
  __shared__ bf16 sA2[BM * 40];
  __shared__ bf16 sA3[BM * 40];
  __shared__ bf16 sB1[BN * 40];
  __shared__ bf16 sB2[BN * 40];
  __shared__ bf16 sB3[BN * 40];
  const int tid = threadIdx.x;
  const int z = blockIdx.z;
  const int row0 = blockIdx.y * BM;
  const int col0 = blockIdx.x * BN;
  const int lane = tid & 63;
  const int wv = tid >> 6;
  const int wm = (wv % WGM) * (FM * 16);
  const int wn = (wv / WGM) * (FN * 16);
  f32x4 acc[FM][FN];
#pragma unroll
  for (int i = 0; i < FM; i++)
#pragma unroll
    for (int j = 0; j < FN; j++)
#pragma unroll
      for (int r = 0; r < 4; r++) acc[i][j][r] = 0.f;

  const int ks = p.ksteps();
  for (int s = 0; s < ks; ++s) {
#pragma unroll
    for (int g0 = 0; g0 < BM * 4; g0 += 256) {
      int g = g0 + tid;
      if (g < BM * 4) {
        int row = g >> 2, k0 = (g & 3) * 8;
        bf16x8 v1, v2, v3;
        p.loadA3(z, row0 + row, k0, s, v1, v2, v3);
        int byte = row * 80 + k0 * 2;
        *(bf16x8*)((char*)sA1 + byte) = v1;
        *(bf16x8*)((char*)sA2 + byte) = v2;
        *(bf16x8*)((char*)sA3 + byte) = v3;
      }
    }
#pragma unroll
    for (int g0 = 0; g0 < BN * 4; g0 += 256) {
      int g = g0 + tid;
      if (g < BN * 4) {
        int row = g >> 2, k0 = (g & 3) * 8;
        bf16x8 v1, v2, v3;
        p.loadB3(z, col0 + row, k0, s, v1, v2, v3);
        int byte = row * 80 + k0 * 2;
        *(bf16x8*)((char*)sB1 + byte) = v1;
        *(bf16x8*)((char*)sB2 + byte) = v2;
        *(bf16x8*)((char*)sB3 + byte) = v3;
      }
    }
    __syncthreads();
    {
      const int kByte = (lane >> 4) << 4;
      bf16x8 a1[FM], a2[FM], a3[FM], b1[FN], b2[FN], b3[FN];
#pragma unroll
      for (int i = 0; i < FM; i++) {
        int r = wm + i * 16 + (lane & 15);
        int byte = r * 80 + kByte;
        a1[i] = *(const bf16x8*)((const char*)sA1 + byte);
        a2[i] = *(const bf16x8*)((const char*)sA2 + byte);
        a3[i] = *(const bf16x8*)((const char*)sA3 + byte);
      }
#pragma unroll
      for (int j = 0; j < FN; j++) {
        int r = wn + j * 16 + (lane & 15);
        int byte = r * 80 + kByte;
        b1[j] = *(const bf16x8*)((const char*)sB1 + byte);
        b2[j] = *(const bf16x8*)((const char*)sB2 + byte);
        b3[j] = *(const bf16x8*)((const char*)sB3 + byte);
      }
#pragma unroll
      for (int i = 0; i < FM; i++)
#pragma unroll
        for (int j = 0; j < FN; j++) {
          acc[i][j] = __builtin_amdgcn_mfma_f32_16x16x32_bf16(a1[i], b1[j], acc[i][j], 0, 0, 0);
          acc[i][j] = __builtin_amdgcn_mfma_f32_16x16x32_bf16(a1[i], b2[j], acc[i][j], 0, 0, 0);
          acc[i][j] = __builtin_amdgcn_mfma_f32_16x16x32_bf16(a2[i], b1[j], acc[i][j], 0, 0, 0);
          acc[i][j] = __builtin_amdgcn_mfma_f32_16x16x32_bf16(a2[i], b2[j], acc[i][j], 0, 0, 0);
          acc[i][j] = __builtin_amdgcn_mfma_f32_16x16x32_bf16(a1[i], b3[j], acc[i][j], 0, 0, 0);
          acc[i][j] = __builtin_amdgcn_mfma_f32_16x16x32_bf16(a3[i], b1[j], acc[i][j], 0, 0, 0);
        }
    }
    __syncthreads();
  }
#pragma unroll
  for (int i = 0; i < FM; i++)
#pragma unroll
    for (int j = 0; j < FN; j++)
#pragma unroll
      for (int rg = 0; rg < 4; rg++) {
        int r = row0 + wm + i * 16 + ((lane >> 4) << 2) + rg;
        int c = col0 + wn + j * 16 + (lane & 15);
        p.store(z, r, c, acc[i][j][rg]);
      }
}

// ---------------- f64-acc 6-term GEMM, reg-prefetch pipelined ----------------
// T14-style: issue global loads for step s+1 into registers right after the
// barrier, so HBM latency hides under step s's ds_read+MFMA. Single LDS buffer,
// two barriers per step (same as before). Numerics identical.
template <int TH, int WGM, int WGN, int FM, int FN, class P>
__global__ __launch_bounds__(TH) void gemm6d(P p) {
  constexpr int BM = WGM * FM * 16;
  constexpr int BN = WGN * FN * 16;
  constexpr int NA = (BM * 4 + TH - 1) / TH;
  constexpr int NB = (BN * 4 + TH - 1) / TH;
  __shared__ bf16 sA1[BM * 40];
  __shared__ bf16 sA2[BM * 40];
  __shared__ bf16 sA3[BM * 40];
  __shared__ bf16 sB1[BN * 40];
  __shared__ bf16 sB2[BN * 40];
  __shared__ bf16 sB3[BN * 40];
  const int tid = threadIdx.x;
  const int z = blockIdx.z;
  const int row0 = blockIdx.y * BM;
  const int col0 = blockIdx.x * BN;
  const int lane = tid & 63;
  const int wv = tid >> 6;
  const int wm = (wv % WGM) * (FM * 16);
  const int wn = (wv / WGM) * (FN * 16);
  double acc[FM][FN][4];
  f32x4 fmn[FM][FN], fcr[FM][FN];
#pragma unroll
  for (int i = 0; i < FM; i++)
#pragma unroll
    for (int j = 0; j < FN; j++)
#pragma unroll
      for (int r = 0; r < 4; r++) {
        acc[i][j][r] = 0.0;
        fmn[i][j][r] = 0.f;
        fcr[i][j][r] = 0.f;
      }

  bf16x8 gA[NA][3], gB[NB][3];
  auto issue = [&](int s) {
#pragma unroll
    for (int u = 0; u < NA; u++) {
      int g = u * TH + tid;
      if (g < BM * 4) {
        int row = g >> 2, k0 = (g & 3) * 8;
        p.loadA3(z, row0 + row, k0, s, gA[u][0], gA[u][1], gA[u][2]);
      }
    }
#pragma unroll
    for (int u = 0; u < NB; u++) {
      int g = u * TH + tid;
      if (g < BN * 4) {
        int row = g >> 2, k0 = (g & 3) * 8;
        p.loadB3(z, col0 + row, k0, s, gB[u][0], gB[u][1], gB[u][2]);
      }
    }
  };

  const int ks = p.ksteps();
  issue(0);
  for (int s = 0; s < ks; ++s) {
#pragma unroll
    for (int u = 0; u < NA; u++) {
      int g = u * TH + tid;
      if (g < BM * 4) {
        int row = g >> 2, k0 = (g & 3) * 8;
        int byte = row * 80 + k0 * 2;
        *(bf16x8*)((char*)sA1 + byte) = gA[u][0];
        *(bf16x8*)((char*)sA2 + byte) = gA[u][1];
        *(bf16x8*)((char*)sA3 + byte) = gA[u][2];
      }
    }
#pragma unroll
    for (int u = 0; u < NB; u++) {
      int g = u * TH + tid;
      if (g < BN * 4) {
        int row = g >> 2, k0 = (g & 3) * 8;
        int byte = row * 80 + k0 * 2;
        *(bf16x8*)((char*)sB1 + byte) = gB[u][0];
        *(bf16x8*)((char*)sB2 + byte) = gB[u][1];
        *(bf16x8*)((char*)sB3 + byte) = gB[u][2];
      }
    }
    __syncthreads();
    if (s + 1 < ks) issue(s + 1);  // overlap next-tile HBM latency with compute
    {
      const int kByte = (lane >> 4) << 4;
      bf16x8 a1[FM], a2[FM], a3[FM], b1[FN], b2[FN], b3[FN];
#pragma unroll
      for (int i = 0; i < FM; i++) {
        int r = wm + i * 16 + (lane & 15);
        int byte = r * 80 + kByte;
        a1[i] = *(const bf16x8*)((const char*)sA1 + byte);
        a2[i] = *(const bf16x8*)((const char*)sA2 + byte);
        a3[i] = *(const bf16x8*)((const char*)sA3 + byte);
      }
#pragma unroll
      for (int j = 0; j < FN; j++) {
        int r = wn + j * 16 + (lane & 15);
        int byte = r * 80 + kByte;
        b1[j] = *(const bf16x8*)((const char*)sB1 + byte);
        b2[j] = *(const bf16x8*)((const char*)sB2 + byte);
        b3[j] = *(const bf16x8*)((const char*)sB3 + byte);
      }
#pragma unroll
      for (int i = 0; i < FM; i++)
#pragma unroll
        for (int j = 0; j < FN; j++) {
          fmn[i][j] = __builtin_amdgcn_mfma_f32_16x16x32_bf16(a1[i], b1[j], fmn[i][j], 0, 0, 0);
          fcr[i][j] = __builtin_amdgcn_mfma_f32_16x16x32_bf16(a1[i], b2[j], fcr[i][j], 0, 0, 0);
          fcr[i][j] = __builtin_amdgcn_mfma_f32_16x16x32_bf16(a2[i], b1[j], fcr[i][j], 0, 0, 0);
          fcr[i][j] = __builtin_amdgcn_mfma_f32_16x16x32_bf16(a2[i], b2[j], fcr[i][j], 0, 0, 0);
          fcr[i][j] = __builtin_amdgcn_mfma_f32_16x16x32_bf16(a1[i], b3[j], fcr[i][j], 0, 0, 0);
          fcr[i][j] = __builtin_amdgcn_mfma_f32_16x16x32_bf16(a3[i], b1[j], fcr[i][j], 0, 0, 0);
        }
    }
    bool flm = ((s & 1) == 1) || (s == ks - 1);
    bool flc = ((s & 7) == 7) || (s == ks - 1);
    if (flm) {
#pragma unroll
      for (int i = 0; i < FM; i++)
#pragma unroll
        for (int j = 0; j < FN; j++)
#pragma unroll
          for (int r = 0; r < 4; r++) {
            acc[i][j][r] += (double)fmn[i][j][r];
            fmn[i][j][r] = 0.f;
          }
    }
    if (flc) {
#pragma unroll
      for (int i = 0; i < FM; i++)
#pragma unroll
        for (int j = 0; j < FN; j++)
#pragma unroll
          for (int r = 0; r < 4; r++) {
            acc[i][j][r] += (double)fcr[i][j][r];
            fcr[i][j][r] = 0.f;
          }
    }
    __syncthreads();
  }
#pragma unroll
  for (int i = 0; i < FM; i++)
#pragma unroll
    for (int j = 0; j < FN; j++)
#pragma unroll
      for (int rg = 0; rg < 4; rg++) {
        int r = row0 + wm + i * 16 + ((lane >> 4) << 2) + rg;
        int c = col0 + wn + j * 16 + (lane & 15);
        p.store(z, r, c, acc[i][j][rg]);
      }
}

// ---------------- problem structs ----------------
struct P6PROJ {  // OPRE = x_half @ projT ; M=3000 N=1024 K=1024
  const float* x;
  const bf16 *b1, *b2, *b3;
  float* out;
  int rowoff, colbase;
  __device__ int ksteps() const { return 32; }
  __device__ void loadA3(int, int r, int k0, int s, bf16x8& v1, bf16x8& v2, bf16x8& v3) const {
    v1 = bzero8(); v2 = bzero8(); v3 = bzero8();
    if (r >= RPC) return;
    const float* src = x + (size_t)(rowoff + r) * 2048 + colbase + s * 32 + k0;
#pragma unroll
    for (int j = 0; j < 8; j++) {
      bf3 t = split3(src[j]);
      v1[j] = t.h; v2[j] = t.m; v3[j] = t.l;
    }
  }
  __device__ void loadB3(int, int c, int k0, int s, bf16x8& v1, bf16x8& v2, bf16x8& v3) const {
    size_t a = (size_t)c * 1024 + s * 32 + k0;
    v1 = *(const bf16x8*)(b1 + a); v2 = *(const bf16x8*)(b2 + a); v3 = *(const bf16x8*)(b3 + a);
  }
  __device__ void store(int, int r, int c, double v) const {
    if (r < RPC) out[(size_t)r * 1024 + c] = (float)v;
  }
};

struct P6Q {  // Q = o_rgb @ attwT per local pair ; M=750 N=128 K=128
  const bf16 *a1, *a2, *a3, *b1, *b2, *b3;
  bf16 *q1, *q2, *q3;
  __device__ int ksteps() const { return 4; }
  __device__ void loadA3(int z, int r, int k0, int s, bf16x8& v1, bf16x8& v2, bf16x8& v3) const {
    if (r >= 750) { v1 = bzero8(); v2 = bzero8(); v3 = bzero8(); return; }
    size_t a = (size_t)z * 96000 + (size_t)r * 128 + s * 32 + k0;
    v1 = *(const bf16x8*)(a1 + a); v2 = *(const bf16x8*)(a2 + a); v3 = *(const bf16x8*)(a3 + a);
  }
  __device__ void loadB3(int z, int c, int k0, int s, bf16x8& v1, bf16x8& v2, bf16x8& v3) const {
    size_t a = (size_t)(z & 7) * 16384 + (size_t)c * 128 + s * 32 + k0;
    v1 = *(const bf16x8*)(b1 + a); v2 = *(const bf16x8*)(b2 + a); v3 = *(const bf16x8*)(b3 + a);
  }
  __device__ void store(int z, int r, int c, float v) const {
    if (r >= 750) return;
    size_t a = (size_t)z * 96000 + (size_t)r * 128 + c;
    bf3 t = split3(v);
    q1[a] = t.h; q2[a] = t.m; q3[a] = t.l;
  }
};

struct P6S {  // P = exp(Q @ o_flow^T) per local pair ; M=N=750 K=128
  const bf16 *a1, *a2, *a3, *b1, *b2, *b3;
  float* out;
  __device__ int ksteps() const { return 4; }
  __device__ void loadA3(int z, int r, int k0, int s, bf16x8& v1, bf16x8& v2, bf16x8& v3) const {
    if (r >= 750) { v1 = bzero8(); v2 = bzero8(); v3 = bzero8(); return; }
    size_t a = (size_t)z * 96000 + (size_t)r * 128 + s * 32 + k0;
    v1 = *(const bf16x8*)(a1 + a); v2 = *(const bf16x8*)(a2 + a); v3 = *(const bf16x8*)(a3 + a);
  }
  __device__ void loadB3(int z, int c, int k0, int s, bf16x8& v1, bf16x8& v2, bf16x8& v3) const {
    if (c >= 750) { v1 = bzero8(); v2 = bzero8(); v3 = bzero8(); return; }
    size_t a = (size_t)z * 96000 + (size_t)c * 128 + s * 32 + k0;
    v1 = *(const bf16x8*)(b1 + a); v2 = *(const bf16x8*)(b2 + a); v3 = *(const bf16x8*)(b3 + a);
  }
  __device__ void store(int z, int r, int c, float v) const {
    if (r < 750 && c < 750) out[(size_t)z * SPAIR + (size_t)r * SROW + c] = expf(v);
  }
};

struct P6E {  // xc-half = (P/Z) @ oT^T (both rgb & flow via z), gelu+tanh epilogue
  const float *Pr, *Pt;          // row-softmax P and transposed P
  const float *invr, *invc;
  const bf16 *br1, *br2, *br3;   // OTR planes
  const bf16 *bt1, *bt2, *bt3;   // OTF planes
  const float* x;
  bf16 *xc1, *xc2, *xc3;
  int pairbase;
  __device__ int ksteps() const { return 24; }
  __device__ void loadA3(int z, int r, int k0, int s, bf16x8& v1, bf16x8& v2, bf16x8& v3) const {
    v1 = bzero8(); v2 = bzero8(); v3 = bzero8();
    if (r >= 750) return;
    int zp = z & 31;
    const float* Pm = (z < 32) ? Pr : Pt;
    const float* inv = (z < 32) ? invr : invc;
    int m0 = s * 32 + k0;
    const float* row = Pm + (size_t)zp * SPAIR + (size_t)r * SROW;
    float sc = inv[zp * 750 + r];
#pragma unroll
    for (int j = 0; j < 8; j++) {
      int m = m0 + j;
      if (m < 750) {
        bf3 t = split3(row[m] * sc);
        v1[j] = t.h; v2[j] = t.m; v3[j] = t.l;
      }
    }
  }
  __device__ void loadB3(int z, int c, int k0, int s, bf16x8& v1, bf16x8& v2, bf16x8& v3) const {
    int zp = z & 31;
    size_t a = (size_t)zp * 98304 + (size_t)c * 768 + s * 32 + k0;
    if (z < 32) {
      v1 = *(const bf16x8*)(br1 + a); v2 = *(const bf16x8*)(br2 + a); v3 = *(const bf16x8*)(br3 + a);
    } else {
      v1 = *(const bf16x8*)(bt1 + a); v2 = *(const bf16x8*)(bt2 + a); v3 = *(const bf16x8*)(bt3 + a);
    }
  }
  __device__ void store(int z, int r, int c, float v) const {
    if (r >= 750) return;
    int zp = z & 31;
    int gp = pairbase + zp;
    int hh = gp & 7, n = gp >> 3;
    int xcol = ((z < 32) ? 0 : 1024) + hh * 128 + c;
    float g = 0.5f * v * (1.f + erff(v * 0.70710678118654752f));
    float f = tanhf(g + x[((size_t)n * 750 + r) * 2048 + xcol]);
    size_t a = (size_t)(n * PT + r + 4) * 2048 + xcol;
    bf3 t = split3(f);
    xc1[a] = t.h; xc2[a] = t.m; xc3[a] = t.l;
  }
};

struct P6CONV {  // emb = relu(conv9(xc, W) + b)
  const bf16 *a1, *a2, *a3, *b1, *b2, *b3;
  const float* bias;
  bf16 *o1, *o2, *o3;
  __device__ int ksteps() const { return 576; }
  __device__ void loadA3(int, int r, int k0, int s, bf16x8& v1, bf16x8& v2, bf16x8& v3) const {
    if (r >= MM) { v1 = bzero8(); v2 = bzero8(); v3 = bzero8(); return; }
    int ktap = s >> 6, kb = s & 63;
    int n = (unsigned)r / 750u;
    size_t a = (size_t)(r + 8 * n + ktap) * 2048 + kb * 32 + k0;
    v1 = *(const bf16x8*)(a1 + a); v2 = *(const bf16x8*)(a2 + a); v3 = *(const bf16x8*)(a3 + a);
  }
  __device__ void loadB3(int, int c, int k0, int s, bf16x8& v1, bf16x8& v2, bf16x8& v3) const {
    int ktap = s >> 6, kb = s & 63;
    size_t a = ((size_t)(ktap * 2048 + c)) * 2048 + kb * 32 + k0;
    v1 = *(const bf16x8*)(b1 + a); v2 = *(const bf16x8*)(b2 + a); v3 = *(const bf16x8*)(b3 + a);
  }
  __device__ void store(int, int r, int c, double v) const {
    if (r >= MM) return;
    v += (double)bias[c];
    if (v < 0) v = 0;
    int n = (unsigned)r / 750u;
    size_t a = (size_t)(r + 8 * n + 4) * 2048 + c;
    bf3 t = split3((float)v);
    o1[a] = t.h; o2[a] = t.m; o3[a] = t.l;
  }
};

struct P6CLS1 {  // cas1 = conv9(emb, cls1_w), N=32 (20 used)
  const bf16 *a1, *a2, *a3, *b1, *b2, *b3;
  float* out;
  __device__ int ksteps() const { return 576; }
  __device__ void loadA3(int, int r, int k0, int s, bf16x8& v1, bf16x8& v2, bf16x8& v3) const {
    if (r >= MM) { v1 = bzero8(); v2 = bzero8(); v3 = bzero8(); return; }
    int ktap = s >> 6, kb = s & 63;
    int n = (unsigned)r / 750u;
    size_t a = (size_t)(r + 8 * n + ktap) * 2048 + kb * 32 + k0;
    v1 = *(const bf16x8*)(a1 + a); v2 = *(const bf16x8*)(a2 + a); v3 = *(const bf16x8*)(a3 + a);
  }
  __device__ void loadB3(int, int c, int k0, int s, bf16x8& v1, bf16x8& v2, bf16x8& v3) const {
    int ktap = s >> 6, kb = s & 63;
    size_t a = ((size_t)(ktap * 32 + c)) * 2048 + kb * 32 + k0;
    v1 = *(const bf16x8*)(b1 + a); v2 = *(const bf16x8*)(b2 + a); v3 = *(const bf16x8*)(b3 + a);
  }
  __device__ void store(int, int r, int c, double v) const {
    if (r < MM && c < NC) out[(size_t)r * NC + c] = (float)v;
  }
};

// ---------------- misc kernels ----------------
__global__ void k_split_projT3(const float* rgbp, const float* flowp, bf16* r1, bf16* r2, bf16* r3,
                               bf16* f1, bf16* f2, bf16* f3) {
  int bx = blockIdx.x;
  int st = bx >> 10, c = bx & 1023;
  int h = c >> 7, e = c & 127;
  const float* src = st ? flowp : rgbp;
  bf16* o1 = st ? f1 : r1;
  bf16* o2 = st ? f2 : r2;
  bf16* o3 = st ? f3 : r3;
  int d0 = threadIdx.x * 4;
  bf16x4 a, b, cc;
#pragma unroll
  for (int j = 0; j < 4; j++) {
    bf3 t = split3(src[(size_t)h * 131072 + (size_t)(d0 + j) * 128 + e]);
    a[j] = t.h; b[j] = t.m; cc[j] = t.l;
  }
  size_t o = (size_t)c * 1024 + d0;
  *(bf16x4*)(o1 + o) = a;
  *(bf16x4*)(o2 + o) = b;
  *(bf16x4*)(o3 + o) = cc;
}

__global__ void k_split_attewT3(const float* aw, bf16* w1, bf16* w2, bf16* w3) {
  int b = blockIdx.x;
  int h = b >> 7, f = b & 127;
  int e = threadIdx.x;
  bf3 t = split3(aw[(size_t)h * 16384 + (size_t)e * 128 + f]);
  size_t a = (size_t)h * 16384 + (size_t)f * 128 + e;
  w1[a] = t.h; w2[a] = t.m; w3[a] = t.l;
}

__global__ void k_split_wt3(const float* ew, bf16* w1, bf16* w2, bf16* w3) {
  __shared__ float tmp[1152];
  int o = blockIdx.x >> 4, ic0 = (blockIdx.x & 15) << 7;
  for (int t = threadIdx.x; t < 1152; t += 256)
    tmp[t] = ew[(size_t)o * 18432 + (size_t)ic0 * 9 + t];
  __syncthreads();
  for (int w = threadIdx.x; w < 1152; w += 256) {
    int k = w >> 7, i = w & 127;
    bf3 t = split3(tmp[i * 9 + k]);
    size_t a = ((size_t)(k * 2048 + o)) * 2048 + ic0 + i;
    w1[a] = t.h; w2[a] = t.m; w3[a] = t.l;
  }
}

__global__ void k_split_wc3(const float* cw, bf16* w1, bf16* w2, bf16* w3) {
  int k = blockIdx.x / 32, c = blockIdx.x % 32;
  for (int i = threadIdx.x; i < 2048; i += 256) {
    float v = (c < NC) ? cw[(size_t)c * 18432 + (size_t)i * 9 + k] : 0.f;
    bf3 t = split3(v);
    size_t a = ((size_t)(k * 32 + c)) * 2048 + i;
    w1[a] = t.h; w2[a] = t.m; w3[a] = t.l;
  }
}

__global__ void k_norm3(const float* opre, bf16* o1, bf16* o2, bf16* o3) {
  int r = blockIdx.x;  // 0..2999 local
  int head = threadIdx.x >> 5, ln = threadIdx.x & 31;
  const float* src = opre + (size_t)r * 1024 + head * 128 + ln * 4;
  float4 v = *(const float4*)src;
  double ss = (double)v.x * v.x + (double)v.y * v.y + (double)v.z * v.z + (double)v.w * v.w;
  for (int k = 16; k; k >>= 1) ss += __shfl_xor(ss, k, 32);
  double rn = 1.0 / fmax(sqrt(ss), 1e-12);
  int nl = r / 750, l = r % 750;
  int zp = nl * 8 + head;
  size_t o = (size_t)zp * 96000 + (size_t)l * 128 + ln * 4;
  float vv[4] = {v.x, v.y, v.z, v.w};
  bf16x4 h4, m4, l4;
#pragma unroll
  for (int j = 0; j < 4; j++) {
    bf3 t = split3((float)((double)vv[j] * rn));
    h4[j] = t.h; m4[j] = t.m; l4[j] = t.l;
  }
  *(bf16x4*)(o1 + o) = h4;
  *(bf16x4*)(o2 + o) = m4;
  *(bf16x4*)(o3 + o) = l4;
}

__global__ void k_trans3(const bf16* i1, const bf16* i2, const bf16* i3, bf16* o1, bf16* o2,
                         bf16* o3) {
  __shared__ bf16 t1[32][33], t2[32][33], t3[32][33];
  int zp = blockIdx.y;
  int lt = blockIdx.x >> 2, et = blockIdx.x & 3;
  int tx = threadIdx.x & 31, ty = threadIdx.x >> 5;
#pragma unroll
  for (int p = 0; p < 4; p++) {
    int lrow = lt * 32 + ty + p * 8;
    int e = et * 32 + tx;
    bf16 a = (bf16)0.f, b = (bf16)0.f, c = (bf16)0.f;
    if (lrow < 750) {
      size_t ad = (size_t)zp * 96000 + (size_t)lrow * 128 + e;
      a = i1[ad]; b = i2[ad]; c = i3[ad];
    }
    t1[ty + p * 8][tx] = a;
    t2[ty + p * 8][tx] = b;
    t3[ty + p * 8][tx] = c;
  }
  __syncthreads();
#pragma unroll
  for (int p = 0; p < 4; p++) {
    int e = et * 32 + ty + p * 8;
    int l2 = lt * 32 + tx;
    size_t ad = (size_t)zp * 98304 + (size_t)e * 768 + l2;
    o1[ad] = t1[tx][ty + p * 8];
    o2[ad] = t2[tx][ty + p * 8];
    o3[ad] = t3[tx][ty + p * 8];
  }
}

__global__ void k_transS(const float* S, float* ST) {
  __shared__ float t[32][33];
  int zp = blockIdx.y;
  int tr = (blockIdx.x / 24) * 32, tc = (blockIdx.x % 24) * 32;
  int tx = threadIdx.x & 31, ty = threadIdx.x >> 5;
#pragma unroll
  for (int p = 0; p < 4; p++) {
    int rr = tr + ty + p * 8, cc = tc + tx;
    t[ty + p * 8][tx] = (rr < 750 && cc < 750) ? S[(size_t)zp * SPAIR + (size_t)rr * SROW + cc] : 0.f;
  }
  __syncthreads();
#pragma unroll
  for (int p = 0; p < 4; p++) {
    int cc = tc + ty + p * 8, rr = tr + tx;
    if (cc < 750 && rr < 750) ST[(size_t)zp * SPAIR + (size_t)cc * SROW + rr] = t[tx][ty + p * 8];
  }
}

__global__ void k_statsd(const float* P, float* inv) {
  int b = blockIdx.x;
  int p = b / 94, r0 = (b % 94) * 8;
  int g = threadIdx.x >> 5, ln = threadIdx.x & 31;
  int r = r0 + g;
  if (r >= 750) return;
  const float* row = P + (size_t)p * SPAIR + (size_t)r * SROW;
  double s = 0.0;
  for (int m = ln; m < 750; m += 32) s += (double)row[m];
  for (int k = 16; k; k >>= 1) s += __shfl_xor(s, k, 32);
  if (ln == 0) inv[p * 750 + r] = (float)(1.0 / s);
}

__global__ void k_cls2(const float* cas1, const float* w2, float* cas_out, float* cast) {
  int idx = blockIdx.x * 256 + threadIdx.x;
  if (idx >= MM * NC) return;
  int r = idx / NC, c = idx % NC;
  int n = r / 750, t = r % 750;
  double a = 0.0;
#pragma unroll
  for (int j = 0; j < 7; j++) {
    int tt = t + 2 * j - 6;
    if (tt >= 0 && tt < 750)
      a += (double)w2[c * 7 + j] * (double)cas1[((size_t)n * 750 + tt) * NC + c];
  }
  if (a < 0) a = 0;
  cas_out[idx] = (float)a;
  cast[((size_t)n * NC + c) * 750 + t] = (float)a;
}

__global__ void k_act(const float* cas, float* act, float* out_act) {
  int r = blockIdx.x * 256 + threadIdx.x;
  if (r >= MM) return;
  double s = 0.0;
#pragma unroll
  for (int c = 0; c < NC; c++) s += (double)cas[(size_t)r * NC + c];
  act[r] = (float)s;
  out_act[r] = (float)s;
}

__global__ __launch_bounds__(512) void k_mask(const float* act, float* arev, float* inner,
                                              float* outer) {
  __shared__ u64 ks[1024];
  __shared__ float av[768];
  __shared__ float bb[768];
  int n = blockIdx.x;
  for (int i = threadIdx.x; i < 1024; i += 512) {
    if (i < 750) {
      float v = act[n * 750 + i];
      av[i] = v;
      ks[i] = ((u64)asc_enc(v) << 32) | (u32)i;
    } else
      ks[i] = ~0ull;
  }
  bsort1024(ks);
  float med = 0.5f * (asc_dec((u32)(ks[374] >> 32)) + asc_dec((u32)(ks[375] >> 32)));
  float amax = asc_dec((u32)(ks[749] >> 32));
  for (int t = threadIdx.x; t < 750; t += 512) bb[t] = (av[t] > med) ? 1.f : 0.f;
  __syncthreads();
  for (int t = threadIdx.x; t < 750; t += 512) {
    float e3 = 1.f, e6 = 1.f, d3 = 0.f, d6 = 0.f;
    for (int j = t - 1; j <= t + 1; ++j) {
      float v = (j >= 0 && j < 750) ? bb[j] : 0.f;
      e3 = fminf(e3, v); d3 = fmaxf(d3, v);
    }
    for (int j = t - 3; j <= t + 2; ++j) {
      float v = (j >= 0 && j < 750) ? bb[j] : 0.f;
      e6 = fminf(e6, v);
    }
    for (int j = t - 2; j <= t + 3; ++j) {
      float v = (j >= 0 && j < 750) ? bb[j] : 0.f;
      d6 = fmaxf(d6, v);
    }
    int g = n * 750 + t;
    inner[g] = (e3 - e6 > 0.5f) ? av[t] : 0.f;
    outer[g] = (d6 - d3 > 0.5f) ? av[t] : 0.f;
    arev[g] = amax - av[t];
  }
}

__global__ __launch_bounds__(512) void k_topk(const float* act, const float* arev,
                                              const float* inner, const float* outer, int* idxb) {
  __shared__ u64 ks[1024];
  int n = blockIdx.x >> 2, w = blockIdx.x & 3;
  const float* src = (w == 0) ? act : ((w == 1) ? arev : ((w == 2) ? inner : outer));
  int K = (w < 2) ? KE : KH;
  int off = (w == 0) ? 0 : ((w == 1) ? 150 : ((w == 2) ? 300 : 337));
  for (int i = threadIdx.x; i < 1024; i += 512) {
    if (i < 750) {
      u32 d = ~asc_enc(src[n * 750 + i]);
      ks[i] = ((u64)d << 32) | (u32)i;
    } else
      ks[i] = ~0ull;
  }
  bsort1024(ks);
  for (int i = threadIdx.x; i < K; i += 512) idxb[n * 374 + off + i] = (int)(ks[i] & 0xFFFFFFFFu);
}

__global__ __launch_bounds__(512) void k_topcas(const float* cast, float* smean) {
  __shared__ u64 ks[1024];
  __shared__ float red[512];
  int b = blockIdx.x;
  for (int i = threadIdx.x; i < 1024; i += 512) {
    if (i < 750) {
      u32 d = ~asc_enc(cast[(size_t)b * 750 + i]);
      ks[i] = ((u64)d << 32) | (u32)i;
    } else
      ks[i] = ~0ull;
  }
  bsort1024(ks);
  float s = 0.f;
  for (int i = threadIdx.x; i < KE; i += 512) s += asc_dec(~(u32)(ks[i] >> 32));
  red[threadIdx.x] = s;
  __syncthreads();
  for (int st = 256; st; st >>= 1) {
    if (threadIdx.x < st) red[threadIdx.x] += red[threadIdx.x + st];
    __syncthreads();
  }
  if (threadIdx.x == 0) smean[b] = red[0] / 150.f;
}

__global__ void k_gather(const int* idxb, const bf16* e1, const bf16* e2, const bf16* e3,
                         float* dout) {
  int b = blockIdx.x;
  int n = b / 374, j = b % 374;
  size_t obase;
  if (j < 150) obase = OUT_EA + ((size_t)n * KE + j) * 2048;
  else if (j < 300) obase = OUT_EB + ((size_t)n * KE + (j - 150)) * 2048;
  else if (j < 337) obase = OUT_HA + ((size_t)n * KH + (j - 300)) * 2048;
  else obase = OUT_HB + ((size_t)n * KH + (j - 337)) * 2048;
  int t = idxb[n * 374 + j];
  size_t irow = (size_t)(n * PT + t + 4) * 2048;
#pragma unroll
  for (int p = 0; p < 8; p++) {
    int c = threadIdx.x + p * 256;
    dout[obase + c] = (float)e1[irow + c] + (float)e2[irow + c] + (float)e3[irow + c];
  }
}

__global__ void k_vs(const float* smean, float* dout) {
  int n = blockIdx.x;
  int c = threadIdx.x;
  float v = (c < NC) ? smean[n * NC + c] : -3.4e38f;
  float m = v;
  for (int s = 32; s; s >>= 1) m = fmaxf(m, __shfl_xor(m, s));
  float e = (c < NC) ? expf(v - m) : 0.f;
  float sum = e;
  for (int s = 32; s; s >>= 1) sum += __shfl_xor(sum, s);
  if (c < NC) dout[n * NC + c] = e / sum;
}

// ---------------- host ----------------
extern "C" void kernel_launch(void* const* d_in, const int* in_sizes, int n_in, void* d_out,
                              int out_size, void* d_ws, size_t ws_size, hipStream_t stream) {
  const float* x = (const float*)d_in[0];
  const float* rgbp = (const float*)d_in[1];
  const float* flowp = (const float*)d_in[2];
  const float* attw = (const float*)d_in[3];
  const float* embw = (const float*)d_in[4];
  const float* embb = (const float*)d_in[5];
  const float* c1w = (const float*)d_in[6];
  const float* c2w = (const float*)d_in[7];
  float* dout = (float*)d_out;
  char* ws = (char*)d_ws;

  if (ws_size < WS_NEED) {
    fprintf(stderr, "[CoLA] FATAL ws_size=%zu < need=%zu\n", ws_size, (size_t)WS_NEED);
    return;
  }

  bf16* XC1 = (bf16*)(ws + O_XC1);
  bf16* XC2 = (bf16*)(ws + O_XC2);
  bf16* XC3 = (bf16*)(ws + O_XC3);
  bf16* EM1 = (bf16*)(ws + O_EM1);
  bf16* EM2 = (bf16*)(ws + O_EM2);
  bf16* EM3 = (bf16*)(ws + O_EM3);
  float* CAS1 = (float*)(ws + O_CAS1);
  float* CAST = (float*)(ws + O_CAST);
  float* ACT = (float*)(ws + O_ACT);
  float* AREV = (float*)(ws + O_AREV);
  float* INNER = (float*)(ws + O_INNER);
  float* OUTER = (float*)(ws + O_OUTER);
  float* SMEAN = (float*)(ws + O_SMEAN);
  int* IDX = (int*)(ws + O_IDX);
  float* RSINV = (float*)(ws + O_RSINV);
  float* CSINV = (float*)(ws + O_CSINV);
  float* SBUF = (float*)(ws + O_S);
  float* STBUF = (float*)(ws + O_ST);
  bf16 *Q1 = (bf16*)(ws + O_Q1), *Q2 = (bf16*)(ws + O_Q2), *Q3 = (bf16*)(ws + O_Q3);
  bf16 *OR1 = (bf16*)(ws + O_OR1), *OR2 = (bf16*)(ws + O_OR2), *OR3 = (bf16*)(ws + O_OR3);
  bf16 *OF1 = (bf16*)(ws + O_OF1), *OF2 = (bf16*)(ws + O_OF2), *OF3 = (bf16*)(ws + O_OF3);
  bf16 *OTR1 = (bf16*)(ws + O_OTR1), *OTR2 = (bf16*)(ws + O_OTR2), *OTR3 = (bf16*)(ws + O_OTR3);
  bf16 *OTF1 = (bf16*)(ws + O_OTF1), *OTF2 = (bf16*)(ws + O_OTF2), *OTF3 = (bf16*)(ws + O_OTF3);
  float* OPRE = (float*)(ws + O_OPRE);
  bf16 *PR1 = (bf16*)(ws + O_PR1), *PR2 = (bf16*)(ws + O_PR2), *PR3 = (bf16*)(ws + O_PR3);
  bf16 *PF1 = (bf16*)(ws + O_PF1), *PF2 = (bf16*)(ws + O_PF2), *PF3 = (bf16*)(ws + O_PF3);
  bf16 *AW1 = (bf16*)(ws + O_AW1), *AW2 = (bf16*)(ws + O_AW2), *AW3 = (bf16*)(ws + O_AW3);
  bf16 *WT1 = (bf16*)(ws + O_WT1), *WT2 = (bf16*)(ws + O_WT2), *WT3 = (bf16*)(ws + O_WT3);
  bf16 *WC1 = (bf16*)(ws + O_WC1), *WC2 = (bf16*)(ws + O_WC2), *WC3 = (bf16*)(ws + O_WC3);

  (void)hipMemsetAsync(ws, 0, O_CAS1, stream);  // zero 6 padded planes

  k_split_projT3<<<2048, 256, 0, stream>>>(rgbp, flowp, PR1, PR2, PR3, PF1, PF2, PF3);
  k_split_attewT3<<<1024, 128, 0, stream>>>(attw, AW1, AW2, AW3);

  for (int cb = 0; cb < NCHUNK; cb++) {
    int rowoff = cb * RPC;
    int pb = cb * PCH;
    // rgb: proj -> norm -> trans -> q
    {
      P6PROJ p{x, PR1, PR2, PR3, OPRE, rowoff, 0};
      gemm6d<512, 2, 4, 4, 2, P6PROJ><<<dim3(8, 24, 1), 512, 0, stream>>>(p);
    }
    k_norm3<<<RPC, 256, 0, stream>>>(OPRE, OR1, OR2, OR3);
    k_trans3<<<dim3(96, 32), 256, 0, stream>>>(OR1, OR2, OR3, OTR1, OTR2, OTR3);
    {
      P6Q p{OR1, OR2, OR3, AW1, AW2, AW3, Q1, Q2, Q3};
      gemm6<2, 2, 4, 4, P6Q><<<dim3(1, 6, PCH), 256, 0, stream>>>(p);
    }
    // flow: proj -> norm -> trans
    {
      P6PROJ p{x, PF1, PF2, PF3, OPRE, rowoff, 1024};
      gemm6d<512, 2, 4, 4, 2, P6PROJ><<<dim3(8, 24, 1), 512, 0, stream>>>(p);
    }
    k_norm3<<<RPC, 256, 0, stream>>>(OPRE, OF1, OF2, OF3);
    k_trans3<<<dim3(96, 32), 256, 0, stream>>>(OF1, OF2, OF3, OTF1, OTF2, OTF3);
    // P = exp(S), transpose, softmax denominators, fused e-GEMMs (rgb+flow in one)
    {
      P6S p{Q1, Q2, Q3, OF1, OF2, OF3, SBUF};
      gemm6<2, 2, 4, 4, P6S><<<dim3(6, 6, PCH), 256, 0, stream>>>(p);
    }
    k_transS<<<dim3(576, PCH), 256, 0, stream>>>(SBUF, STBUF);
    k_statsd<<<PCH * 94, 256, 0, stream>>>(SBUF, RSINV);
    k_statsd<<<PCH * 94, 256, 0, stream>>>(STBUF, CSINV);
    {
      P6E p{SBUF, STBUF, RSINV, CSINV, OTR1, OTR2, OTR3, OTF1, OTF2, OTF3, x, XC1, XC2, XC3, pb};
      gemm6<2, 2, 4, 4, P6E><<<dim3(1, 6, 2 * PCH), 256, 0, stream>>>(p);
    }
  }

  // conv weights (alias dead attention arena), conv GEMMs
  k_split_wt3<<<32768, 256, 0, stream>>>(embw, WT1, WT2, WT3);
  k_split_wc3<<<288, 256, 0, stream>>>(c1w, WC1, WC2, WC3);
  {
    // round-6 mapping (x=col fastest, lowest FETCH) + reg-prefetch pipeline
    P6CONV p{XC1, XC2, XC3, WT1, WT2, WT3, embb, EM1, EM2, EM3};
    gemm6d<512, 2, 4, 4, 2, P6CONV><<<dim3(16, 94, 1), 512, 0, stream>>>(p);
  }
  {
    P6CLS1 p{EM1, EM2, EM3, WC1, WC2, WC3, CAS1};
    gemm6d<512, 4, 2, 2, 1, P6CLS1><<<dim3(1, 94, 1), 512, 0, stream>>>(p);
  }
  k_cls2<<<(MM * NC + 255) / 256, 256, 0, stream>>>(CAS1, c2w, dout + OUT_CAS, CAST);
  k_act<<<(MM + 255) / 256, 256, 0, stream>>>(dout + OUT_CAS, ACT, dout + OUT_ACT);

  // postprocess
  k_mask<<<16, 512, 0, stream>>>(ACT, AREV, INNER, OUTER);
  k_topk<<<64, 512, 0, stream>>>(ACT, AREV, INNER, OUTER, IDX);
  k_topcas<<<320, 512, 0, stream>>>(CAST, SMEAN);
  k_gather<<<16 * 374, 256, 0, stream>>>(IDX, EM1, EM2, EM3, dout);
  k_vs<<<16, 64, 0, stream>>>(SMEAN, dout);
}

// Round 11
// 9021.029 us; speedup vs baseline: 1.4049x; 1.0190x over previous
//
#include <hip/hip_runtime.h>
#include <cstdio>
#include <cstdint>

typedef __bf16 bf16;
typedef __attribute__((ext_vector_type(8))) __bf16 bf16x8;
typedef __attribute__((ext_vector_type(4))) __bf16 bf16x4;
typedef __attribute__((ext_vector_type(4))) float f32x4;
typedef unsigned long long u64;
typedef unsigned int u32;

// ---------------- problem dims ----------------
constexpr int BATCH = 16, TT = 750, DD = 2048, NC = 20;
constexpr int MM = 12000;
constexpr int PT = 758;            // padded T (4+750+4)
constexpr int PCH = 32;            // pairs per chunk (4 batches x 8 heads)
constexpr int NCHUNK = 4;
constexpr int RPC = 3000;          // x rows per chunk
constexpr int SROW = 752;
constexpr int SPAIR = 750 * SROW;  // 564000
constexpr int KE = 150, KH = 37;

// ---------------- output offsets (floats) ----------------
constexpr size_t OUT_EA  = 320;
constexpr size_t OUT_EB  = OUT_EA + (size_t)BATCH * KE * DD;
constexpr size_t OUT_HA  = OUT_EB + (size_t)BATCH * KE * DD;
constexpr size_t OUT_HB  = OUT_HA + (size_t)BATCH * KH * DD;
constexpr size_t OUT_ACT = OUT_HB + (size_t)BATCH * KH * DD;
constexpr size_t OUT_CAS = OUT_ACT + MM;

// ---------------- workspace (bytes) ----------------
constexpr size_t XCB = (size_t)(BATCH * PT) * DD * 2;   // 49,676,288
constexpr size_t O_XC1   = 0;
constexpr size_t O_XC2   = O_XC1 + XCB;
constexpr size_t O_XC3   = O_XC2 + XCB;
constexpr size_t O_EM1   = O_XC3 + XCB;
constexpr size_t O_EM2   = O_EM1 + XCB;
constexpr size_t O_EM3   = O_EM2 + XCB;
constexpr size_t O_CAS1  = O_EM3 + XCB;                  // 298,057,728
constexpr size_t O_CAST  = O_CAS1 + 960000;
constexpr size_t O_ACT   = O_CAST + 960000;
constexpr size_t O_AREV  = O_ACT + 48000;
constexpr size_t O_INNER = O_AREV + 48000;
constexpr size_t O_OUTER = O_INNER + 48000;
constexpr size_t O_SMEAN = O_OUTER + 48000;
constexpr size_t O_IDX   = O_SMEAN + 1280;
constexpr size_t O_RSINV = O_IDX + 23936;
constexpr size_t O_CSINV = O_RSINV + 96000;
constexpr size_t O_DBG   = O_CSINV + 96000;
constexpr size_t AR      = O_DBG + 256;                  // 300,387,200

constexpr size_t SB   = (size_t)PCH * SPAIR * 4;         // 72,192,000
constexpr size_t PL   = (size_t)PCH * 750 * 128 * 2;     // 6,144,000  o plane
constexpr size_t TPL  = (size_t)PCH * 128 * 768 * 2;     // 6,291,456  oT plane
constexpr size_t O_S    = AR;
constexpr size_t O_ST   = O_S + SB;
constexpr size_t O_Q1   = O_ST + SB;
constexpr size_t O_Q2   = O_Q1 + PL;
constexpr size_t O_Q3   = O_Q2 + PL;
constexpr size_t O_OR1  = O_Q3 + PL;
constexpr size_t O_OR2  = O_OR1 + PL;
constexpr size_t O_OR3  = O_OR2 + PL;
constexpr size_t O_OF1  = O_OR3 + PL;
constexpr size_t O_OF2  = O_OF1 + PL;
constexpr size_t O_OF3  = O_OF2 + PL;
constexpr size_t O_OTR1 = O_OF3 + PL;
constexpr size_t O_OTR2 = O_OTR1 + TPL;
constexpr size_t O_OTR3 = O_OTR2 + TPL;
constexpr size_t O_OTF1 = O_OTR3 + TPL;
constexpr size_t O_OTF2 = O_OTF1 + TPL;
constexpr size_t O_OTF3 = O_OTF2 + TPL;
constexpr size_t O_OPRE = O_OTF3 + TPL;                  // RPC*1024*4
constexpr size_t PRP  = (size_t)1024 * 1024 * 2;
constexpr size_t O_PR1  = O_OPRE + (size_t)RPC * 1024 * 4;
constexpr size_t O_PR2  = O_PR1 + PRP;
constexpr size_t O_PR3  = O_PR2 + PRP;
constexpr size_t O_PF1  = O_PR3 + PRP;
constexpr size_t O_PF2  = O_PF1 + PRP;
constexpr size_t O_PF3  = O_PF2 + PRP;
constexpr size_t AWP  = (size_t)8 * 128 * 128 * 2;
constexpr size_t O_AW1  = O_PF3 + PRP;
constexpr size_t O_AW2  = O_AW1 + AWP;
constexpr size_t O_AW3  = O_AW2 + AWP;
constexpr size_t WS_NEED = O_AW3 + AWP;                  // 563,473,280

// conv weights alias dead attention arena
constexpr size_t WTP  = (size_t)9 * 2048 * 2048 * 2;     // 75,497,472
constexpr size_t O_WT1  = AR;
constexpr size_t O_WT2  = O_WT1 + WTP;
constexpr size_t O_WT3  = O_WT2 + WTP;
constexpr size_t WCP  = (size_t)9 * 32 * 2048 * 2;
constexpr size_t O_WC1  = O_WT3 + WTP;
constexpr size_t O_WC2  = O_WC1 + WCP;
constexpr size_t O_WC3  = O_WC2 + WCP;

static_assert(O_WC3 + WCP <= WS_NEED, "WT/WC overrun");
static_assert(WS_NEED <= 603979776, "exceeds harness ws");

// ---------------- helpers ----------------
struct bf3 { bf16 h, m, l; };
static __device__ __forceinline__ bf3 split3(float v) {
  bf3 r;
  r.h = (bf16)v;
  float rem = v - (float)r.h;
  r.m = (bf16)rem;
  r.l = (bf16)(rem - (float)r.m);
  return r;
}
static __device__ __forceinline__ bf16x8 bzero8() {
  bf16x8 v;
#pragma unroll
  for (int i = 0; i < 8; i++) v[i] = (bf16)0.f;
  return v;
}
static __device__ __forceinline__ u32 asc_enc(float f) {
  u32 u = __float_as_uint(f);
  return (u & 0x80000000u) ? ~u : (u | 0x80000000u);
}
static __device__ __forceinline__ float asc_dec(u32 a) {
  u32 u = (a & 0x80000000u) ? (a ^ 0x80000000u) : ~a;
  return __uint_as_float(u);
}
static __device__ void bsort1024(u64* ks) {
  const int tid = threadIdx.x;
  for (int kk = 2; kk <= 1024; kk <<= 1) {
    for (int j = kk >> 1; j > 0; j >>= 1) {
      __syncthreads();
      for (int i = tid; i < 1024; i += 512) {
        int ixj = i ^ j;
        if (ixj > i) {
          u64 a = ks[i], b = ks[ixj];
          bool up = ((i & kk) == 0);
          if ((a > b) == up) { ks[i] = b; ks[ixj] = a; }
        }
      }
    }
  }
  __syncthreads();
}

// Fragment-linear conflict-free LDS layout.
// Per 16-row x 32-k block (1KB): 64 fragment slots of 16B.
// slot(kc, r15) = kc*16 + ((r15 + 2*kc) & 15).
// Reads (lane l: r15=l&15, kc=l>>4): each 8-lane phase spans 32 banks -> 0 conflicts.
// Writes (thread g: r15=(g>>2)&15, kc=g&3): slots {r,r+2,r+4,r+6} mod 8 over 2 rows -> 0 conflicts.
static __device__ __forceinline__ int ldsOff(int row, int kc) {
  return ((row >> 4) << 10) + ((kc * 16 + (((row & 15) + 2 * kc) & 15)) << 4);
}

// ---------------- f32-acc 6-term GEMM (3-plane operands, BK=32) ----------------
template <int WGM, int WGN, int FM, int FN, class P>
__global__ __launch_bounds__(256) void gemm6(P p) {
  constexpr int BM = WGM * FM * 16;
  constexpr int BN = WGN * FN * 16;
  __shared__ bf16 sA1[BM * 32];
  __shared__ bf16 sA2[BM * 32];
  __shared__ bf16 sA3[BM * 32];
  __shared__ bf16 sB1[BN * 32];
  __shared__ bf16 sB2[BN * 32];
  __shared__ bf16 sB3[BN * 32];
  const int tid = threadIdx.x;
  const int z = blockIdx.z;
  const int row0 = blockIdx.y * BM;
  const int col0 = blockIdx.x * BN;
  const int lane = tid & 63;
  const int wv = tid >> 6;
  const int wm = (wv % WGM) * (FM * 16);
  const int wn = (wv / WGM) * (FN * 16);
  const int lps = ((lane >> 4) * 16 + (((lane & 15) + 2 * (lane >> 4)) & 15)) << 4;
  f32x4 acc[FM][FN];
#pragma unroll
  for (int i = 0; i < FM; i++)
#pragma unroll
    for (int j = 0; j < FN; j++)
#pragma unroll
      for (int r = 0; r < 4; r++) acc[i][j][r] = 0.f;

  const int ks = p.ksteps();
  for (int s = 0; s < ks; ++s) {
#pragma unroll
    for (int g0 = 0; g0 < BM * 4; g0 += 256) {
      int g = g0 + tid;
      if (g < BM * 4) {
        int row = g >> 2, k0 = (g & 3) * 8;
        bf16x8 v1, v2, v3;
        p.loadA3(z, row0 + row, k0, s, v1, v2, v3);
        int byte = ldsOff(row, g & 3);
        *(bf16x8*)((char*)sA1 + byte) = v1;
        *(bf16x8*)((char*)sA2 + byte) = v2;
        *(bf16x8*)((char*)sA3 + byte) = v3;
      }
    }
#pragma unroll
    for (int g0 = 0; g0 < BN * 4; g0 += 256) {
      int g = g0 + tid;
      if (g < BN * 4) {
        int row = g >> 2, k0 = (g & 3) * 8;
        bf16x8 v1, v2, v3;
        p.loadB3(z, col0 + row, k0, s, v1, v2, v3);
        int byte = ldsOff(row, g & 3);
        *(bf16x8*)((char*)sB1 + byte) = v1;
        *(bf16x8*)((char*)sB2 + byte) = v2;
        *(bf16x8*)((char*)sB3 + byte) = v3;
      }
    }
    __syncthreads();
    {
      bf16x8 a1[FM], a2[FM], a3[FM], b1[FN], b2[FN], b3[FN];
#pragma unroll
      for (int i = 0; i < FM; i++) {
        int byte = (((wm >> 4) + i) << 10) + lps;
        a1[i] = *(const bf16x8*)((const char*)sA1 + byte);
        a2[i] = *(const bf16x8*)((const char*)sA2 + byte);
        a3[i] = *(const bf16x8*)((const char*)sA3 + byte);
      }
#pragma unroll
      for (int j = 0; j < FN; j++) {
        int byte = (((wn >> 4) + j) << 10) + lps;
        b1[j] = *(const bf16x8*)((const char*)sB1 + byte);
        b2[j] = *(const bf16x8*)((const char*)sB2 + byte);
        b3[j] = *(const bf16x8*)((const char*)sB3 + byte);
      }
#pragma unroll
      for (int i = 0; i < FM; i++)
#pragma unroll
        for (int j = 0; j < FN; j++) {
          acc[i][j] = __builtin_amdgcn_mfma_f32_16x16x32_bf16(a1[i], b1[j], acc[i][j], 0, 0, 0);
          acc[i][j] = __builtin_amdgcn_mfma_f32_16x16x32_bf16(a1[i], b2[j], acc[i][j], 0, 0, 0);
          acc[i][j] = __builtin_amdgcn_mfma_f32_16x16x32_bf16(a2[i], b1[j], acc[i][j], 0, 0, 0);
          acc[i][j] = __builtin_amdgcn_mfma_f32_16x16x32_bf16(a2[i], b2[j], acc[i][j], 0, 0, 0);
          acc[i][j] = __builtin_amdgcn_mfma_f32_16x16x32_bf16(a1[i], b3[j], acc[i][j], 0, 0, 0);
          acc[i][j] = __builtin_amdgcn_mfma_f32_16x16x32_bf16(a3[i], b1[j], acc[i][j], 0, 0, 0);
        }
    }
    __syncthreads();
  }
#pragma unroll
  for (int i = 0; i < FM; i++)
#pragma unroll
    for (int j = 0; j < FN; j++)
#pragma unroll
      for (int rg = 0; rg < 4; rg++) {
        int r = row0 + wm + i * 16 + ((lane >> 4) << 2) + rg;
        int c = col0 + wn + j * 16 + (lane & 15);
        p.store(z, r, c, acc[i][j][rg]);
      }
}

// ---------------- f64-acc 6-term GEMM, reg-prefetch pipelined ----------------
template <int TH, int WGM, int WGN, int FM, int FN, class P>
__global__ __launch_bounds__(TH) void gemm6d(P p) {
  constexpr int BM = WGM * FM * 16;
  constexpr int BN = WGN * FN * 16;
  constexpr int NA = (BM * 4 + TH - 1) / TH;
  constexpr int NB = (BN * 4 + TH - 1) / TH;
  __shared__ bf16 sA1[BM * 32];
  __shared__ bf16 sA2[BM * 32];
  __shared__ bf16 sA3[BM * 32];
  __shared__ bf16 sB1[BN * 32];
  __shared__ bf16 sB2[BN * 32];
  __shared__ bf16 sB3[BN * 32];
  const int tid = threadIdx.x;
  const int z = blockIdx.z;
  const int row0 = blockIdx.y * BM;
  const int col0 = blockIdx.x * BN;
  const int lane = tid & 63;
  const int wv = tid >> 6;
  const int wm = (wv % WGM) * (FM * 16);
  const int wn = (wv / WGM) * (FN * 16);
  const int lps = ((lane >> 4) * 16 + (((lane & 15) + 2 * (lane >> 4)) & 15)) << 4;
  double acc[FM][FN][4];
  f32x4 fmn[FM][FN], fcr[FM][FN];
#pragma unroll
  for (int i = 0; i < FM; i++)
#pragma unroll
    for (int j = 0; j < FN; j++)
#pragma unroll
      for (int r = 0; r < 4; r++) {
        acc[i][j][r] = 0.0;
        fmn[i][j][r] = 0.f;
        fcr[i][j][r] = 0.f;
      }

  bf16x8 gA[NA][3], gB[NB][3];
  auto issue = [&](int s) {
#pragma unroll
    for (int u = 0; u < NA; u++) {
      int g = u * TH + tid;
      if (g < BM * 4) {
        int row = g >> 2, k0 = (g & 3) * 8;
        p.loadA3(z, row0 + row, k0, s, gA[u][0], gA[u][1], gA[u][2]);
      }
    }
#pragma unroll
    for (int u = 0; u < NB; u++) {
      int g = u * TH + tid;
      if (g < BN * 4) {
        int row = g >> 2, k0 = (g & 3) * 8;
        p.loadB3(z, col0 + row, k0, s, gB[u][0], gB[u][1], gB[u][2]);
      }
    }
  };

  const int ks = p.ksteps();
  issue(0);
  for (int s = 0; s < ks; ++s) {
#pragma unroll
    for (int u = 0; u < NA; u++) {
      int g = u * TH + tid;
      if (g < BM * 4) {
        int byte = ldsOff(g >> 2, g & 3);
        *(bf16x8*)((char*)sA1 + byte) = gA[u][0];
        *(bf16x8*)((char*)sA2 + byte) = gA[u][1];
        *(bf16x8*)((char*)sA3 + byte) = gA[u][2];
      }
    }
#pragma unroll
    for (int u = 0; u < NB; u++) {
      int g = u * TH + tid;
      if (g < BN * 4) {
        int byte = ldsOff(g >> 2, g & 3);
        *(bf16x8*)((char*)sB1 + byte) = gB[u][0];
        *(bf16x8*)((char*)sB2 + byte) = gB[u][1];
        *(bf16x8*)((char*)sB3 + byte) = gB[u][2];
      }
    }
    __syncthreads();
    if (s + 1 < ks) issue(s + 1);  // overlap next-tile HBM latency with compute
    {
      bf16x8 a1[FM], a2[FM], a3[FM], b1[FN], b2[FN], b3[FN];
#pragma unroll
      for (int i = 0; i < FM; i++) {
        int byte = (((wm >> 4) + i) << 10) + lps;
        a1[i] = *(const bf16x8*)((const char*)sA1 + byte);
        a2[i] = *(const bf16x8*)((const char*)sA2 + byte);
        a3[i] = *(const bf16x8*)((const char*)sA3 + byte);
      }
#pragma unroll
      for (int j = 0; j < FN; j++) {
        int byte = (((wn >> 4) + j) << 10) + lps;
        b1[j] = *(const bf16x8*)((const char*)sB1 + byte);
        b2[j] = *(const bf16x8*)((const char*)sB2 + byte);
        b3[j] = *(const bf16x8*)((const char*)sB3 + byte);
      }
#pragma unroll
      for (int i = 0; i < FM; i++)
#pragma unroll
        for (int j = 0; j < FN; j++) {
          fmn[i][j] = __builtin_amdgcn_mfma_f32_16x16x32_bf16(a1[i], b1[j], fmn[i][j], 0, 0, 0);
          fcr[i][j] = __builtin_amdgcn_mfma_f32_16x16x32_bf16(a1[i], b2[j], fcr[i][j], 0, 0, 0);
          fcr[i][j] = __builtin_amdgcn_mfma_f32_16x16x32_bf16(a2[i], b1[j], fcr[i][j], 0, 0, 0);
          fcr[i][j] = __builtin_amdgcn_mfma_f32_16x16x32_bf16(a2[i], b2[j], fcr[i][j], 0, 0, 0);
          fcr[i][j] = __builtin_amdgcn_mfma_f32_16x16x32_bf16(a1[i], b3[j], fcr[i][j], 0, 0, 0);
          fcr[i][j] = __builtin_amdgcn_mfma_f32_16x16x32_bf16(a3[i], b1[j], fcr[i][j], 0, 0, 0);
        }
    }
    bool flm = ((s & 1) == 1) || (s == ks - 1);
    bool flc = ((s & 7) == 7) || (s == ks - 1);
    if (flm) {
#pragma unroll
      for (int i = 0; i < FM; i++)
#pragma unroll
        for (int j = 0; j < FN; j++)
#pragma unroll
          for (int r = 0; r < 4; r++) {
            acc[i][j][r] += (double)fmn[i][j][r];
            fmn[i][j][r] = 0.f;
          }
    }
    if (flc) {
#pragma unroll
      for (int i = 0; i < FM; i++)
#pragma unroll
        for (int j = 0; j < FN; j++)
#pragma unroll
          for (int r = 0; r < 4; r++) {
            acc[i][j][r] += (double)fcr[i][j][r];
            fcr[i][j][r] = 0.f;
          }
    }
    __syncthreads();
  }
#pragma unroll
  for (int i = 0; i < FM; i++)
#pragma unroll
    for (int j = 0; j < FN; j++)
#pragma unroll
      for (int rg = 0; rg < 4; rg++) {
        int r = row0 + wm + i * 16 + ((lane >> 4) << 2) + rg;
        int c = col0 + wn + j * 16 + (lane & 15);
        p.store(z, r, c, acc[i][j][rg]);
      }
}

// ---------------- problem structs ----------------
struct P6PROJ {  // OPRE = x_half @ projT ; M=3000 N=1024 K=1024
  const float* x;
  const bf16 *b1, *b2, *b3;
  float* out;
  int rowoff, colbase;
  __device__ int ksteps() const { return 32; }
  __device__ void loadA3(int, int r, int k0, int s, bf16x8& v1, bf16x8& v2, bf16x8& v3) const {
    v1 = bzero8(); v2 = bzero8(); v3 = bzero8();
    if (r >= RPC) return;
    const float* src = x + (size_t)(rowoff + r) * 2048 + colbase + s * 32 + k0;
#pragma unroll
    for (int j = 0; j < 8; j++) {
      bf3 t = split3(src[j]);
      v1[j] = t.h; v2[j] = t.m; v3[j] = t.l;
    }
  }
  __device__ void loadB3(int, int c, int k0, int s, bf16x8& v1, bf16x8& v2, bf16x8& v3) const {
    size_t a = (size_t)c * 1024 + s * 32 + k0;
    v1 = *(const bf16x8*)(b1 + a); v2 = *(const bf16x8*)(b2 + a); v3 = *(const bf16x8*)(b3 + a);
  }
  __device__ void store(int, int r, int c, double v) const {
    if (r < RPC) out[(size_t)r * 1024 + c] = (float)v;
  }
};

struct P6Q {  // Q = o_rgb @ attwT per local pair ; M=750 N=128 K=128
  const bf16 *a1, *a2, *a3, *b1, *b2, *b3;
  bf16 *q1, *q2, *q3;
  __device__ int ksteps() const { return 4; }
  __device__ void loadA3(int z, int r, int k0, int s, bf16x8& v1, bf16x8& v2, bf16x8& v3) const {
    if (r >= 750) { v1 = bzero8(); v2 = bzero8(); v3 = bzero8(); return; }
    size_t a = (size_t)z * 96000 + (size_t)r * 128 + s * 32 + k0;
    v1 = *(const bf16x8*)(a1 + a); v2 = *(const bf16x8*)(a2 + a); v3 = *(const bf16x8*)(a3 + a);
  }
  __device__ void loadB3(int z, int c, int k0, int s, bf16x8& v1, bf16x8& v2, bf16x8& v3) const {
    size_t a = (size_t)(z & 7) * 16384 + (size_t)c * 128 + s * 32 + k0;
    v1 = *(const bf16x8*)(b1 + a); v2 = *(const bf16x8*)(b2 + a); v3 = *(const bf16x8*)(b3 + a);
  }
  __device__ void store(int z, int r, int c, float v) const {
    if (r >= 750) return;
    size_t a = (size_t)z * 96000 + (size_t)r * 128 + c;
    bf3 t = split3(v);
    q1[a] = t.h; q2[a] = t.m; q3[a] = t.l;
  }
};

struct P6S {  // P = exp(Q @ o_flow^T) per local pair ; M=N=750 K=128
  const bf16 *a1, *a2, *a3, *b1, *b2, *b3;
  float* out;
  __device__ int ksteps() const { return 4; }
  __device__ void loadA3(int z, int r, int k0, int s, bf16x8& v1, bf16x8& v2, bf16x8& v3) const {
    if (r >= 750) { v1 = bzero8(); v2 = bzero8(); v3 = bzero8(); return; }
    size_t a = (size_t)z * 96000 + (size_t)r * 128 + s * 32 + k0;
    v1 = *(const bf16x8*)(a1 + a); v2 = *(const bf16x8*)(a2 + a); v3 = *(const bf16x8*)(a3 + a);
  }
  __device__ void loadB3(int z, int c, int k0, int s, bf16x8& v1, bf16x8& v2, bf16x8& v3) const {
    if (c >= 750) { v1 = bzero8(); v2 = bzero8(); v3 = bzero8(); return; }
    size_t a = (size_t)z * 96000 + (size_t)c * 128 + s * 32 + k0;
    v1 = *(const bf16x8*)(b1 + a); v2 = *(const bf16x8*)(b2 + a); v3 = *(const bf16x8*)(b3 + a);
  }
  __device__ void store(int z, int r, int c, float v) const {
    if (r < 750 && c < 750) out[(size_t)z * SPAIR + (size_t)r * SROW + c] = expf(v);
  }
};

struct P6E {  // xc-half = (P/Z) @ oT^T (both rgb & flow via z), gelu+tanh epilogue
  const float *Pr, *Pt;          // row-softmax P and transposed P
  const float *invr, *invc;
  const bf16 *br1, *br2, *br3;   // OTR planes
  const bf16 *bt1, *bt2, *bt3;   // OTF planes
  const float* x;
  bf16 *xc1, *xc2, *xc3;
  int pairbase;
  __device__ int ksteps() const { return 24; }
  __device__ void loadA3(int z, int r, int k0, int s, bf16x8& v1, bf16x8& v2, bf16x8& v3) const {
    v1 = bzero8(); v2 = bzero8(); v3 = bzero8();
    if (r >= 750) return;
    int zp = z & 31;
    const float* Pm = (z < 32) ? Pr : Pt;
    const float* inv = (z < 32) ? invr : invc;
    int m0 = s * 32 + k0;
    const float* row = Pm + (size_t)zp * SPAIR + (size_t)r * SROW;
    float sc = inv[zp * 750 + r];
#pragma unroll
    for (int j = 0; j < 8; j++) {
      int m = m0 + j;
      if (m < 750) {
        bf3 t = split3(row[m] * sc);
        v1[j] = t.h; v2[j] = t.m; v3[j] = t.l;
      }
    }
  }
  __device__ void loadB3(int z, int c, int k0, int s, bf16x8& v1, bf16x8& v2, bf16x8& v3) const {
    int zp = z & 31;
    size_t a = (size_t)zp * 98304 + (size_t)c * 768 + s * 32 + k0;
    if (z < 32) {
      v1 = *(const bf16x8*)(br1 + a); v2 = *(const bf16x8*)(br2 + a); v3 = *(const bf16x8*)(br3 + a);
    } else {
      v1 = *(const bf16x8*)(bt1 + a); v2 = *(const bf16x8*)(bt2 + a); v3 = *(const bf16x8*)(bt3 + a);
    }
  }
  __device__ void store(int z, int r, int c, float v) const {
    if (r >= 750) return;
    int zp = z & 31;
    int gp = pairbase + zp;
    int hh = gp & 7, n = gp >> 3;
    int xcol = ((z < 32) ? 0 : 1024) + hh * 128 + c;
    float g = 0.5f * v * (1.f + erff(v * 0.70710678118654752f));
    float f = tanhf(g + x[((size_t)n * 750 + r) * 2048 + xcol]);
    size_t a = (size_t)(n * PT + r + 4) * 2048 + xcol;
    bf3 t = split3(f);
    xc1[a] = t.h; xc2[a] = t.m; xc3[a] = t.l;
  }
};

struct P6CONV {  // emb = relu(conv9(xc, W) + b)
  const bf16 *a1, *a2, *a3, *b1, *b2, *b3;
  const float* bias;
  bf16 *o1, *o2, *o3;
  __device__ int ksteps() const { return 576; }
  __device__ void loadA3(int, int r, int k0, int s, bf16x8& v1, bf16x8& v2, bf16x8& v3) const {
    if (r >= MM) { v1 = bzero8(); v2 = bzero8(); v3 = bzero8(); return; }
    int ktap = s >> 6, kb = s & 63;
    int n = (unsigned)r / 750u;
    size_t a = (size_t)(r + 8 * n + ktap) * 2048 + kb * 32 + k0;
    v1 = *(const bf16x8*)(a1 + a); v2 = *(const bf16x8*)(a2 + a); v3 = *(const bf16x8*)(a3 + a);
  }
  __device__ void loadB3(int, int c, int k0, int s, bf16x8& v1, bf16x8& v2, bf16x8& v3) const {
    int ktap = s >> 6, kb = s & 63;
    size_t a = ((size_t)(ktap * 2048 + c)) * 2048 + kb * 32 + k0;
    v1 = *(const bf16x8*)(b1 + a); v2 = *(const bf16x8*)(b2 + a); v3 = *(const bf16x8*)(b3 + a);
  }
  __device__ void store(int, int r, int c, double v) const {
    if (r >= MM) return;
    v += (double)bias[c];
    if (v < 0) v = 0;
    int n = (unsigned)r / 750u;
    size_t a = (size_t)(r + 8 * n + 4) * 2048 + c;
    bf3 t = split3((float)v);
    o1[a] = t.h; o2[a] = t.m; o3[a] = t.l;
  }
};

struct P6CLS1 {  // cas1 = conv9(emb, cls1_w), N=32 (20 used)
  const bf16 *a1, *a2, *a3, *b1, *b2, *b3;
  float* out;
  __device__ int ksteps() const { return 576; }
  __device__ void loadA3(int, int r, int k0, int s, bf16x8& v1, bf16x8& v2, bf16x8& v3) const {
    if (r >= MM) { v1 = bzero8(); v2 = bzero8(); v3 = bzero8(); return; }
    int ktap = s >> 6, kb = s & 63;
    int n = (unsigned)r / 750u;
    size_t a = (size_t)(r + 8 * n + ktap) * 2048 + kb * 32 + k0;
    v1 = *(const bf16x8*)(a1 + a); v2 = *(const bf16x8*)(a2 + a); v3 = *(const bf16x8*)(a3 + a);
  }
  __device__ void loadB3(int, int c, int k0, int s, bf16x8& v1, bf16x8& v2, bf16x8& v3) const {
    int ktap = s >> 6, kb = s & 63;
    size_t a = ((size_t)(ktap * 32 + c)) * 2048 + kb * 32 + k0;
    v1 = *(const bf16x8*)(b1 + a); v2 = *(const bf16x8*)(b2 + a); v3 = *(const bf16x8*)(b3 + a);
  }
  __device__ void store(int, int r, int c, double v) const {
    if (r < MM && c < NC) out[(size_t)r * NC + c] = (float)v;
  }
};

// ---------------- misc kernels ----------------
__global__ void k_split_projT3(const float* rgbp, const float* flowp, bf16* r1, bf16* r2, bf16* r3,
                               bf16* f1, bf16* f2, bf16* f3) {
  int bx = blockIdx.x;
  int st = bx >> 10, c = bx & 1023;
  int h = c >> 7, e = c & 127;
  const float* src = st ? flowp : rgbp;
  bf16* o1 = st ? f1 : r1;
  bf16* o2 = st ? f2 : r2;
  bf16* o3 = st ? f3 : r3;
  int d0 = threadIdx.x * 4;
  bf16x4 a, b, cc;
#pragma unroll
  for (int j = 0; j < 4; j++) {
    bf3 t = split3(src[(size_t)h * 131072 + (size_t)(d0 + j) * 128 + e]);
    a[j] = t.h; b[j] = t.m; cc[j] = t.l;
  }
  size_t o = (size_t)c * 1024 + d0;
  *(bf16x4*)(o1 + o) = a;
  *(bf16x4*)(o2 + o) = b;
  *(bf16x4*)(o3 + o) = cc;
}

__global__ void k_split_attewT3(const float* aw, bf16* w1, bf16* w2, bf16* w3) {
  int b = blockIdx.x;
  int h = b >> 7, f = b & 127;
  int e = threadIdx.x;
  bf3 t = split3(aw[(size_t)h * 16384 + (size_t)e * 128 + f]);
  size_t a = (size_t)h * 16384 + (size_t)f * 128 + e;
  w1[a] = t.h; w2[a] = t.m; w3[a] = t.l;
}

__global__ void k_split_wt3(const float* ew, bf16* w1, bf16* w2, bf16* w3) {
  __shared__ float tmp[1152];
  int o = blockIdx.x >> 4, ic0 = (blockIdx.x & 15) << 7;
  for (int t = threadIdx.x; t < 1152; t += 256)
    tmp[t] = ew[(size_t)o * 18432 + (size_t)ic0 * 9 + t];
  __syncthreads();
  for (int w = threadIdx.x; w < 1152; w += 256) {
    int k = w >> 7, i = w & 127;
    bf3 t = split3(tmp[i * 9 + k]);
    size_t a = ((size_t)(k * 2048 + o)) * 2048 + ic0 + i;
    w1[a] = t.h; w2[a] = t.m; w3[a] = t.l;
  }
}

__global__ void k_split_wc3(const float* cw, bf16* w1, bf16* w2, bf16* w3) {
  int k = blockIdx.x / 32, c = blockIdx.x % 32;
  for (int i = threadIdx.x; i < 2048; i += 256) {
    float v = (c < NC) ? cw[(size_t)c * 18432 + (size_t)i * 9 + k] : 0.f;
    bf3 t = split3(v);
    size_t a = ((size_t)(k * 32 + c)) * 2048 + i;
    w1[a] = t.h; w2[a] = t.m; w3[a] = t.l;
  }
}

__global__ void k_norm3(const float* opre, bf16* o1, bf16* o2, bf16* o3) {
  int r = blockIdx.x;  // 0..2999 local
  int head = threadIdx.x >> 5, ln = threadIdx.x & 31;
  const float* src = opre + (size_t)r * 1024 + head * 128 + ln * 4;
  float4 v = *(const float4*)src;
  double ss = (double)v.x * v.x + (double)v.y * v.y + (double)v.z * v.z + (double)v.w * v.w;
  for (int k = 16; k; k >>= 1) ss += __shfl_xor(ss, k, 32);
  double rn = 1.0 / fmax(sqrt(ss), 1e-12);
  int nl = r / 750, l = r % 750;
  int zp = nl * 8 + head;
  size_t o = (size_t)zp * 96000 + (size_t)l * 128 + ln * 4;
  float vv[4] = {v.x, v.y, v.z, v.w};
  bf16x4 h4, m4, l4;
#pragma unroll
  for (int j = 0; j < 4; j++) {
    bf3 t = split3((float)((double)vv[j] * rn));
    h4[j] = t.h; m4[j] = t.m; l4[j] = t.l;
  }
  *(bf16x4*)(o1 + o) = h4;
  *(bf16x4*)(o2 + o) = m4;
  *(bf16x4*)(o3 + o) = l4;
}

__global__ void k_trans3(const bf16* i1, const bf16* i2, const bf16* i3, bf16* o1, bf16* o2,
                         bf16* o3) {
  __shared__ bf16 t1[32][33], t2[32][33], t3[32][33];
  int zp = blockIdx.y;
  int lt = blockIdx.x >> 2, et = blockIdx.x & 3;
  int tx = threadIdx.x & 31, ty = threadIdx.x >> 5;
#pragma unroll
  for (int p = 0; p < 4; p++) {
    int lrow = lt * 32 + ty + p * 8;
    int e = et * 32 + tx;
    bf16 a = (bf16)0.f, b = (bf16)0.f, c = (bf16)0.f;
    if (lrow < 750) {
      size_t ad = (size_t)zp * 96000 + (size_t)lrow * 128 + e;
      a = i1[ad]; b = i2[ad]; c = i3[ad];
    }
    t1[ty + p * 8][tx] = a;
    t2[ty + p * 8][tx] = b;
    t3[ty + p * 8][tx] = c;
  }
  __syncthreads();
#pragma unroll
  for (int p = 0; p < 4; p++) {
    int e = et * 32 + ty + p * 8;
    int l2 = lt * 32 + tx;
    size_t ad = (size_t)zp * 98304 + (size_t)e * 768 + l2;
    o1[ad] = t1[tx][ty + p * 8];
    o2[ad] = t2[tx][ty + p * 8];
    o3[ad] = t3[tx][ty + p * 8];
  }
}

__global__ void k_transS(const float* S, float* ST) {
  __shared__ float t[32][33];
  int zp = blockIdx.y;
  int tr = (blockIdx.x / 24) * 32, tc = (blockIdx.x % 24) * 32;
  int tx = threadIdx.x & 31, ty = threadIdx.x >> 5;
#pragma unroll
  for (int p = 0; p < 4; p++) {
    int rr = tr + ty + p * 8, cc = tc + tx;
    t[ty + p * 8][tx] = (rr < 750 && cc < 750) ? S[(size_t)zp * SPAIR + (size_t)rr * SROW + cc] : 0.f;
  }
  __syncthreads();
#pragma unroll
  for (int p = 0; p < 4; p++) {
    int cc = tc + ty + p * 8, rr = tr + tx;
    if (cc < 750 && rr < 750) ST[(size_t)zp * SPAIR + (size_t)cc * SROW + rr] = t[tx][ty + p * 8];
  }
}

__global__ void k_statsd(const float* P, float* inv) {
  int b = blockIdx.x;
  int p = b / 94, r0 = (b % 94) * 8;
  int g = threadIdx.x >> 5, ln = threadIdx.x & 31;
  int r = r0 + g;
  if (r >= 750) return;
  const float* row = P + (size_t)p * SPAIR + (size_t)r * SROW;
  double s = 0.0;
  for (int m = ln; m < 750; m += 32) s += (double)row[m];
  for (int k = 16; k; k >>= 1) s += __shfl_xor(s, k, 32);
  if (ln == 0) inv[p * 750 + r] = (float)(1.0 / s);
}

__global__ void k_cls2(const float* cas1, const float* w2, float* cas_out, float* cast) {
  int idx = blockIdx.x * 256 + threadIdx.x;
  if (idx >= MM * NC) return;
  int r = idx / NC, c = idx % NC;
  int n = r / 750, t = r % 750;
  double a = 0.0;
#pragma unroll
  for (int j = 0; j < 7; j++) {
    int tt = t + 2 * j - 6;
    if (tt >= 0 && tt < 750)
      a += (double)w2[c * 7 + j] * (double)cas1[((size_t)n * 750 + tt) * NC + c];
  }
  if (a < 0) a = 0;
  cas_out[idx] = (float)a;
  cast[((size_t)n * NC + c) * 750 + t] = (float)a;
}

__global__ void k_act(const float* cas, float* act, float* out_act) {
  int r = blockIdx.x * 256 + threadIdx.x;
  if (r >= MM) return;
  double s = 0.0;
#pragma unroll
  for (int c = 0; c < NC; c++) s += (double)cas[(size_t)r * NC + c];
  act[r] = (float)s;
  out_act[r] = (float)s;
}

__global__ __launch_bounds__(512) void k_mask(const float* act, float* arev, float* inner,
                                              float* outer) {
  __shared__ u64 ks[1024];
  __shared__ float av[768];
  __shared__ float bb[768];
  int n = blockIdx.x;
  for (int i = threadIdx.x; i < 1024; i += 512) {
    if (i < 750) {
      float v = act[n * 750 + i];
      av[i] = v;
      ks[i] = ((u64)asc_enc(v) << 32) | (u32)i;
    } else
      ks[i] = ~0ull;
  }
  bsort1024(ks);
  float med = 0.5f * (asc_dec((u32)(ks[374] >> 32)) + asc_dec((u32)(ks[375] >> 32)));
  float amax = asc_dec((u32)(ks[749] >> 32));
  for (int t = threadIdx.x; t < 750; t += 512) bb[t] = (av[t] > med) ? 1.f : 0.f;
  __syncthreads();
  for (int t = threadIdx.x; t < 750; t += 512) {
    float e3 = 1.f, e6 = 1.f, d3 = 0.f, d6 = 0.f;
    for (int j = t - 1; j <= t + 1; ++j) {
      float v = (j >= 0 && j < 750) ? bb[j] : 0.f;
      e3 = fminf(e3, v); d3 = fmaxf(d3, v);
    }
    for (int j = t - 3; j <= t + 2; ++j) {
      float v = (j >= 0 && j < 750) ? bb[j] : 0.f;
      e6 = fminf(e6, v);
    }
    for (int j = t - 2; j <= t + 3; ++j) {
      float v = (j >= 0 && j < 750) ? bb[j] : 0.f;
      d6 = fmaxf(d6, v);
    }
    int g = n * 750 + t;
    inner[g] = (e3 - e6 > 0.5f) ? av[t] : 0.f;
    outer[g] = (d6 - d3 > 0.5f) ? av[t] : 0.f;
    arev[g] = amax - av[t];
  }
}

__global__ __launch_bounds__(512) void k_topk(const float* act, const float* arev,
                                              const float* inner, const float* outer, int* idxb) {
  __shared__ u64 ks[1024];
  int n = blockIdx.x >> 2, w = blockIdx.x & 3;
  const float* src = (w == 0) ? act : ((w == 1) ? arev : ((w == 2) ? inner : outer));
  int K = (w < 2) ? KE : KH;
  int off = (w == 0) ? 0 : ((w == 1) ? 150 : ((w == 2) ? 300 : 337));
  for (int i = threadIdx.x; i < 1024; i += 512) {
    if (i < 750) {
      u32 d = ~asc_enc(src[n * 750 + i]);
      ks[i] = ((u64)d << 32) | (u32)i;
    } else
      ks[i] = ~0ull;
  }
  bsort1024(ks);
  for (int i = threadIdx.x; i < K; i += 512) idxb[n * 374 + off + i] = (int)(ks[i] & 0xFFFFFFFFu);
}

__global__ __launch_bounds__(512) void k_topcas(const float* cast, float* smean) {
  __shared__ u64 ks[1024];
  __shared__ float red[512];
  int b = blockIdx.x;
  for (int i = threadIdx.x; i < 1024; i += 512) {
    if (i < 750) {
      u32 d = ~asc_enc(cast[(size_t)b * 750 + i]);
      ks[i] = ((u64)d << 32) | (u32)i;
    } else
      ks[i] = ~0ull;
  }
  bsort1024(ks);
  float s = 0.f;
  for (int i = threadIdx.x; i < KE; i += 512) s += asc_dec(~(u32)(ks[i] >> 32));
  red[threadIdx.x] = s;
  __syncthreads();
  for (int st = 256; st; st >>= 1) {
    if (threadIdx.x < st) red[threadIdx.x] += red[threadIdx.x + st];
    __syncthreads();
  }
  if (threadIdx.x == 0) smean[b] = red[0] / 150.f;
}

__global__ void k_gather(const int* idxb, const bf16* e1, const bf16* e2, const bf16* e3,
                         float* dout) {
  int b = blockIdx.x;
  int n = b / 374, j = b % 374;
  size_t obase;
  if (j < 150) obase = OUT_EA + ((size_t)n * KE + j) * 2048;
  else if (j < 300) obase = OUT_EB + ((size_t)n * KE + (j - 150)) * 2048;
  else if (j < 337) obase = OUT_HA + ((size_t)n * KH + (j - 300)) * 2048;
  else obase = OUT_HB + ((size_t)n * KH + (j - 337)) * 2048;
  int t = idxb[n * 374 + j];
  size_t irow = (size_t)(n * PT + t + 4) * 2048;
#pragma unroll
  for (int p = 0; p < 8; p++) {
    int c = threadIdx.x + p * 256;
    dout[obase + c] = (float)e1[irow + c] + (float)e2[irow + c] + (float)e3[irow + c];
  }
}

__global__ void k_vs(const float* smean, float* dout) {
  int n = blockIdx.x;
  int c = threadIdx.x;
  float v = (c < NC) ? smean[n * NC + c] : -3.4e38f;
  float m = v;
  for (int s = 32; s; s >>= 1) m = fmaxf(m, __shfl_xor(m, s));
  float e = (c < NC) ? expf(v - m) : 0.f;
  float sum = e;
  for (int s = 32; s; s >>= 1) sum += __shfl_xor(sum, s);
  if (c < NC) dout[n * NC + c] = e / sum;
}

// ---------------- host ----------------
extern "C" void kernel_launch(void* const* d_in, const int* in_sizes, int n_in, void* d_out,
                              int out_size, void* d_ws, size_t ws_size, hipStream_t stream) {
  const float* x = (const float*)d_in[0];
  const float* rgbp = (const float*)d_in[1];
  const float* flowp = (const float*)d_in[2];
  const float* attw = (const float*)d_in[3];
  const float* embw = (const float*)d_in[4];
  const float* embb = (const float*)d_in[5];
  const float* c1w = (const float*)d_in[6];
  const float* c2w = (const float*)d_in[7];
  float* dout = (float*)d_out;
  char* ws = (char*)d_ws;

  if (ws_size < WS_NEED) {
    fprintf(stderr, "[CoLA] FATAL ws_size=%zu < need=%zu\n", ws_size, (size_t)WS_NEED);
    return;
  }

  bf16* XC1 = (bf16*)(ws + O_XC1);
  bf16* XC2 = (bf16*)(ws + O_XC2);
  bf16* XC3 = (bf16*)(ws + O_XC3);
  bf16* EM1 = (bf16*)(ws + O_EM1);
  bf16* EM2 = (bf16*)(ws + O_EM2);
  bf16* EM3 = (bf16*)(ws + O_EM3);
  float* CAS1 = (float*)(ws + O_CAS1);
  float* CAST = (float*)(ws + O_CAST);
  float* ACT = (float*)(ws + O_ACT);
  float* AREV = (float*)(ws + O_AREV);
  float* INNER = (float*)(ws + O_INNER);
  float* OUTER = (float*)(ws + O_OUTER);
  float* SMEAN = (float*)(ws + O_SMEAN);
  int* IDX = (int*)(ws + O_IDX);
  float* RSINV = (float*)(ws + O_RSINV);
  float* CSINV = (float*)(ws + O_CSINV);
  float* SBUF = (float*)(ws + O_S);
  float* STBUF = (float*)(ws + O_ST);
  bf16 *Q1 = (bf16*)(ws + O_Q1), *Q2 = (bf16*)(ws + O_Q2), *Q3 = (bf16*)(ws + O_Q3);
  bf16 *OR1 = (bf16*)(ws + O_OR1), *OR2 = (bf16*)(ws + O_OR2), *OR3 = (bf16*)(ws + O_OR3);
  bf16 *OF1 = (bf16*)(ws + O_OF1), *OF2 = (bf16*)(ws + O_OF2), *OF3 = (bf16*)(ws + O_OF3);
  bf16 *OTR1 = (bf16*)(ws + O_OTR1), *OTR2 = (bf16*)(ws + O_OTR2), *OTR3 = (bf16*)(ws + O_OTR3);
  bf16 *OTF1 = (bf16*)(ws + O_OTF1), *OTF2 = (bf16*)(ws + O_OTF2), *OTF3 = (bf16*)(ws + O_OTF3);
  float* OPRE = (float*)(ws + O_OPRE);
  bf16 *PR1 = (bf16*)(ws + O_PR1), *PR2 = (bf16*)(ws + O_PR2), *PR3 = (bf16*)(ws + O_PR3);
  bf16 *PF1 = (bf16*)(ws + O_PF1), *PF2 = (bf16*)(ws + O_PF2), *PF3 = (bf16*)(ws + O_PF3);
  bf16 *AW1 = (bf16*)(ws + O_AW1), *AW2 = (bf16*)(ws + O_AW2), *AW3 = (bf16*)(ws + O_AW3);
  bf16 *WT1 = (bf16*)(ws + O_WT1), *WT2 = (bf16*)(ws + O_WT2), *WT3 = (bf16*)(ws + O_WT3);
  bf16 *WC1 = (bf16*)(ws + O_WC1), *WC2 = (bf16*)(ws + O_WC2), *WC3 = (bf16*)(ws + O_WC3);

  (void)hipMemsetAsync(ws, 0, O_CAS1, stream);  // zero 6 padded planes

  k_split_projT3<<<2048, 256, 0, stream>>>(rgbp, flowp, PR1, PR2, PR3, PF1, PF2, PF3);
  k_split_attewT3<<<1024, 128, 0, stream>>>(attw, AW1, AW2, AW3);

  for (int cb = 0; cb < NCHUNK; cb++) {
    int rowoff = cb * RPC;
    int pb = cb * PCH;
    // rgb: proj -> norm -> trans -> q
    {
      P6PROJ p{x, PR1, PR2, PR3, OPRE, rowoff, 0};
      gemm6d<512, 2, 4, 4, 2, P6PROJ><<<dim3(8, 24, 1), 512, 0, stream>>>(p);
    }
    k_norm3<<<RPC, 256, 0, stream>>>(OPRE, OR1, OR2, OR3);
    k_trans3<<<dim3(96, 32), 256, 0, stream>>>(OR1, OR2, OR3, OTR1, OTR2, OTR3);
    {
      P6Q p{OR1, OR2, OR3, AW1, AW2, AW3, Q1, Q2, Q3};
      gemm6<2, 2, 4, 4, P6Q><<<dim3(1, 6, PCH), 256, 0, stream>>>(p);
    }
    // flow: proj -> norm -> trans
    {
      P6PROJ p{x, PF1, PF2, PF3, OPRE, rowoff, 1024};
      gemm6d<512, 2, 4, 4, 2, P6PROJ><<<dim3(8, 24, 1), 512, 0, stream>>>(p);
    }
    k_norm3<<<RPC, 256, 0, stream>>>(OPRE, OF1, OF2, OF3);
    k_trans3<<<dim3(96, 32), 256, 0, stream>>>(OF1, OF2, OF3, OTF1, OTF2, OTF3);
    // P = exp(S), transpose, softmax denominators, fused e-GEMMs (rgb+flow in one)
    {
      P6S p{Q1, Q2, Q3, OF1, OF2, OF3, SBUF};
      gemm6<2, 2, 4, 4, P6S><<<dim3(6, 6, PCH), 256, 0, stream>>>(p);
    }
    k_transS<<<dim3(576, PCH), 256, 0, stream>>>(SBUF, STBUF);
    k_statsd<<<PCH * 94, 256, 0, stream>>>(SBUF, RSINV);
    k_statsd<<<PCH * 94, 256, 0, stream>>>(STBUF, CSINV);
    {
      P6E p{SBUF, STBUF, RSINV, CSINV, OTR1, OTR2, OTR3, OTF1, OTF2, OTF3, x, XC1, XC2, XC3, pb};
      gemm6<2, 2, 4, 4, P6E><<<dim3(1, 6, 2 * PCH), 256, 0, stream>>>(p);
    }
  }

  // conv weights (alias dead attention arena), conv GEMMs
  k_split_wt3<<<32768, 256, 0, stream>>>(embw, WT1, WT2, WT3);
  k_split_wc3<<<288, 256, 0, stream>>>(c1w, WC1, WC2, WC3);
  {
    P6CONV p{XC1, XC2, XC3, WT1, WT2, WT3, embb, EM1, EM2, EM3};
    gemm6d<512, 2, 4, 4, 2, P6CONV><<<dim3(16, 94, 1), 512, 0, stream>>>(p);
  }
  {
    P6CLS1 p{EM1, EM2, EM3, WC1, WC2, WC3, CAS1};
    gemm6d<512, 4, 2, 2, 1, P6CLS1><<<dim3(1, 94, 1), 512, 0, stream>>>(p);
  }
  k_cls2<<<(MM * NC + 255) / 256, 256, 0, stream>>>(CAS1, c2w, dout + OUT_CAS, CAST);
  k_act<<<(MM + 255) / 256, 256, 0, stream>>>(dout + OUT_CAS, ACT, dout + OUT_ACT);

  // postprocess
  k_mask<<<16, 512, 0, stream>>>(ACT, AREV, INNER, OUTER);
  k_topk<<<64, 512, 0, stream>>>(ACT, AREV, INNER, OUTER, IDX);
  k_topcas<<<320, 512, 0, stream>>>(CAST, SMEAN);
  k_gather<<<16 * 374, 256, 0, stream>>>(IDX, EM1, EM2, EM3, dout);
  k_vs<<<16, 64, 0, stream>>>(SMEAN, dout);
}

// Round 12
// 8754.311 us; speedup vs baseline: 1.4477x; 1.0305x over previous
//
#include <hip/hip_runtime.h>
#include <cstdio>
#include <cstdint>

typedef __bf16 bf16;
typedef __attribute__((ext_vector_type(8))) __bf16 bf16x8;
typedef __attribute__((ext_vector_type(4))) __bf16 bf16x4;
typedef __attribute__((ext_vector_type(4))) float f32x4;
typedef unsigned long long u64;
typedef unsigned int u32;

// ---------------- problem dims ----------------
constexpr int BATCH = 16, TT = 750, DD = 2048, NC = 20;
constexpr int MM = 12000;
constexpr int PT = 758;            // padded T (4+750+4)
constexpr int PCH = 32;            // pairs per chunk (4 batches x 8 heads)
constexpr int NCHUNK = 4;
constexpr int RPC = 3000;          // x rows per chunk
constexpr int SROW = 752;
constexpr int SPAIR = 750 * SROW;  // 564000
constexpr int KE = 150, KH = 37;

// ---------------- output offsets (floats) ----------------
constexpr size_t OUT_EA  = 320;
constexpr size_t OUT_EB  = OUT_EA + (size_t)BATCH * KE * DD;
constexpr size_t OUT_HA  = OUT_EB + (size_t)BATCH * KE * DD;
constexpr size_t OUT_HB  = OUT_HA + (size_t)BATCH * KH * DD;
constexpr size_t OUT_ACT = OUT_HB + (size_t)BATCH * KH * DD;
constexpr size_t OUT_CAS = OUT_ACT + MM;

// ---------------- workspace (bytes) ----------------
constexpr size_t XCB = (size_t)(BATCH * PT) * DD * 2;   // 49,676,288
constexpr size_t O_XC1   = 0;
constexpr size_t O_XC2   = O_XC1 + XCB;
constexpr size_t O_XC3   = O_XC2 + XCB;
constexpr size_t O_EM1   = O_XC3 + XCB;
constexpr size_t O_EM2   = O_EM1 + XCB;
constexpr size_t O_EM3   = O_EM2 + XCB;
constexpr size_t O_CAS1  = O_EM3 + XCB;                  // 298,057,728
constexpr size_t O_CAST  = O_CAS1 + 960000;
constexpr size_t O_ACT   = O_CAST + 960000;
constexpr size_t O_AREV  = O_ACT + 48000;
constexpr size_t O_INNER = O_AREV + 48000;
constexpr size_t O_OUTER = O_INNER + 48000;
constexpr size_t O_SMEAN = O_OUTER + 48000;
constexpr size_t O_IDX   = O_SMEAN + 1280;
constexpr size_t O_RSINV = O_IDX + 23936;
constexpr size_t O_CSINV = O_RSINV + 96000;
constexpr size_t O_DBG   = O_CSINV + 96000;
constexpr size_t AR      = O_DBG + 256;                  // 300,387,200

constexpr size_t SB   = (size_t)PCH * SPAIR * 4;         // 72,192,000
constexpr size_t PL   = (size_t)PCH * 750 * 128 * 2;     // 6,144,000  o plane
constexpr size_t TPL  = (size_t)PCH * 128 * 768 * 2;     // 6,291,456  oT plane
constexpr size_t O_S    = AR;
constexpr size_t O_ST   = O_S + SB;
constexpr size_t O_Q1   = O_ST + SB;
constexpr size_t O_Q2   = O_Q1 + PL;
constexpr size_t O_Q3   = O_Q2 + PL;
constexpr size_t O_OR1  = O_Q3 + PL;
constexpr size_t O_OR2  = O_OR1 + PL;
constexpr size_t O_OR3  = O_OR2 + PL;
constexpr size_t O_OF1  = O_OR3 + PL;
constexpr size_t O_OF2  = O_OF1 + PL;
constexpr size_t O_OF3  = O_OF2 + PL;
constexpr size_t O_OTR1 = O_OF3 + PL;
constexpr size_t O_OTR2 = O_OTR1 + TPL;
constexpr size_t O_OTR3 = O_OTR2 + TPL;
constexpr size_t O_OTF1 = O_OTR3 + TPL;
constexpr size_t O_OTF2 = O_OTF1 + TPL;
constexpr size_t O_OTF3 = O_OTF2 + TPL;
constexpr size_t O_OPRE = O_OTF3 + TPL;                  // RPC*1024*4
constexpr size_t PRP  = (size_t)1024 * 1024 * 2;
constexpr size_t O_PR1  = O_OPRE + (size_t)RPC * 1024 * 4;
constexpr size_t O_PR2  = O_PR1 + PRP;
constexpr size_t O_PR3  = O_PR2 + PRP;
constexpr size_t O_PF1  = O_PR3 + PRP;
constexpr size_t O_PF2  = O_PF1 + PRP;
constexpr size_t O_PF3  = O_PF2 + PRP;
constexpr size_t AWP  = (size_t)8 * 128 * 128 * 2;
constexpr size_t O_AW1  = O_PF3 + PRP;
constexpr size_t O_AW2  = O_AW1 + AWP;
constexpr size_t O_AW3  = O_AW2 + AWP;
constexpr size_t WS_NEED = O_AW3 + AWP;                  // 563,473,280

// conv weights alias dead attention arena
constexpr size_t WTP  = (size_t)9 * 2048 * 2048 * 2;     // 75,497,472 (= 576*128*64*16)
constexpr size_t O_WT1  = AR;
constexpr size_t O_WT2  = O_WT1 + WTP;
constexpr size_t O_WT3  = O_WT2 + WTP;
constexpr size_t WCP  = (size_t)9 * 32 * 2048 * 2;
constexpr size_t O_WC1  = O_WT3 + WTP;
constexpr size_t O_WC2  = O_WC1 + WCP;
constexpr size_t O_WC3  = O_WC2 + WCP;

static_assert(O_WC3 + WCP <= WS_NEED, "WT/WC overrun");
static_assert(WS_NEED <= 603979776, "exceeds harness ws");

// ---------------- helpers ----------------
struct bf3 { bf16 h, m, l; };
static __device__ __forceinline__ bf3 split3(float v) {
  bf3 r;
  r.h = (bf16)v;
  float rem = v - (float)r.h;
  r.m = (bf16)rem;
  r.l = (bf16)(rem - (float)r.m);
  return r;
}
static __device__ __forceinline__ bf16x8 bzero8() {
  bf16x8 v;
#pragma unroll
  for (int i = 0; i < 8; i++) v[i] = (bf16)0.f;
  return v;
}
static __device__ __forceinline__ u32 asc_enc(float f) {
  u32 u = __float_as_uint(f);
  return (u & 0x80000000u) ? ~u : (u | 0x80000000u);
}
static __device__ __forceinline__ float asc_dec(u32 a) {
  u32 u = (a & 0x80000000u) ? (a ^ 0x80000000u) : ~a;
  return __uint_as_float(u);
}
static __device__ void bsort1024(u64* ks) {
  const int tid = threadIdx.x;
  for (int kk = 2; kk <= 1024; kk <<= 1) {
    for (int j = kk >> 1; j > 0; j >>= 1) {
      __syncthreads();
      for (int i = tid; i < 1024; i += 512) {
        int ixj = i ^ j;
        if (ixj > i) {
          u64 a = ks[i], b = ks[ixj];
          bool up = ((i & kk) == 0);
          if ((a > b) == up) { ks[i] = b; ks[ixj] = a; }
        }
      }
    }
  }
  __syncthreads();
}

// Fragment-linear conflict-free LDS layout (see round 10).
static __device__ __forceinline__ int ldsOff(int row, int kc) {
  return ((row >> 4) << 10) + ((kc * 16 + (((row & 15) + 2 * kc) & 15)) << 4);
}

// ---------------- f32-acc 6-term GEMM (3-plane operands, BK=32) ----------------
template <int WGM, int WGN, int FM, int FN, class P>
__global__ __launch_bounds__(256) void gemm6(P p) {
  constexpr int BM = WGM * FM * 16;
  constexpr int BN = WGN * FN * 16;
  __shared__ bf16 sA1[BM * 32];
  __shared__ bf16 sA2[BM * 32];
  __shared__ bf16 sA3[BM * 32];
  __shared__ bf16 sB1[BN * 32];
  __shared__ bf16 sB2[BN * 32];
  __shared__ bf16 sB3[BN * 32];
  const int tid = threadIdx.x;
  const int z = blockIdx.z;
  const int row0 = blockIdx.y * BM;
  const int col0 = blockIdx.x * BN;
  const int lane = tid & 63;
  const int wv = tid >> 6;
  const int wm = (wv % WGM) * (FM * 16);
  const int wn = (wv / WGM) * (FN * 16);
  const int lps = ((lane >> 4) * 16 + (((lane & 15) + 2 * (lane >> 4)) & 15)) << 4;
  f32x4 acc[FM][FN];
#pragma unroll
  for (int i = 0; i < FM; i++)
#pragma unroll
    for (int j = 0; j < FN; j++)
#pragma unroll
      for (int r = 0; r < 4; r++) acc[i][j][r] = 0.f;

  const int ks = p.ksteps();
  for (int s = 0; s < ks; ++s) {
#pragma unroll
    for (int g0 = 0; g0 < BM * 4; g0 += 256) {
      int g = g0 + tid;
      if (g < BM * 4) {
        int row = g >> 2, k0 = (g & 3) * 8;
        bf16x8 v1, v2, v3;
        p.loadA3(z, row0 + row, k0, s, v1, v2, v3);
        int byte = ldsOff(row, g & 3);
        *(bf16x8*)((char*)sA1 + byte) = v1;
        *(bf16x8*)((char*)sA2 + byte) = v2;
        *(bf16x8*)((char*)sA3 + byte) = v3;
      }
    }
#pragma unroll
    for (int g0 = 0; g0 < BN * 4; g0 += 256) {
      int g = g0 + tid;
      if (g < BN * 4) {
        int row = g >> 2, k0 = (g & 3) * 8;
        bf16x8 v1, v2, v3;
        p.loadB3(z, col0 + row, k0, s, v1, v2, v3);
        int byte = ldsOff(row, g & 3);
        *(bf16x8*)((char*)sB1 + byte) = v1;
        *(bf16x8*)((char*)sB2 + byte) = v2;
        *(bf16x8*)((char*)sB3 + byte) = v3;
      }
    }
    __syncthreads();
    {
      bf16x8 a1[FM], a2[FM], a3[FM], b1[FN], b2[FN], b3[FN];
#pragma unroll
      for (int i = 0; i < FM; i++) {
        int byte = (((wm >> 4) + i) << 10) + lps;
        a1[i] = *(const bf16x8*)((const char*)sA1 + byte);
        a2[i] = *(const bf16x8*)((const char*)sA2 + byte);
        a3[i] = *(const bf16x8*)((const char*)sA3 + byte);
      }
#pragma unroll
      for (int j = 0; j < FN; j++) {
        int byte = (((wn >> 4) + j) << 10) + lps;
        b1[j] = *(const bf16x8*)((const char*)sB1 + byte);
        b2[j] = *(const bf16x8*)((const char*)sB2 + byte);
        b3[j] = *(const bf16x8*)((const char*)sB3 + byte);
      }
#pragma unroll
      for (int i = 0; i < FM; i++)
#pragma unroll
        for (int j = 0; j < FN; j++) {
          acc[i][j] = __builtin_amdgcn_mfma_f32_16x16x32_bf16(a1[i], b1[j], acc[i][j], 0, 0, 0);
          acc[i][j] = __builtin_amdgcn_mfma_f32_16x16x32_bf16(a1[i], b2[j], acc[i][j], 0, 0, 0);
          acc[i][j] = __builtin_amdgcn_mfma_f32_16x16x32_bf16(a2[i], b1[j], acc[i][j], 0, 0, 0);
          acc[i][j] = __builtin_amdgcn_mfma_f32_16x16x32_bf16(a2[i], b2[j], acc[i][j], 0, 0, 0);
          acc[i][j] = __builtin_amdgcn_mfma_f32_16x16x32_bf16(a1[i], b3[j], acc[i][j], 0, 0, 0);
          acc[i][j] = __builtin_amdgcn_mfma_f32_16x16x32_bf16(a3[i], b1[j], acc[i][j], 0, 0, 0);
        }
    }
    __syncthreads();
  }
#pragma unroll
  for (int i = 0; i < FM; i++)
#pragma unroll
    for (int j = 0; j < FN; j++)
#pragma unroll
      for (int rg = 0; rg < 4; rg++) {
        int r = row0 + wm + i * 16 + ((lane >> 4) << 2) + rg;
        int c = col0 + wn + j * 16 + (lane & 15);
        p.store(z, r, c, acc[i][j][rg]);
      }
}

// ---------------- f64-acc 6-term GEMM, A in LDS + B direct fragment loads ----------------
// B is pre-swizzled in MFMA fragment order: lane l of a wave loads its own 16B at
// base + lane*16 (coalesced 1KB per fragment, L2/L3-served). 1-step register prefetch
// for both A (via LDS) and B (registers). Numerics identical to gemm6d.
template <int TH, int WGM, int WGN, int FM, int FN, class P>
__global__ __launch_bounds__(TH) void gemm6dBF(P p) {
  constexpr int BM = WGM * FM * 16;
  constexpr int NA = (BM * 4 + TH - 1) / TH;
  __shared__ bf16 sA1[BM * 32];
  __shared__ bf16 sA2[BM * 32];
  __shared__ bf16 sA3[BM * 32];
  const int tid = threadIdx.x;
  const int z = blockIdx.z;
  const int row0 = blockIdx.y * BM;
  const int col0 = blockIdx.x * (WGN * FN * 16);
  const int lane = tid & 63;
  const int wv = tid >> 6;
  const int wm = (wv % WGM) * (FM * 16);
  const int wn = (wv / WGM) * (FN * 16);
  const int cb0 = (col0 + wn) >> 4;  // this wave's first B col-fragment index
  const int lps = ((lane >> 4) * 16 + (((lane & 15) + 2 * (lane >> 4)) & 15)) << 4;
  double acc[FM][FN][4];
  f32x4 fmn[FM][FN], fcr[FM][FN];
#pragma unroll
  for (int i = 0; i < FM; i++)
#pragma unroll
    for (int j = 0; j < FN; j++)
#pragma unroll
      for (int r = 0; r < 4; r++) {
        acc[i][j][r] = 0.0;
        fmn[i][j][r] = 0.f;
        fcr[i][j][r] = 0.f;
      }

  bf16x8 gA[NA][3];
  bf16x8 bC[FN][3], bN[FN][3];
  auto issueA = [&](int s) {
#pragma unroll
    for (int u = 0; u < NA; u++) {
      int g = u * TH + tid;
      if (g < BM * 4) {
        int row = g >> 2, k0 = (g & 3) * 8;
        p.loadA3(z, row0 + row, k0, s, gA[u][0], gA[u][1], gA[u][2]);
      }
    }
  };

  const int ks = p.ksteps();
  issueA(0);
#pragma unroll
  for (int j = 0; j < FN; j++) p.loadBfrag(z, cb0 + j, 0, lane, bC[j][0], bC[j][1], bC[j][2]);
  for (int s = 0; s < ks; ++s) {
#pragma unroll
    for (int u = 0; u < NA; u++) {
      int g = u * TH + tid;
      if (g < BM * 4) {
        int byte = ldsOff(g >> 2, g & 3);
        *(bf16x8*)((char*)sA1 + byte) = gA[u][0];
        *(bf16x8*)((char*)sA2 + byte) = gA[u][1];
        *(bf16x8*)((char*)sA3 + byte) = gA[u][2];
      }
    }
    __syncthreads();
    if (s + 1 < ks) {
      issueA(s + 1);
#pragma unroll
      for (int j = 0; j < FN; j++)
        p.loadBfrag(z, cb0 + j, s + 1, lane, bN[j][0], bN[j][1], bN[j][2]);
    }
    {
      bf16x8 a1[FM], a2[FM], a3[FM];
#pragma unroll
      for (int i = 0; i < FM; i++) {
        int byte = (((wm >> 4) + i) << 10) + lps;
        a1[i] = *(const bf16x8*)((const char*)sA1 + byte);
        a2[i] = *(const bf16x8*)((const char*)sA2 + byte);
        a3[i] = *(const bf16x8*)((const char*)sA3 + byte);
      }
#pragma unroll
      for (int i = 0; i < FM; i++)
#pragma unroll
        for (int j = 0; j < FN; j++) {
          fmn[i][j] = __builtin_amdgcn_mfma_f32_16x16x32_bf16(a1[i], bC[j][0], fmn[i][j], 0, 0, 0);
          fcr[i][j] = __builtin_amdgcn_mfma_f32_16x16x32_bf16(a1[i], bC[j][1], fcr[i][j], 0, 0, 0);
          fcr[i][j] = __builtin_amdgcn_mfma_f32_16x16x32_bf16(a2[i], bC[j][0], fcr[i][j], 0, 0, 0);
          fcr[i][j] = __builtin_amdgcn_mfma_f32_16x16x32_bf16(a2[i], bC[j][1], fcr[i][j], 0, 0, 0);
          fcr[i][j] = __builtin_amdgcn_mfma_f32_16x16x32_bf16(a1[i], bC[j][2], fcr[i][j], 0, 0, 0);
          fcr[i][j] = __builtin_amdgcn_mfma_f32_16x16x32_bf16(a3[i], bC[j][0], fcr[i][j], 0, 0, 0);
        }
    }
    bool flm = ((s & 1) == 1) || (s == ks - 1);
    bool flc = ((s & 7) == 7) || (s == ks - 1);
    if (flm) {
#pragma unroll
      for (int i = 0; i < FM; i++)
#pragma unroll
        for (int j = 0; j < FN; j++)
#pragma unroll
          for (int r = 0; r < 4; r++) {
            acc[i][j][r] += (double)fmn[i][j][r];
            fmn[i][j][r] = 0.f;
          }
    }
    if (flc) {
#pragma unroll
      for (int i = 0; i < FM; i++)
#pragma unroll
        for (int j = 0; j < FN; j++)
#pragma unroll
          for (int r = 0; r < 4; r++) {
            acc[i][j][r] += (double)fcr[i][j][r];
            fcr[i][j][r] = 0.f;
          }
    }
    __syncthreads();
    if (s + 1 < ks) {
#pragma unroll
      for (int j = 0; j < FN; j++)
#pragma unroll
        for (int pl = 0; pl < 3; pl++) bC[j][pl] = bN[j][pl];
    }
  }
#pragma unroll
  for (int i = 0; i < FM; i++)
#pragma unroll
    for (int j = 0; j < FN; j++)
#pragma unroll
      for (int rg = 0; rg < 4; rg++) {
        int r = row0 + wm + i * 16 + ((lane >> 4) << 2) + rg;
        int c = col0 + wn + j * 16 + (lane & 15);
        p.store(z, r, c, acc[i][j][rg]);
      }
}

// ---------------- f64-acc 6-term GEMM (old, B via LDS) — used by CLS1 ----------------
template <int TH, int WGM, int WGN, int FM, int FN, class P>
__global__ __launch_bounds__(TH) void gemm6d(P p) {
  constexpr int BM = WGM * FM * 16;
  constexpr int BN = WGN * FN * 16;
  constexpr int NA = (BM * 4 + TH - 1) / TH;
  constexpr int NB = (BN * 4 + TH - 1) / TH;
  __shared__ bf16 sA1[BM * 32];
  __shared__ bf16 sA2[BM * 32];
  __shared__ bf16 sA3[BM * 32];
  __shared__ bf16 sB1[BN * 32];
  __shared__ bf16 sB2[BN * 32];
  __shared__ bf16 sB3[BN * 32];
  const int tid = threadIdx.x;
  const int z = blockIdx.z;
  const int row0 = blockIdx.y * BM;
  const int col0 = blockIdx.x * BN;
  const int lane = tid & 63;
  const int wv = tid >> 6;
  const int wm = (wv % WGM) * (FM * 16);
  const int wn = (wv / WGM) * (FN * 16);
  const int lps = ((lane >> 4) * 16 + (((lane & 15) + 2 * (lane >> 4)) & 15)) << 4;
  double acc[FM][FN][4];
  f32x4 fmn[FM][FN], fcr[FM][FN];
#pragma unroll
  for (int i = 0; i < FM; i++)
#pragma unroll
    for (int j = 0; j < FN; j++)
#pragma unroll
      for (int r = 0; r < 4; r++) {
        acc[i][j][r] = 0.0;
        fmn[i][j][r] = 0.f;
        fcr[i][j][r] = 0.f;
      }

  bf16x8 gA[NA][3], gB[NB][3];
  auto issue = [&](int s) {
#pragma unroll
    for (int u = 0; u < NA; u++) {
      int g = u * TH + tid;
      if (g < BM * 4) {
        int row = g >> 2, k0 = (g & 3) * 8;
        p.loadA3(z, row0 + row, k0, s, gA[u][0], gA[u][1], gA[u][2]);
      }
    }
#pragma unroll
    for (int u = 0; u < NB; u++) {
      int g = u * TH + tid;
      if (g < BN * 4) {
        int row = g >> 2, k0 = (g & 3) * 8;
        p.loadB3(z, col0 + row, k0, s, gB[u][0], gB[u][1], gB[u][2]);
      }
    }
  };

  const int ks = p.ksteps();
  issue(0);
  for (int s = 0; s < ks; ++s) {
#pragma unroll
    for (int u = 0; u < NA; u++) {
      int g = u * TH + tid;
      if (g < BM * 4) {
        int byte = ldsOff(g >> 2, g & 3);
        *(bf16x8*)((char*)sA1 + byte) = gA[u][0];
        *(bf16x8*)((char*)sA2 + byte) = gA[u][1];
        *(bf16x8*)((char*)sA3 + byte) = gA[u][2];
      }
    }
#pragma unroll
    for (int u = 0; u < NB; u++) {
      int g = u * TH + tid;
      if (g < BN * 4) {
        int byte = ldsOff(g >> 2, g & 3);
        *(bf16x8*)((char*)sB1 + byte) = gB[u][0];
        *(bf16x8*)((char*)sB2 + byte) = gB[u][1];
        *(bf16x8*)((char*)sB3 + byte) = gB[u][2];
      }
    }
    __syncthreads();
    if (s + 1 < ks) issue(s + 1);
    {
      bf16x8 a1[FM], a2[FM], a3[FM], b1[FN], b2[FN], b3[FN];
#pragma unroll
      for (int i = 0; i < FM; i++) {
        int byte = (((wm >> 4) + i) << 10) + lps;
        a1[i] = *(const bf16x8*)((const char*)sA1 + byte);
        a2[i] = *(const bf16x8*)((const char*)sA2 + byte);
        a3[i] = *(const bf16x8*)((const char*)sA3 + byte);
      }
#pragma unroll
      for (int j = 0; j < FN; j++) {
        int byte = (((wn >> 4) + j) << 10) + lps;
        b1[j] = *(const bf16x8*)((const char*)sB1 + byte);
        b2[j] = *(const bf16x8*)((const char*)sB2 + byte);
        b3[j] = *(const bf16x8*)((const char*)sB3 + byte);
      }
#pragma unroll
      for (int i = 0; i < FM; i++)
#pragma unroll
        for (int j = 0; j < FN; j++) {
          fmn[i][j] = __builtin_amdgcn_mfma_f32_16x16x32_bf16(a1[i], b1[j], fmn[i][j], 0, 0, 0);
          fcr[i][j] = __builtin_amdgcn_mfma_f32_16x16x32_bf16(a1[i], b2[j], fcr[i][j], 0, 0, 0);
          fcr[i][j] = __builtin_amdgcn_mfma_f32_16x16x32_bf16(a2[i], b1[j], fcr[i][j], 0, 0, 0);
          fcr[i][j] = __builtin_amdgcn_mfma_f32_16x16x32_bf16(a2[i], b2[j], fcr[i][j], 0, 0, 0);
          fcr[i][j] = __builtin_amdgcn_mfma_f32_16x16x32_bf16(a1[i], b3[j], fcr[i][j], 0, 0, 0);
          fcr[i][j] = __builtin_amdgcn_mfma_f32_16x16x32_bf16(a3[i], b1[j], fcr[i][j], 0, 0, 0);
        }
    }
    bool flm = ((s & 1) == 1) || (s == ks - 1);
    bool flc = ((s & 7) == 7) || (s == ks - 1);
    if (flm) {
#pragma unroll
      for (int i = 0; i < FM; i++)
#pragma unroll
        for (int j = 0; j < FN; j++)
#pragma unroll
          for (int r = 0; r < 4; r++) {
            acc[i][j][r] += (double)fmn[i][j][r];
            fmn[i][j][r] = 0.f;
          }
    }
    if (flc) {
#pragma unroll
      for (int i = 0; i < FM; i++)
#pragma unroll
        for (int j = 0; j < FN; j++)
#pragma unroll
          for (int r = 0; r < 4; r++) {
            acc[i][j][r] += (double)fcr[i][j][r];
            fcr[i][j][r] = 0.f;
          }
    }
    __syncthreads();
  }
#pragma unroll
  for (int i = 0; i < FM; i++)
#pragma unroll
    for (int j = 0; j < FN; j++)
#pragma unroll
      for (int rg = 0; rg < 4; rg++) {
        int r = row0 + wm + i * 16 + ((lane >> 4) << 2) + rg;
        int c = col0 + wn + j * 16 + (lane & 15);
        p.store(z, r, c, acc[i][j][rg]);
      }
}

// ---------------- problem structs ----------------
struct P6PROJ {  // OPRE = x_half @ projT ; M=3000 N=1024 K=1024 ; B in fragment order
  const float* x;
  const bf16 *b1, *b2, *b3;   // fragment-order projT planes
  float* out;
  int rowoff, colbase;
  __device__ int ksteps() const { return 32; }
  __device__ void loadA3(int, int r, int k0, int s, bf16x8& v1, bf16x8& v2, bf16x8& v3) const {
    v1 = bzero8(); v2 = bzero8(); v3 = bzero8();
    if (r >= RPC) return;
    const float* src = x + (size_t)(rowoff + r) * 2048 + colbase + s * 32 + k0;
#pragma unroll
    for (int j = 0; j < 8; j++) {
      bf3 t = split3(src[j]);
      v1[j] = t.h; v2[j] = t.m; v3[j] = t.l;
    }
  }
  __device__ void loadBfrag(int, int cb, int s, int lane, bf16x8& v1, bf16x8& v2,
                            bf16x8& v3) const {
    size_t a = (((size_t)s * 64 + cb) * 64 + lane) * 8;
    v1 = *(const bf16x8*)(b1 + a); v2 = *(const bf16x8*)(b2 + a); v3 = *(const bf16x8*)(b3 + a);
  }
  __device__ void store(int, int r, int c, double v) const {
    if (r < RPC) out[(size_t)r * 1024 + c] = (float)v;
  }
};

struct P6Q {  // Q = o_rgb @ attwT per local pair ; M=750 N=128 K=128
  const bf16 *a1, *a2, *a3, *b1, *b2, *b3;
  bf16 *q1, *q2, *q3;
  __device__ int ksteps() const { return 4; }
  __device__ void loadA3(int z, int r, int k0, int s, bf16x8& v1, bf16x8& v2, bf16x8& v3) const {
    if (r >= 750) { v1 = bzero8(); v2 = bzero8(); v3 = bzero8(); return; }
    size_t a = (size_t)z * 96000 + (size_t)r * 128 + s * 32 + k0;
    v1 = *(const bf16x8*)(a1 + a); v2 = *(const bf16x8*)(a2 + a); v3 = *(const bf16x8*)(a3 + a);
  }
  __device__ void loadB3(int z, int c, int k0, int s, bf16x8& v1, bf16x8& v2, bf16x8& v3) const {
    size_t a = (size_t)(z & 7) * 16384 + (size_t)c * 128 + s * 32 + k0;
    v1 = *(const bf16x8*)(b1 + a); v2 = *(const bf16x8*)(b2 + a); v3 = *(const bf16x8*)(b3 + a);
  }
  __device__ void store(int z, int r, int c, float v) const {
    if (r >= 750) return;
    size_t a = (size_t)z * 96000 + (size_t)r * 128 + c;
    bf3 t = split3(v);
    q1[a] = t.h; q2[a] = t.m; q3[a] = t.l;
  }
};

struct P6S {  // P = exp(Q @ o_flow^T) per local pair ; M=N=750 K=128
  const bf16 *a1, *a2, *a3, *b1, *b2, *b3;
  float* out;
  __device__ int ksteps() const { return 4; }
  __device__ void loadA3(int z, int r, int k0, int s, bf16x8& v1, bf16x8& v2, bf16x8& v3) const {
    if (r >= 750) { v1 = bzero8(); v2 = bzero8(); v3 = bzero8(); return; }
    size_t a = (size_t)z * 96000 + (size_t)r * 128 + s * 32 + k0;
    v1 = *(const bf16x8*)(a1 + a); v2 = *(const bf16x8*)(a2 + a); v3 = *(const bf16x8*)(a3 + a);
  }
  __device__ void loadB3(int z, int c, int k0, int s, bf16x8& v1, bf16x8& v2, bf16x8& v3) const {
    if (c >= 750) { v1 = bzero8(); v2 = bzero8(); v3 = bzero8(); return; }
    size_t a = (size_t)z * 96000 + (size_t)c * 128 + s * 32 + k0;
    v1 = *(const bf16x8*)(a1 == b1 ? a1 : b1 + a);  // placeholder avoided below
    v1 = *(const bf16x8*)(b1 + a); v2 = *(const bf16x8*)(b2 + a); v3 = *(const bf16x8*)(b3 + a);
  }
  __device__ void store(int z, int r, int c, float v) const {
    if (r < 750 && c < 750) out[(size_t)z * SPAIR + (size_t)r * SROW + c] = expf(v);
  }
};

struct P6E {  // xc-half = (P/Z) @ oT^T (both rgb & flow via z), gelu+tanh epilogue
  const float *Pr, *Pt;
  const float *invr, *invc;
  const bf16 *br1, *br2, *br3;
  const bf16 *bt1, *bt2, *bt3;
  const float* x;
  bf16 *xc1, *xc2, *xc3;
  int pairbase;
  __device__ int ksteps() const { return 24; }
  __device__ void loadA3(int z, int r, int k0, int s, bf16x8& v1, bf16x8& v2, bf16x8& v3) const {
    v1 = bzero8(); v2 = bzero8(); v3 = bzero8();
    if (r >= 750) return;
    int zp = z & 31;
    const float* Pm = (z < 32) ? Pr : Pt;
    const float* inv = (z < 32) ? invr : invc;
    int m0 = s * 32 + k0;
    const float* row = Pm + (size_t)zp * SPAIR + (size_t)r * SROW;
    float sc = inv[zp * 750 + r];
#pragma unroll
    for (int j = 0; j < 8; j++) {
      int m = m0 + j;
      if (m < 750) {
        bf3 t = split3(row[m] * sc);
        v1[j] = t.h; v2[j] = t.m; v3[j] = t.l;
      }
    }
  }
  __device__ void loadB3(int z, int c, int k0, int s, bf16x8& v1, bf16x8& v2, bf16x8& v3) const {
    int zp = z & 31;
    size_t a = (size_t)zp * 98304 + (size_t)c * 768 + s * 32 + k0;
    if (z < 32) {
      v1 = *(const bf16x8*)(br1 + a); v2 = *(const bf16x8*)(br2 + a); v3 = *(const bf16x8*)(br3 + a);
    } else {
      v1 = *(const bf16x8*)(bt1 + a); v2 = *(const bf16x8*)(bt2 + a); v3 = *(const bf16x8*)(bt3 + a);
    }
  }
  __device__ void store(int z, int r, int c, float v) const {
    if (r >= 750) return;
    int zp = z & 31;
    int gp = pairbase + zp;
    int hh = gp & 7, n = gp >> 3;
    int xcol = ((z < 32) ? 0 : 1024) + hh * 128 + c;
    float g = 0.5f * v * (1.f + erff(v * 0.70710678118654752f));
    float f = tanhf(g + x[((size_t)n * 750 + r) * 2048 + xcol]);
    size_t a = (size_t)(n * PT + r + 4) * 2048 + xcol;
    bf3 t = split3(f);
    xc1[a] = t.h; xc2[a] = t.m; xc3[a] = t.l;
  }
};

struct P6CONV {  // emb = relu(conv9(xc, W) + b) ; B in fragment order
  const bf16 *a1, *a2, *a3, *b1, *b2, *b3;  // b* = WT fragment-order planes
  const float* bias;
  bf16 *o1, *o2, *o3;
  __device__ int ksteps() const { return 576; }
  __device__ void loadA3(int, int r, int k0, int s, bf16x8& v1, bf16x8& v2, bf16x8& v3) const {
    if (r >= MM) { v1 = bzero8(); v2 = bzero8(); v3 = bzero8(); return; }
    int ktap = s >> 6, kb = s & 63;
    int n = (unsigned)r / 750u;
    size_t a = (size_t)(r + 8 * n + ktap) * 2048 + kb * 32 + k0;
    v1 = *(const bf16x8*)(a1 + a); v2 = *(const bf16x8*)(a2 + a); v3 = *(const bf16x8*)(a3 + a);
  }
  __device__ void loadBfrag(int, int cb, int s, int lane, bf16x8& v1, bf16x8& v2,
                            bf16x8& v3) const {
    size_t a = (((size_t)s * 128 + cb) * 64 + lane) * 8;
    v1 = *(const bf16x8*)(b1 + a); v2 = *(const bf16x8*)(b2 + a); v3 = *(const bf16x8*)(b3 + a);
  }
  __device__ void store(int, int r, int c, double v) const {
    if (r >= MM) return;
    v += (double)bias[c];
    if (v < 0) v = 0;
    int n = (unsigned)r / 750u;
    size_t a = (size_t)(r + 8 * n + 4) * 2048 + c;
    bf3 t = split3((float)v);
    o1[a] = t.h; o2[a] = t.m; o3[a] = t.l;
  }
};

struct P6CLS1 {  // cas1 = conv9(emb, cls1_w), N=32 (20 used) — old B-via-LDS path
  const bf16 *a1, *a2, *a3, *b1, *b2, *b3;
  float* out;
  __device__ int ksteps() const { return 576; }
  __device__ void loadA3(int, int r, int k0, int s, bf16x8& v1, bf16x8& v2, bf16x8& v3) const {
    if (r >= MM) { v1 = bzero8(); v2 = bzero8(); v3 = bzero8(); return; }
    int ktap = s >> 6, kb = s & 63;
    int n = (unsigned)r / 750u;
    size_t a = (size_t)(r + 8 * n + ktap) * 2048 + kb * 32 + k0;
    v1 = *(const bf16x8*)(a1 + a); v2 = *(const bf16x8*)(a2 + a); v3 = *(const bf16x8*)(a3 + a);
  }
  __device__ void loadB3(int, int c, int k0, int s, bf16x8& v1, bf16x8& v2, bf16x8& v3) const {
    int ktap = s >> 6, kb = s & 63;
    size_t a = ((size_t)(ktap * 32 + c)) * 2048 + kb * 32 + k0;
    v1 = *(const bf16x8*)(b1 + a); v2 = *(const bf16x8*)(b2 + a); v3 = *(const bf16x8*)(b3 + a);
  }
  __device__ void store(int, int r, int c, double v) const {
    if (r < MM && c < NC) out[(size_t)r * NC + c] = (float)v;
  }
};

// ---------------- misc kernels ----------------
// projT planes in MFMA fragment order: frag[(s*64+cb)*64+lane][e]:
//   col = cb*16 + (lane&15) (=h*128+e'), k = s*32 + (lane>>4)*8 + e
__global__ void k_split_projT3f(const float* rgbp, const float* flowp, bf16* r1, bf16* r2,
                                bf16* r3, bf16* f1, bf16* f2, bf16* f3) {
  int st = blockIdx.x >> 6, cb = blockIdx.x & 63;
  const float* src = st ? flowp : rgbp;
  bf16* o1 = st ? f1 : r1;
  bf16* o2 = st ? f2 : r2;
  bf16* o3 = st ? f3 : r3;
  for (int u = threadIdx.x; u < 16384; u += 256) {
    int s = u >> 9;
    int lane = (u >> 3) & 63;
    int e = u & 7;
    int col = cb * 16 + (lane & 15);
    int h = col >> 7, ep = col & 127;
    int k = s * 32 + (lane >> 4) * 8 + e;
    bf3 t = split3(src[(size_t)h * 131072 + (size_t)k * 128 + ep]);
    size_t d = (((size_t)s * 64 + cb) * 64 + lane) * 8 + e;
    o1[d] = t.h; o2[d] = t.m; o3[d] = t.l;
  }
}

__global__ void k_split_attewT3(const float* aw, bf16* w1, bf16* w2, bf16* w3) {
  int b = blockIdx.x;
  int h = b >> 7, f = b & 127;
  int e = threadIdx.x;
  bf3 t = split3(aw[(size_t)h * 16384 + (size_t)e * 128 + f]);
  size_t a = (size_t)h * 16384 + (size_t)f * 128 + e;
  w1[a] = t.h; w2[a] = t.m; w3[a] = t.l;
}

// WT planes in fragment order: frag[((ktap*64+kb)*128+cb)*64+lane][e]:
//   oc = cb*16 + (lane&15), ic = kb*32 + (lane>>4)*8 + e
__global__ void k_split_wt3f(const float* ew, bf16* w1, bf16* w2, bf16* w3) {
  int cb = blockIdx.x & 127;
  int ktap = blockIdx.x >> 7;
  for (int u = threadIdx.x; u < 32768; u += 256) {
    int kb = u >> 9;
    int lane = (u >> 3) & 63;
    int e = u & 7;
    int oc = cb * 16 + (lane & 15);
    int ic = kb * 32 + (lane >> 4) * 8 + e;
    bf3 t = split3(ew[(size_t)oc * 18432 + (size_t)ic * 9 + ktap]);
    size_t d = (((size_t)(ktap * 64 + kb) * 128 + cb) * 64 + lane) * 8 + e;
    w1[d] = t.h; w2[d] = t.m; w3[d] = t.l;
  }
}

__global__ void k_split_wc3(const float* cw, bf16* w1, bf16* w2, bf16* w3) {
  int k = blockIdx.x / 32, c = blockIdx.x % 32;
  for (int i = threadIdx.x; i < 2048; i += 256) {
    float v = (c < NC) ? cw[(size_t)c * 18432 + (size_t)i * 9 + k] : 0.f;
    bf3 t = split3(v);
    size_t a = ((size_t)(k * 32 + c)) * 2048 + i;
    w1[a] = t.h; w2[a] = t.m; w3[a] = t.l;
  }
}

__global__ void k_norm3(const float* opre, bf16* o1, bf16* o2, bf16* o3) {
  int r = blockIdx.x;
  int head = threadIdx.x >> 5, ln = threadIdx.x & 31;
  const float* src = opre + (size_t)r * 1024 + head * 128 + ln * 4;
  float4 v = *(const float4*)src;
  double ss = (double)v.x * v.x + (double)v.y * v.y + (double)v.z * v.z + (double)v.w * v.w;
  for (int k = 16; k; k >>= 1) ss += __shfl_xor(ss, k, 32);
  double rn = 1.0 / fmax(sqrt(ss), 1e-12);
  int nl = r / 750, l = r % 750;
  int zp = nl * 8 + head;
  size_t o = (size_t)zp * 96000 + (size_t)l * 128 + ln * 4;
  float vv[4] = {v.x, v.y, v.z, v.w};
  bf16x4 h4, m4, l4;
#pragma unroll
  for (int j = 0; j < 4; j++) {
    bf3 t = split3((float)((double)vv[j] * rn));
    h4[j] = t.h; m4[j] = t.m; l4[j] = t.l;
  }
  *(bf16x4*)(o1 + o) = h4;
  *(bf16x4*)(o2 + o) = m4;
  *(bf16x4*)(o3 + o) = l4;
}

__global__ void k_trans3(const bf16* i1, const bf16* i2, const bf16* i3, bf16* o1, bf16* o2,
                         bf16* o3) {
  __shared__ bf16 t1[32][33], t2[32][33], t3[32][33];
  int zp = blockIdx.y;
  int lt = blockIdx.x >> 2, et = blockIdx.x & 3;
  int tx = threadIdx.x & 31, ty = threadIdx.x >> 5;
#pragma unroll
  for (int p = 0; p < 4; p++) {
    int lrow = lt * 32 + ty + p * 8;
    int e = et * 32 + tx;
    bf16 a = (bf16)0.f, b = (bf16)0.f, c = (bf16)0.f;
    if (lrow < 750) {
      size_t ad = (size_t)zp * 96000 + (size_t)lrow * 128 + e;
      a = i1[ad]; b = i2[ad]; c = i3[ad];
    }
    t1[ty + p * 8][tx] = a;
    t2[ty + p * 8][tx] = b;
    t3[ty + p * 8][tx] = c;
  }
  __syncthreads();
#pragma unroll
  for (int p = 0; p < 4; p++) {
    int e = et * 32 + ty + p * 8;
    int l2 = lt * 32 + tx;
    size_t ad = (size_t)zp * 98304 + (size_t)e * 768 + l2;
    o1[ad] = t1[tx][ty + p * 8];
    o2[ad] = t2[tx][ty + p * 8];
    o3[ad] = t3[tx][ty + p * 8];
  }
}

__global__ void k_transS(const float* S, float* ST) {
  __shared__ float t[32][33];
  int zp = blockIdx.y;
  int tr = (blockIdx.x / 24) * 32, tc = (blockIdx.x % 24) * 32;
  int tx = threadIdx.x & 31, ty = threadIdx.x >> 5;
#pragma unroll
  for (int p = 0; p < 4; p++) {
    int rr = tr + ty + p * 8, cc = tc + tx;
    t[ty + p * 8][tx] = (rr < 750 && cc < 750) ? S[(size_t)zp * SPAIR + (size_t)rr * SROW + cc] : 0.f;
  }
  __syncthreads();
#pragma unroll
  for (int p = 0; p < 4; p++) {
    int cc = tc + ty + p * 8, rr = tr + tx;
    if (cc < 750 && rr < 750) ST[(size_t)zp * SPAIR + (size_t)cc * SROW + rr] = t[tx][ty + p * 8];
  }
}

__global__ void k_statsd(const float* P, float* inv) {
  int b = blockIdx.x;
  int p = b / 94, r0 = (b % 94) * 8;
  int g = threadIdx.x >> 5, ln = threadIdx.x & 31;
  int r = r0 + g;
  if (r >= 750) return;
  const float* row = P + (size_t)p * SPAIR + (size_t)r * SROW;
  double s = 0.0;
  for (int m = ln; m < 750; m += 32) s += (double)row[m];
  for (int k = 16; k; k >>= 1) s += __shfl_xor(s, k, 32);
  if (ln == 0) inv[p * 750 + r] = (float)(1.0 / s);
}

__global__ void k_cls2(const float* cas1, const float* w2, float* cas_out, float* cast) {
  int idx = blockIdx.x * 256 + threadIdx.x;
  if (idx >= MM * NC) return;
  int r = idx / NC, c = idx % NC;
  int n = r / 750, t = r % 750;
  double a = 0.0;
#pragma unroll
  for (int j = 0; j < 7; j++) {
    int tt = t + 2 * j - 6;
    if (tt >= 0 && tt < 750)
      a += (double)w2[c * 7 + j] * (double)cas1[((size_t)n * 750 + tt) * NC + c];
  }
  if (a < 0) a = 0;
  cas_out[idx] = (float)a;
  cast[((size_t)n * NC + c) * 750 + t] = (float)a;
}

__global__ void k_act(const float* cas, float* act, float* out_act) {
  int r = blockIdx.x * 256 + threadIdx.x;
  if (r >= MM) return;
  double s = 0.0;
#pragma unroll
  for (int c = 0; c < NC; c++) s += (double)cas[(size_t)r * NC + c];
  act[r] = (float)s;
  out_act[r] = (float)s;
}

__global__ __launch_bounds__(512) void k_mask(const float* act, float* arev, float* inner,
                                              float* outer) {
  __shared__ u64 ks[1024];
  __shared__ float av[768];
  __shared__ float bb[768];
  int n = blockIdx.x;
  for (int i = threadIdx.x; i < 1024; i += 512) {
    if (i < 750) {
      float v = act[n * 750 + i];
      av[i] = v;
      ks[i] = ((u64)asc_enc(v) << 32) | (u32)i;
    } else
      ks[i] = ~0ull;
  }
  bsort1024(ks);
  float med = 0.5f * (asc_dec((u32)(ks[374] >> 32)) + asc_dec((u32)(ks[375] >> 32)));
  float amax = asc_dec((u32)(ks[749] >> 32));
  for (int t = threadIdx.x; t < 750; t += 512) bb[t] = (av[t] > med) ? 1.f : 0.f;
  __syncthreads();
  for (int t = threadIdx.x; t < 750; t += 512) {
    float e3 = 1.f, e6 = 1.f, d3 = 0.f, d6 = 0.f;
    for (int j = t - 1; j <= t + 1; ++j) {
      float v = (j >= 0 && j < 750) ? bb[j] : 0.f;
      e3 = fminf(e3, v); d3 = fmaxf(d3, v);
    }
    for (int j = t - 3; j <= t + 2; ++j) {
      float v = (j >= 0 && j < 750) ? bb[j] : 0.f;
      e6 = fminf(e6, v);
    }
    for (int j = t - 2; j <= t + 3; ++j) {
      float v = (j >= 0 && j < 750) ? bb[j] : 0.f;
      d6 = fmaxf(d6, v);
    }
    int g = n * 750 + t;
    inner[g] = (e3 - e6 > 0.5f) ? av[t] : 0.f;
    outer[g] = (d6 - d3 > 0.5f) ? av[t] : 0.f;
    arev[g] = amax - av[t];
  }
}

__global__ __launch_bounds__(512) void k_topk(const float* act, const float* arev,
                                              const float* inner, const float* outer, int* idxb) {
  __shared__ u64 ks[1024];
  int n = blockIdx.x >> 2, w = blockIdx.x & 3;
  const float* src = (w == 0) ? act : ((w == 1) ? arev : ((w == 2) ? inner : outer));
  int K = (w < 2) ? KE : KH;
  int off = (w == 0) ? 0 : ((w == 1) ? 150 : ((w == 2) ? 300 : 337));
  for (int i = threadIdx.x; i < 1024; i += 512) {
    if (i < 750) {
      u32 d = ~asc_enc(src[n * 750 + i]);
      ks[i] = ((u64)d << 32) | (u32)i;
    } else
      ks[i] = ~0ull;
  }
  bsort1024(ks);
  for (int i = threadIdx.x; i < K; i += 512) idxb[n * 374 + off + i] = (int)(ks[i] & 0xFFFFFFFFu);
}

__global__ __launch_bounds__(512) void k_topcas(const float* cast, float* smean) {
  __shared__ u64 ks[1024];
  __shared__ float red[512];
  int b = blockIdx.x;
  for (int i = threadIdx.x; i < 1024; i += 512) {
    if (i < 750) {
      u32 d = ~asc_enc(cast[(size_t)b * 750 + i]);
      ks[i] = ((u64)d << 32) | (u32)i;
    } else
      ks[i] = ~0ull;
  }
  bsort1024(ks);
  float s = 0.f;
  for (int i = threadIdx.x; i < KE; i += 512) s += asc_dec(~(u32)(ks[i] >> 32));
  red[threadIdx.x] = s;
  __syncthreads();
  for (int st = 256; st; st >>= 1) {
    if (threadIdx.x < st) red[threadIdx.x] += red[threadIdx.x + st];
    __syncthreads();
  }
  if (threadIdx.x == 0) smean[b] = red[0] / 150.f;
}

__global__ void k_gather(const int* idxb, const bf16* e1, const bf16* e2, const bf16* e3,
                         float* dout) {
  int b = blockIdx.x;
  int n = b / 374, j = b % 374;
  size_t obase;
  if (j < 150) obase = OUT_EA + ((size_t)n * KE + j) * 2048;
  else if (j < 300) obase = OUT_EB + ((size_t)n * KE + (j - 150)) * 2048;
  else if (j < 337) obase = OUT_HA + ((size_t)n * KH + (j - 300)) * 2048;
  else obase = OUT_HB + ((size_t)n * KH + (j - 337)) * 2048;
  int t = idxb[n * 374 + j];
  size_t irow = (size_t)(n * PT + t + 4) * 2048;
#pragma unroll
  for (int p = 0; p < 8; p++) {
    int c = threadIdx.x + p * 256;
    dout[obase + c] = (float)e1[irow + c] + (float)e2[irow + c] + (float)e3[irow + c];
  }
}

__global__ void k_vs(const float* smean, float* dout) {
  int n = blockIdx.x;
  int c = threadIdx.x;
  float v = (c < NC) ? smean[n * NC + c] : -3.4e38f;
  float m = v;
  for (int s = 32; s; s >>= 1) m = fmaxf(m, __shfl_xor(m, s));
  float e = (c < NC) ? expf(v - m) : 0.f;
  float sum = e;
  for (int s = 32; s; s >>= 1) sum += __shfl_xor(sum, s);
  if (c < NC) dout[n * NC + c] = e / sum;
}

// ---------------- host ----------------
extern "C" void kernel_launch(void* const* d_in, const int* in_sizes, int n_in, void* d_out,
                              int out_size, void* d_ws, size_t ws_size, hipStream_t stream) {
  const float* x = (const float*)d_in[0];
  const float* rgbp = (const float*)d_in[1];
  const float* flowp = (const float*)d_in[2];
  const float* attw = (const float*)d_in[3];
  const float* embw = (const float*)d_in[4];
  const float* embb = (const float*)d_in[5];
  const float* c1w = (const float*)d_in[6];
  const float* c2w = (const float*)d_in[7];
  float* dout = (float*)d_out;
  char* ws = (char*)d_ws;

  if (ws_size < WS_NEED) {
    fprintf(stderr, "[CoLA] FATAL ws_size=%zu < need=%zu\n", ws_size, (size_t)WS_NEED);
    return;
  }

  bf16* XC1 = (bf16*)(ws + O_XC1);
  bf16* XC2 = (bf16*)(ws + O_XC2);
  bf16* XC3 = (bf16*)(ws + O_XC3);
  bf16* EM1 = (bf16*)(ws + O_EM1);
  bf16* EM2 = (bf16*)(ws + O_EM2);
  bf16* EM3 = (bf16*)(ws + O_EM3);
  float* CAS1 = (float*)(ws + O_CAS1);
  float* CAST = (float*)(ws + O_CAST);
  float* ACT = (float*)(ws + O_ACT);
  float* AREV = (float*)(ws + O_AREV);
  float* INNER = (float*)(ws + O_INNER);
  float* OUTER = (float*)(ws + O_OUTER);
  float* SMEAN = (float*)(ws + O_SMEAN);
  int* IDX = (int*)(ws + O_IDX);
  float* RSINV = (float*)(ws + O_RSINV);
  float* CSINV = (float*)(ws + O_CSINV);
  float* SBUF = (float*)(ws + O_S);
  float* STBUF = (float*)(ws + O_ST);
  bf16 *Q1 = (bf16*)(ws + O_Q1), *Q2 = (bf16*)(ws + O_Q2), *Q3 = (bf16*)(ws + O_Q3);
  bf16 *OR1 = (bf16*)(ws + O_OR1), *OR2 = (bf16*)(ws + O_OR2), *OR3 = (bf16*)(ws + O_OR3);
  bf16 *OF1 = (bf16*)(ws + O_OF1), *OF2 = (bf16*)(ws + O_OF2), *OF3 = (bf16*)(ws + O_OF3);
  bf16 *OTR1 = (bf16*)(ws + O_OTR1), *OTR2 = (bf16*)(ws + O_OTR2), *OTR3 = (bf16*)(ws + O_OTR3);
  bf16 *OTF1 = (bf16*)(ws + O_OTF1), *OTF2 = (bf16*)(ws + O_OTF2), *OTF3 = (bf16*)(ws + O_OTF3);
  float* OPRE = (float*)(ws + O_OPRE);
  bf16 *PR1 = (bf16*)(ws + O_PR1), *PR2 = (bf16*)(ws + O_PR2), *PR3 = (bf16*)(ws + O_PR3);
  bf16 *PF1 = (bf16*)(ws + O_PF1), *PF2 = (bf16*)(ws + O_PF2), *PF3 = (bf16*)(ws + O_PF3);
  bf16 *AW1 = (bf16*)(ws + O_AW1), *AW2 = (bf16*)(ws + O_AW2), *AW3 = (bf16*)(ws + O_AW3);
  bf16 *WT1 = (bf16*)(ws + O_WT1), *WT2 = (bf16*)(ws + O_WT2), *WT3 = (bf16*)(ws + O_WT3);
  bf16 *WC1 = (bf16*)(ws + O_WC1), *WC2 = (bf16*)(ws + O_WC2), *WC3 = (bf16*)(ws + O_WC3);

  (void)hipMemsetAsync(ws, 0, O_CAS1, stream);  // zero 6 padded planes

  k_split_projT3f<<<128, 256, 0, stream>>>(rgbp, flowp, PR1, PR2, PR3, PF1, PF2, PF3);
  k_split_attewT3<<<1024, 128, 0, stream>>>(attw, AW1, AW2, AW3);

  for (int cb = 0; cb < NCHUNK; cb++) {
    int rowoff = cb * RPC;
    int pb = cb * PCH;
    // rgb: proj -> norm -> trans -> q
    {
      P6PROJ p{x, PR1, PR2, PR3, OPRE, rowoff, 0};
      gemm6dBF<512, 2, 4, 4, 2, P6PROJ><<<dim3(8, 24, 1), 512, 0, stream>>>(p);
    }
    k_norm3<<<RPC, 256, 0, stream>>>(OPRE, OR1, OR2, OR3);
    k_trans3<<<dim3(96, 32), 256, 0, stream>>>(OR1, OR2, OR3, OTR1, OTR2, OTR3);
    {
      P6Q p{OR1, OR2, OR3, AW1, AW2, AW3, Q1, Q2, Q3};
      gemm6<2, 2, 4, 4, P6Q><<<dim3(1, 6, PCH), 256, 0, stream>>>(p);
    }
    // flow: proj -> norm -> trans
    {
      P6PROJ p{x, PF1, PF2, PF3, OPRE, rowoff, 1024};
      gemm6dBF<512, 2, 4, 4, 2, P6PROJ><<<dim3(8, 24, 1), 512, 0, stream>>>(p);
    }
    k_norm3<<<RPC, 256, 0, stream>>>(OPRE, OF1, OF2, OF3);
    k_trans3<<<dim3(96, 32), 256, 0, stream>>>(OF1, OF2, OF3, OTF1, OTF2, OTF3);
    // P = exp(S), transpose, softmax denominators, fused e-GEMMs (rgb+flow in one)
    {
      P6S p{Q1, Q2, Q3, OF1, OF2, OF3, SBUF};
      gemm6<2, 2, 4, 4, P6S><<<dim3(6, 6, PCH), 256, 0, stream>>>(p);
    }
    k_transS<<<dim3(576, PCH), 256, 0, stream>>>(SBUF, STBUF);
    k_statsd<<<PCH * 94, 256, 0, stream>>>(SBUF, RSINV);
    k_statsd<<<PCH * 94, 256, 0, stream>>>(STBUF, CSINV);
    {
      P6E p{SBUF, STBUF, RSINV, CSINV, OTR1, OTR2, OTR3, OTF1, OTF2, OTF3, x, XC1, XC2, XC3, pb};
      gemm6<2, 2, 4, 4, P6E><<<dim3(1, 6, 2 * PCH), 256, 0, stream>>>(p);
    }
  }

  // conv weights (alias dead attention arena), conv GEMMs
  k_split_wt3f<<<1152, 256, 0, stream>>>(embw, WT1, WT2, WT3);
  k_split_wc3<<<288, 256, 0, stream>>>(c1w, WC1, WC2, WC3);
  {
    P6CONV p{XC1, XC2, XC3, WT1, WT2, WT3, embb, EM1, EM2, EM3};
    gemm6dBF<512, 2, 4, 4, 2, P6CONV><<<dim3(16, 94, 1), 512, 0, stream>>>(p);
  }
  {
    P6CLS1 p{EM1, EM2, EM3, WC1, WC2, WC3, CAS1};
    gemm6d<512, 4, 2, 2, 1, P6CLS1><<<dim3(1, 94, 1), 512, 0, stream>>>(p);
  }
  k_cls2<<<(MM * NC + 255) / 256, 256, 0, stream>>>(CAS1, c2w, dout + OUT_CAS, CAST);
  k_act<<<(MM + 255) / 256, 256, 0, stream>>>(dout + OUT_CAS, ACT, dout + OUT_ACT);

  // postprocess
  k_mask<<<16, 512, 0, stream>>>(ACT, AREV, INNER, OUTER);
  k_topk<<<64, 512, 0, stream>>>(ACT, AREV, INNER, OUTER, IDX);
  k_topcas<<<320, 512, 0, stream>>>(CAST, SMEAN);
  k_gather<<<16 * 374, 256, 0, stream>>>(IDX, EM1, EM2, EM3, dout);
  k_vs<<<16, 64, 0, stream>>>(SMEAN, dout);
}